// Round 8
// baseline (1169.479 us; speedup 1.0000x reference)
//
#include <hip/hip_runtime.h>

// TransformerBlock (attn + MLP + top2-MoE) on MI355X.
// Pre-gate chain in split-fp16 3-term MFMA (fp32-class accuracy so the MoE
// top-2 selection matches the fp32 reference); post-gate experts in plain
// fp16 MFMA, SPARSE top-2 dispatch.
// R8: attn no-max softmax (P=exp(s/8), bounded 35-sigma below f16 overflow)
// with row-sum via MFMA x ones; gemm_split gets the R7-proven 2-phase dbuf
// (128 KB LDS, 1 barrier/K-step). moe1/moe2/attn-staging unchanged from R7.

typedef _Float16 f16;
typedef _Float16 f16x4 __attribute__((ext_vector_type(4)));
typedef _Float16 f16x8 __attribute__((ext_vector_type(8)));
typedef float f32x4 __attribute__((ext_vector_type(4)));
typedef unsigned short ushort;

#define MFMA16(a, b, c) __builtin_amdgcn_mfma_f32_16x16x32_f16((a), (b), (c), 0, 0, 0)

__device__ __forceinline__ void gload16(void* lds, const void* g) {
  __builtin_amdgcn_global_load_lds(
      (const __attribute__((address_space(1))) unsigned int*)g,
      (__attribute__((address_space(3))) unsigned int*)lds, 16, 0, 0);
}

__device__ __forceinline__ void split2(float t, f16& h, f16& l) {
  h = (f16)t;
  l = (f16)(t - (float)h);
}

__device__ __forceinline__ float gelu_f(float x) {  // exact (pre-gate path)
  return 0.5f * x * (1.0f + erff(x * 0.70710678118654752f));
}

__device__ __forceinline__ float gelu_fast(float x) {  // tanh-approx (post-gate experts)
  return x / (1.0f + __expf(-1.5957691216f * (x + 0.044715f * x * x * x)));
}

// ---------------- LayerNorm: one wave per row of 768; split-fp16 planes out ----------------
__global__ __launch_bounds__(256) void ln_kernel(
    const float* __restrict__ x, const float* __restrict__ gam,
    const float* __restrict__ bet, f16* __restrict__ oh, f16* __restrict__ ol) {
  const int w = threadIdx.x >> 6, lane = threadIdx.x & 63;
  const size_t row = (size_t)blockIdx.x * 4 + w;
  const float* xr = x + row * 768;
  f32x4 v[3];
  float s = 0.0f;
#pragma unroll
  for (int c = 0; c < 3; c++) {
    v[c] = *(const f32x4*)(xr + c * 256 + lane * 4);
    s += v[c][0] + v[c][1] + v[c][2] + v[c][3];
  }
#pragma unroll
  for (int off = 32; off; off >>= 1) s += __shfl_xor(s, off);
  const float mean = s * (1.0f / 768.0f);
  float q = 0.0f;
#pragma unroll
  for (int c = 0; c < 3; c++)
#pragma unroll
    for (int j = 0; j < 4; j++) {
      float d = v[c][j] - mean;
      q += d * d;
    }
#pragma unroll
  for (int off = 32; off; off >>= 1) q += __shfl_xor(q, off);
  // precise rsqrt: rsqrtf() approx (~1e-5 rel) would risk gate flips downstream
  const float rstd = 1.0f / sqrtf(q * (1.0f / 768.0f) + 1e-5f);
#pragma unroll
  for (int c = 0; c < 3; c++) {
    const int col = c * 256 + lane * 4;
    f32x4 gv = *(const f32x4*)(gam + col);
    f32x4 bv = *(const f32x4*)(bet + col);
    f16x4 yh, yl;
#pragma unroll
    for (int j = 0; j < 4; j++) {
      float y = (v[c][j] - mean) * rstd * gv[j] + bv[j];
      f16 hh, ll;
      split2(y, hh, ll);
      yh[j] = hh;
      yl[j] = ll;
    }
    *(f16x4*)(oh + row * 768 + col) = yh;
    *(f16x4*)(ol + row * 768 + col) = yl;
  }
}

// ---------------- fp32 -> split fp16 (elementwise, x4) ----------------
__global__ __launch_bounds__(256) void convert_split_k(
    const float* __restrict__ in, f16* __restrict__ oh, f16* __restrict__ ol,
    int n4) {
  const int i = blockIdx.x * 256 + threadIdx.x;
  if (i >= n4) return;
  f32x4 v = ((const f32x4*)in)[i];
  f16x4 h, l;
#pragma unroll
  for (int j = 0; j < 4; j++) {
    f16 hh, ll;
    split2(v[j], hh, ll);
    h[j] = hh;
    l[j] = ll;
  }
  ((f16x4*)oh)[i] = h;
  ((f16x4*)ol)[i] = l;
}

// ---------------- fp32 [R][ldin] (32x32 tiles) -> fp16 [C][R] split ----------------
__global__ __launch_bounds__(256) void transpose_k(
    const float* __restrict__ in, f16* __restrict__ oh, f16* __restrict__ ol,
    int R, int ldin) {
  __shared__ float t[32][33];
  const int tx = threadIdx.x & 31, ty = threadIdx.x >> 5;
  const int r0 = blockIdx.y * 32, c0 = blockIdx.x * 32;
#pragma unroll
  for (int i = 0; i < 4; i++)
    t[ty + 8 * i][tx] = in[(size_t)(r0 + ty + 8 * i) * ldin + c0 + tx];
  __syncthreads();
#pragma unroll
  for (int i = 0; i < 4; i++) {
    const float val = t[tx][ty + 8 * i];
    const size_t o = (size_t)(c0 + ty + 8 * i) * R + r0 + tx;
    f16 hh, ll;
    split2(val, hh, ll);
    oh[o] = hh;
    ol[o] = ll;
  }
}

// ---------------- per-expert fp32 [R][C] -> f16 [C][R] (blockIdx.z = expert) ----------------
__global__ __launch_bounds__(256) void etrans_kernel(
    const float* __restrict__ in0, f16* __restrict__ out0, int R, int C) {
  const size_t eoff = (size_t)blockIdx.z * R * C;
  const float* in = in0 + eoff;
  f16* out = out0 + eoff;
  __shared__ float t[32][33];
  const int tx = threadIdx.x & 31, ty = threadIdx.x >> 5;
  const int r0 = blockIdx.y * 32, c0 = blockIdx.x * 32;
#pragma unroll
  for (int i = 0; i < 4; i++)
    t[ty + 8 * i][tx] = in[(size_t)(r0 + ty + 8 * i) * C + c0 + tx];
  __syncthreads();
#pragma unroll
  for (int i = 0; i < 4; i++)
    out[(size_t)(c0 + ty + 8 * i) * R + r0 + tx] = (f16)t[tx][ty + 8 * i];
}

// ---------------- V transpose: qkv planes (v part) -> [B,H,64,1024]; z = hi/lo ----------------
__global__ __launch_bounds__(256) void vtrans_kernel(
    const ushort* __restrict__ srcH, const ushort* __restrict__ srcL,
    ushort* __restrict__ dstH, ushort* __restrict__ dstL) {
  const int nt = blockIdx.x, bh = blockIdx.y;
  const ushort* src = blockIdx.z ? srcL : srcH;
  ushort* dst = blockIdx.z ? dstL : dstH;
  const int b = bh / 12, h = bh % 12;
  __shared__ ushort t[64][65];
  const int tid = threadIdx.x;
#pragma unroll
  for (int i = 0; i < 16; i++) {
    const int idx = i * 256 + tid;
    const int r = idx >> 6, c = idx & 63;
    t[r][c] = src[((size_t)b * 1024 + nt * 64 + r) * 2304 + 1536 + h * 64 + c];
  }
  __syncthreads();
#pragma unroll
  for (int i = 0; i < 16; i++) {
    const int idx = i * 256 + tid;
    const int d = idx >> 6, n = idx & 63;
    dst[((size_t)bh * 64 + d) * 1024 + nt * 64 + n] = t[n][d];
  }
}

// ---------------- split-fp16 3-term GEMM: C = A·B^T (+bias), A[M,K] B[N,K] ----------------
// 128x128 tile, BK=64, 4 waves (2x2). Row-major LDS [128][64]f16 (=128B rows),
// XOR chunk-swizzle; staging: lane L -> row L>>3, global chunk (L&7)^((L>>3)&7).
// R8: 2-phase double-buffered (128 KB LDS), 1 barrier/K-step, STAGE overlaps COMPUTE.
template <int MODE>
__global__ __launch_bounds__(256) void gemm_split(
    const f16* __restrict__ Ah, const f16* __restrict__ Al, int lda,
    const f16* __restrict__ Bh, const f16* __restrict__ Bl, int ldb,
    const float* __restrict__ bias, const float* __restrict__ residF,
    const f16* __restrict__ residH, const f16* __restrict__ residL, int addto,
    float* __restrict__ outF, f16* __restrict__ outH, f16* __restrict__ outL,
    int ldo, int K) {
  __shared__ __align__(16) f16 A0h[128][64], A0l[128][64], B0h[128][64], B0l[128][64];
  __shared__ __align__(16) f16 A1h[128][64], A1l[128][64], B1h[128][64], B1l[128][64];
  const int tid = threadIdx.x;
  const int lane = tid & 63, wid = tid >> 6;
  const int wm = wid >> 1, wn = wid & 1;
  const int g = lane >> 4, lr = lane & 15;
  const int swz = (((tid & 7) ^ ((tid >> 3) & 7)) << 3);  // element offset
  const size_t m0 = (size_t)blockIdx.y * 128, n0 = (size_t)blockIdx.x * 128;
  f32x4 acc[4][4] = {};
  auto STAGE = [&](f16 (&sAh)[128][64], f16 (&sAl)[128][64],
                   f16 (&sBh)[128][64], f16 (&sBl)[128][64], int k0) {
#pragma unroll
    for (int s = 0; s < 4; s++) {
      const int u = s * 256 + tid;  // 16B unit within a 16KB plane
      const int row = u >> 3;
      const size_t ga = (m0 + row) * (size_t)lda + k0 + swz;
      const size_t gb = (n0 + row) * (size_t)ldb + k0 + swz;
      gload16(&sAh[0][0] + u * 8, Ah + ga);
      gload16(&sAl[0][0] + u * 8, Al + ga);
      gload16(&sBh[0][0] + u * 8, Bh + gb);
      gload16(&sBl[0][0] + u * 8, Bl + gb);
    }
  };
  auto COMPUTE = [&](f16 (&sAh)[128][64], f16 (&sAl)[128][64],
                     f16 (&sBh)[128][64], f16 (&sBl)[128][64]) {
#pragma unroll
    for (int kk = 0; kk < 2; kk++) {
      f16x8 fah[4], fal[4], fbh[4], fbl[4];
#pragma unroll
      for (int mi = 0; mi < 4; mi++) {
        const int row = wm * 64 + mi * 16 + lr;
        const int c = (((kk * 4 + g) ^ (lr & 7)) << 3);
        fah[mi] = *(const f16x8*)&sAh[row][c];
        fal[mi] = *(const f16x8*)&sAl[row][c];
      }
#pragma unroll
      for (int ni = 0; ni < 4; ni++) {
        const int row = wn * 64 + ni * 16 + lr;
        const int c = (((kk * 4 + g) ^ (lr & 7)) << 3);
        fbh[ni] = *(const f16x8*)&sBh[row][c];
        fbl[ni] = *(const f16x8*)&sBl[row][c];
      }
#pragma unroll
      for (int mi = 0; mi < 4; mi++)
#pragma unroll
        for (int ni = 0; ni < 4; ni++) {
          acc[mi][ni] = MFMA16(fah[mi], fbh[ni], acc[mi][ni]);
          acc[mi][ni] = MFMA16(fah[mi], fbl[ni], acc[mi][ni]);
          acc[mi][ni] = MFMA16(fal[mi], fbh[ni], acc[mi][ni]);
        }
    }
  };
  const int nt = K >> 6;  // 12 or 24, always even
  STAGE(A0h, A0l, B0h, B0l, 0);
  for (int t = 0; t < nt; t += 2) {
    __syncthreads();  // drains stage of buf0 (overlapped with prev COMPUTE)
    if (t + 1 < nt) STAGE(A1h, A1l, B1h, B1l, (t + 1) * 64);
    COMPUTE(A0h, A0l, B0h, B0l);
    __syncthreads();  // drains stage of buf1 (overlapped with COMPUTE above)
    if (t + 2 < nt) STAGE(A0h, A0l, B0h, B0l, (t + 2) * 64);
    COMPUTE(A1h, A1l, B1h, B1l);
  }
#pragma unroll
  for (int ni = 0; ni < 4; ni++) {
    const size_t col = n0 + wn * 64 + ni * 16 + lr;
    const float bv = bias ? bias[col] : 0.0f;
#pragma unroll
    for (int mi = 0; mi < 4; mi++) {
      const size_t rowb = m0 + wm * 64 + mi * 16 + g * 4;
      const f32x4 c = acc[mi][ni];
#pragma unroll
      for (int r = 0; r < 4; r++) {
        const size_t idx = (rowb + r) * (size_t)ldo + col;
        const float v = c[r] + bv;
        if constexpr (MODE == 0) {
          f16 hh, ll;
          split2(v, hh, ll);
          outH[idx] = hh;
          outL[idx] = ll;
        } else if constexpr (MODE == 1) {
          const float tt = v + residF[idx];
          f16 hh, ll;
          split2(tt, hh, ll);
          outH[idx] = hh;
          outL[idx] = ll;
        } else if constexpr (MODE == 2) {
          const float tt = gelu_f(v);
          f16 hh, ll;
          split2(tt, hh, ll);
          outH[idx] = hh;
          outL[idx] = ll;
        } else {
          outF[idx] = addto ? (outF[idx] + v)
                            : ((float)residH[idx] + (float)residL[idx] + v);
        }
      }
    }
  }
}

// ---------------- MoE expert GEMM 1: 2-phase dbuf, XCD-chunked, indirect A ----------------
// 1-D grid 1584 (= 12 x 132). ehid[gr][1536] = gelu_fast(xm[list] . w1t[e] + b1).
__global__ __launch_bounds__(256) void gemm_moe1(
    const f16* __restrict__ xmh, const f16* __restrict__ etw1,
    const float* __restrict__ eb1, const int* __restrict__ lists,
    const int* __restrict__ cnts, const int* __restrict__ starts,
    f16* __restrict__ ehid, int hf) {
  const int per = gridDim.x >> 3;  // 1584/8 = 198
  const int lin = (blockIdx.x & 7) * per + (blockIdx.x >> 3);
  const int bx = lin % 12, by = lin / 12;
  const int m0 = by * 128;
  if (m0 >= starts[4]) return;
  int e = 0;
  while (e < 3 && m0 >= starts[e + 1]) e++;
  const int cnt = cnts[e];
  const int loc0 = m0 - starts[e];
  const int* list = lists + e * 8192;
  const f16* Bw = etw1 + ((size_t)e * 3072 + hf * 1536) * 768;
  const float* bias = eb1 + e * 3072 + hf * 1536;
  __shared__ __align__(16) f16 As0[128][64], Bs0[128][64];
  __shared__ __align__(16) f16 As1[128][64], Bs1[128][64];
  const int tid = threadIdx.x;
  const int lane = tid & 63, wid = tid >> 6;
  const int wm = wid >> 1, wn = wid & 1;
  const int g = lane >> 4, lr = lane & 15;
  const int swz = (((tid & 7) ^ ((tid >> 3) & 7)) << 3);
  const int n0 = bx * 128;
  size_t arow[4];
#pragma unroll
  for (int s = 0; s < 4; s++) {
    const int row = (s * 256 + tid) >> 3;
    const int loc = loc0 + row;
    arow[s] = (size_t)list[loc < cnt ? loc : cnt - 1] * 768;
  }
  f32x4 acc[4][4] = {};
  auto STAGE = [&](f16 (&A)[128][64], f16 (&B)[128][64], int k0) {
#pragma unroll
    for (int s = 0; s < 4; s++) {
      const int u = s * 256 + tid;
      const int row = u >> 3;
      gload16(&A[0][0] + u * 8, xmh + arow[s] + k0 + swz);
      gload16(&B[0][0] + u * 8, Bw + (size_t)(n0 + row) * 768 + k0 + swz);
    }
  };
  auto COMPUTE = [&](f16 (&A)[128][64], f16 (&B)[128][64]) {
#pragma unroll
    for (int kk = 0; kk < 2; kk++) {
      f16x8 fa[4], fb[4];
#pragma unroll
      for (int mi = 0; mi < 4; mi++) {
        const int row = wm * 64 + mi * 16 + lr;
        fa[mi] = *(const f16x8*)&A[row][(((kk * 4 + g) ^ (lr & 7)) << 3)];
      }
#pragma unroll
      for (int ni = 0; ni < 4; ni++) {
        const int row = wn * 64 + ni * 16 + lr;
        fb[ni] = *(const f16x8*)&B[row][(((kk * 4 + g) ^ (lr & 7)) << 3)];
      }
#pragma unroll
      for (int mi = 0; mi < 4; mi++)
#pragma unroll
        for (int ni = 0; ni < 4; ni++)
          acc[mi][ni] = MFMA16(fa[mi], fb[ni], acc[mi][ni]);
    }
  };
  STAGE(As0, Bs0, 0);
#pragma unroll
  for (int t = 0; t < 12; t += 2) {
    __syncthreads();                           // drains prev stage (overlapped)
    if (t + 1 < 12) STAGE(As1, Bs1, (t + 1) * 64);
    COMPUTE(As0, Bs0);
    __syncthreads();
    if (t + 2 < 12) STAGE(As0, Bs0, (t + 2) * 64);
    COMPUTE(As1, Bs1);
  }
#pragma unroll
  for (int ni = 0; ni < 4; ni++) {
    const int col = n0 + wn * 64 + ni * 16 + lr;
    const float bv = bias[col];
#pragma unroll
    for (int mi = 0; mi < 4; mi++) {
      const int gr = m0 + wm * 64 + mi * 16 + g * 4;
      const f32x4 c = acc[mi][ni];
#pragma unroll
      for (int r = 0; r < 4; r++)
        ehid[(size_t)(gr + r) * 1536 + col] = (f16)gelu_fast(c[r] + bv);
    }
  }
}

// ---------------- MoE expert GEMM 2: 2-phase dbuf, XCD-chunked, atomic scatter ----------------
// 1-D grid 792 (= 6 x 132). out[tok] += comb[tok][e]*(ehid . w2t[e] + b2(hf0)).
__global__ __launch_bounds__(256) void gemm_moe2(
    const f16* __restrict__ ehid, const f16* __restrict__ etw2,
    const float* __restrict__ eb2, const float* __restrict__ comb,
    const int* __restrict__ lists, const int* __restrict__ cnts,
    const int* __restrict__ starts, float* __restrict__ outF, int hf) {
  const int per = gridDim.x >> 3;  // 792/8 = 99
  const int lin = (blockIdx.x & 7) * per + (blockIdx.x >> 3);
  const int bx = lin % 6, by = lin / 6;
  const int m0 = by * 128;
  if (m0 >= starts[4]) return;
  int e = 0;
  while (e < 3 && m0 >= starts[e + 1]) e++;
  const int cnt = cnts[e];
  const int st = starts[e];
  const int* list = lists + e * 8192;
  const f16* Bw = etw2 + (size_t)e * 768 * 3072 + hf * 1536;
  __shared__ __align__(16) f16 As0[128][64], Bs0[128][64];
  __shared__ __align__(16) f16 As1[128][64], Bs1[128][64];
  const int tid = threadIdx.x;
  const int lane = tid & 63, wid = tid >> 6;
  const int wm = wid >> 1, wn = wid & 1;
  const int g = lane >> 4, lr = lane & 15;
  const int swz = (((tid & 7) ^ ((tid >> 3) & 7)) << 3);
  const int n0 = bx * 128;
  f32x4 acc[4][4] = {};
  auto STAGE = [&](f16 (&A)[128][64], f16 (&B)[128][64], int k0) {
#pragma unroll
    for (int s = 0; s < 4; s++) {
      const int u = s * 256 + tid;
      const int row = u >> 3;
      gload16(&A[0][0] + u * 8, ehid + (size_t)(m0 + row) * 1536 + k0 + swz);
      gload16(&B[0][0] + u * 8, Bw + (size_t)(n0 + row) * 3072 + k0 + swz);
    }
  };
  auto COMPUTE = [&](f16 (&A)[128][64], f16 (&B)[128][64]) {
#pragma unroll
    for (int kk = 0; kk < 2; kk++) {
      f16x8 fa[4], fb[4];
#pragma unroll
      for (int mi = 0; mi < 4; mi++) {
        const int row = wm * 64 + mi * 16 + lr;
        fa[mi] = *(const f16x8*)&A[row][(((kk * 4 + g) ^ (lr & 7)) << 3)];
      }
#pragma unroll
      for (int ni = 0; ni < 4; ni++) {
        const int row = wn * 64 + ni * 16 + lr;
        fb[ni] = *(const f16x8*)&B[row][(((kk * 4 + g) ^ (lr & 7)) << 3)];
      }
#pragma unroll
      for (int mi = 0; mi < 4; mi++)
#pragma unroll
        for (int ni = 0; ni < 4; ni++)
          acc[mi][ni] = MFMA16(fa[mi], fb[ni], acc[mi][ni]);
    }
  };
  STAGE(As0, Bs0, 0);
#pragma unroll
  for (int t = 0; t < 24; t += 2) {
    __syncthreads();                           // drains prev stage (overlapped)
    if (t + 1 < 24) STAGE(As1, Bs1, (t + 1) * 64);
    COMPUTE(As0, Bs0);
    __syncthreads();
    if (t + 2 < 24) STAGE(As0, Bs0, (t + 2) * 64);
    COMPUTE(As1, Bs1);
  }
#pragma unroll
  for (int ni = 0; ni < 4; ni++) {
    const int col = n0 + wn * 64 + ni * 16 + lr;
    const float bv = hf ? 0.0f : eb2[e * 768 + col];
#pragma unroll
    for (int mi = 0; mi < 4; mi++) {
      const int gr = m0 + wm * 64 + mi * 16 + g * 4;
      const f32x4 c = acc[mi][ni];
#pragma unroll
      for (int r = 0; r < 4; r++) {
        const int loc = gr + r - st;
        if (loc < cnt) {
          const int tok = list[loc];
          const float w = comb[(size_t)tok * 4 + e];
          unsafeAtomicAdd(&outF[(size_t)tok * 768 + col], w * (c[r] + bv));
        }
      }
    }
  }
}

// ---------------- flash attention, split-fp16 3-term, KVBLK=64 ----------------
// 1536 blocks, XCD-swizzled. R8: no-max softmax P=exp(s/8) (bounded: std(s)
// ~0.31, f16 overflow needs s>11 = 35 sigma); row-sum via MFMA x ones.
__global__ __launch_bounds__(256) void attn_kernel(
    const f16* __restrict__ qh, const f16* __restrict__ ql,
    const f16* __restrict__ vth, const f16* __restrict__ vtl,
    f16* __restrict__ ch, f16* __restrict__ cl) {
  const int wg = blockIdx.y * 16 + blockIdx.x;          // 0..1535
  const int nid = (wg & 7) * 192 + (wg >> 3);           // bijective (1536%8==0)
  const int qt = nid & 15, bh = nid >> 4;
  const int b = bh / 12, h = bh % 12;
  const int tid = threadIdx.x;
  const int lane = tid & 63, w = tid >> 6;
  const int g = lane >> 4, lr = lane & 15;
  __shared__ __align__(16) f16 Ksh[64][64];
  __shared__ __align__(16) f16 Ksl[64][64];
  __shared__ __align__(16) f16 Vsh[64][64];
  __shared__ __align__(16) f16 Vsl[64][64];
  __shared__ __align__(16) char Psh[4][2048];  // per-wave P (16 x 64 f16), XOR-swizzled
  __shared__ __align__(16) char Psl[4][2048];
  const int swz = (((tid & 7) ^ ((tid >> 3) & 7)) << 3);
  const size_t qrow = (size_t)b * 1024 + qt * 64 + w * 16 + lr;
  const f16* qbh = qh + qrow * 2304 + h * 64;
  const f16* qbl = ql + qrow * 2304 + h * 64;
  const f16x8 qfh0 = *(const f16x8*)(qbh + g * 8);
  const f16x8 qfh1 = *(const f16x8*)(qbh + 32 + g * 8);
  const f16x8 qfl0 = *(const f16x8*)(qbl + g * 8);
  const f16x8 qfl1 = *(const f16x8*)(qbl + 32 + g * 8);
  const f16x8 ones = {(f16)1, (f16)1, (f16)1, (f16)1, (f16)1, (f16)1, (f16)1, (f16)1};
  f32x4 o[4] = {};
  f32x4 osum = {};
  const f16* kbh = qh + ((size_t)b * 1024) * 2304 + 768 + h * 64;
  const f16* kbl = ql + ((size_t)b * 1024) * 2304 + 768 + h * 64;
  const f16* vbh = vth + (size_t)bh * 64 * 1024;
  const f16* vbl = vtl + (size_t)bh * 64 * 1024;
  char* pbh = Psh[w];
  char* pbl = Psl[w];
  for (int kv0 = 0; kv0 < 1024; kv0 += 64) {
    __syncthreads();
#pragma unroll
    for (int s = 0; s < 2; s++) {
      const int u = s * 256 + tid;  // 16B unit within an 8KB plane
      const int row = u >> 3;
      const size_t ko = (size_t)(kv0 + row) * 2304 + swz;
      gload16(&Ksh[0][0] + u * 8, kbh + ko);
      gload16(&Ksl[0][0] + u * 8, kbl + ko);
      const size_t vo = (size_t)row * 1024 + kv0 + swz;  // row = d
      gload16(&Vsh[0][0] + u * 8, vbh + vo);
      gload16(&Vsl[0][0] + u * 8, vbl + vo);
    }
    __syncthreads();
    f32x4 s[4];
    __builtin_amdgcn_s_setprio(1);
#pragma unroll
    for (int nb = 0; nb < 4; nb++) {
      const int row = nb * 16 + lr;
      const int c0 = ((g ^ (lr & 7)) << 3);
      const int c1 = (((4 + g) ^ (lr & 7)) << 3);
      const f16x8 kh0 = *(const f16x8*)&Ksh[row][c0];
      const f16x8 kh1 = *(const f16x8*)&Ksh[row][c1];
      const f16x8 kl0 = *(const f16x8*)&Ksl[row][c0];
      const f16x8 kl1 = *(const f16x8*)&Ksl[row][c1];
      f32x4 t = {};
      t = MFMA16(qfh0, kh0, t);
      t = MFMA16(qfh1, kh1, t);
      t = MFMA16(qfh0, kl0, t);
      t = MFMA16(qfh1, kl1, t);
      t = MFMA16(qfl0, kh0, t);
      t = MFMA16(qfl1, kh1, t);
      s[nb] = t;
    }
    __builtin_amdgcn_s_setprio(0);
    // P = exp(s/8), no max subtraction (shift-invariant; overflow at 35 sigma)
    // -> LDS (swizzled) as split fp16
#pragma unroll
    for (int nb = 0; nb < 4; nb++)
#pragma unroll
      for (int r = 0; r < 4; r++) {
        const int row = g * 4 + r;
        const int sw = ((nb * 16 + lr) * 2) ^ ((row & 7) << 4);
        const float p = __expf(s[nb][r] * 0.125f);
        f16 hh, ll;
        split2(p, hh, ll);
        *(f16*)(pbh + row * 128 + sw) = hh;
        *(f16*)(pbl + row * 128 + sw) = ll;
      }
    // PV + row-sum via MFMA x ones
    __builtin_amdgcn_s_setprio(1);
#pragma unroll
    for (int ks = 0; ks < 2; ks++) {
      const int pc = (ks * 64 + g * 16) ^ ((lr & 7) << 4);
      const f16x8 pfh = *(const f16x8*)(pbh + lr * 128 + pc);
      const f16x8 pfl = *(const f16x8*)(pbl + lr * 128 + pc);
      osum = MFMA16(pfh, ones, osum);
      osum = MFMA16(pfl, ones, osum);
#pragma unroll
      for (int db = 0; db < 4; db++) {
        const int vrow = db * 16 + lr;
        const int vc = (((ks * 4 + g) ^ (lr & 7)) << 3);
        const f16x8 vfh = *(const f16x8*)&Vsh[vrow][vc];
        const f16x8 vfl = *(const f16x8*)&Vsl[vrow][vc];
        o[db] = MFMA16(pfh, vfh, o[db]);
        o[db] = MFMA16(pfh, vfl, o[db]);
        o[db] = MFMA16(pfl, vfh, o[db]);
      }
    }
    __builtin_amdgcn_s_setprio(0);
  }
  const size_t orow = (size_t)b * 1024 + qt * 64 + w * 16 + g * 4;
#pragma unroll
  for (int r = 0; r < 4; r++) {
    const float inv = 1.0f / osum[r];
#pragma unroll
    for (int db = 0; db < 4; db++) {
      const float val = o[db][r] * inv;
      const size_t oi = (orow + r) * 768 + h * 64 + db * 16 + lr;
      f16 hh, ll;
      split2(val, hh, ll);
      ch[oi] = hh;
      cl[oi] = ll;
    }
  }
}

// ---------------- gate: fp32 logits from split xm, top-2, softmax -> comb[T][4] ----------------
__global__ __launch_bounds__(256) void gate_kernel(
    const f16* __restrict__ xmh, const f16* __restrict__ xml,
    const float* __restrict__ gw, const float* __restrict__ gb,
    float* __restrict__ comb) {
  const int t = blockIdx.x * 256 + threadIdx.x;
  const f16* xrh = xmh + (size_t)t * 768;
  const f16* xrl = xml + (size_t)t * 768;
  float a0 = 0, a1 = 0, a2 = 0, a3 = 0;
  for (int k = 0; k < 768; k += 4) {
    const f16x4 xh = *(const f16x4*)(xrh + k);
    const f16x4 xl = *(const f16x4*)(xrl + k);
    const f32x4 w0 = *(const f32x4*)(gw + k);
    const f32x4 w1 = *(const f32x4*)(gw + 768 + k);
    const f32x4 w2 = *(const f32x4*)(gw + 1536 + k);
    const f32x4 w3 = *(const f32x4*)(gw + 2304 + k);
#pragma unroll
    for (int j = 0; j < 4; j++) {
      const float xv = (float)xh[j] + (float)xl[j];
      a0 += xv * w0[j];
      a1 += xv * w1[j];
      a2 += xv * w2[j];
      a3 += xv * w3[j];
    }
  }
  float l[4] = {a0 + gb[0], a1 + gb[1], a2 + gb[2], a3 + gb[3]};
  int i0 = 0;
#pragma unroll
  for (int e = 1; e < 4; e++)
    if (l[e] > l[i0]) i0 = e;  // strict > matches top_k tie order
  int i1 = -1;
#pragma unroll
  for (int e = 0; e < 4; e++)
    if (e != i0 && (i1 < 0 || l[e] > l[i1])) i1 = e;
  const float e1 = expf(l[i1] - l[i0]);
  const float inv = 1.0f / (1.0f + e1);
  float c[4] = {0.0f, 0.0f, 0.0f, 0.0f};
  c[i0] = inv;
  c[i1] = e1 * inv;
  f32x4 cv = {c[0], c[1], c[2], c[3]};
  *(f32x4*)(comb + (size_t)t * 4) = cv;
}

// ---------------- per-expert token lists + 128-aligned segment starts ----------------
__global__ __launch_bounds__(1024) void listbuild_kernel(
    const float* __restrict__ comb, int* __restrict__ lists /*[4][8192]*/,
    int* __restrict__ cnts /*[4]*/, int* __restrict__ starts /*[5]*/) {
  __shared__ int wsum[16];
  const int tid = threadIdx.x;
  const int lane = tid & 63, wv = tid >> 6;
  for (int e = 0; e < 4; e++) {
    int base = 0;
    for (int c = 0; c < 8; c++) {
      const int t = c * 1024 + tid;
      const int flag = comb[(size_t)t * 4 + e] > 0.0f ? 1 : 0;
      const unsigned long long mask = __ballot(flag);
      const int myrank = __popcll(mask & ((1ull << lane) - 1ull));
      if (lane == 0) wsum[wv] = __popcll(mask);
      __syncthreads();
      int wbase = 0, total = 0;
#pragma unroll
      for (int i = 0; i < 16; i++) {
        if (i < wv) wbase += wsum[i];
        total += wsum[i];
      }
      if (flag) lists[e * 8192 + base + wbase + myrank] = t;
      base += total;
      __syncthreads();
    }
    if (tid == 0) cnts[e] = base;
  }
  if (tid == 0) {
    int s = 0;
    starts[0] = 0;
#pragma unroll
    for (int e = 0; e < 4; e++) {
      s += (cnts[e] + 127) & ~127;
      starts[e + 1] = s;
    }
  }
}

extern "C" void kernel_launch(void* const* d_in, const int* in_sizes, int n_in,
                              void* d_out, int out_size, void* d_ws,
                              size_t ws_size, hipStream_t stream) {
  const float* x = (const float*)d_in[0];
  const float* ln1g = (const float*)d_in[1];
  const float* ln1b = (const float*)d_in[2];
  const float* in_w = (const float*)d_in[3];
  const float* in_b = (const float*)d_in[4];
  const float* out_w = (const float*)d_in[5];
  const float* out_b = (const float*)d_in[6];
  const float* mlp_w1 = (const float*)d_in[7];
  const float* mlp_b1 = (const float*)d_in[8];
  const float* mlp_w2 = (const float*)d_in[9];
  const float* mlp_b2 = (const float*)d_in[10];
  const float* ln2g = (const float*)d_in[11];
  const float* ln2b = (const float*)d_in[12];
  const float* gate_w = (const float*)d_in[13];
  const float* gate_b = (const float*)d_in[14];
  const float* exp_w1 = (const float*)d_in[15];
  const float* exp_b1 = (const float*)d_in[16];
  const float* exp_w2 = (const float*)d_in[17];
  const float* exp_b2 = (const float*)d_in[18];
  float* out = (float*)d_out;
  (void)in_sizes; (void)n_in; (void)out_size;

  const size_t MB = 1ull << 20;
  if (ws_size < 130 * MB) return;  // clean absmax failure (not a crash) if ws too small
  char* ws = (char*)d_ws;
  // Region layout (lifetimes hand-verified):
  // S1 [0,24MB):   h planes -> attn ctx planes -> w1t planes -> xm planes
  // S2 [24,33MB):  in_w+out_w planes -> w2t planes
  // S3 [33,105MB): qkv planes -> mlp hid planes -> {ehid 52, etw1 18}
  // S4 [105,129MB): vt planes -> x1 planes -> etw2 18
  // S5 [129MB..):  comb, lists, cnts, starts
  char* S1 = ws;
  char* S2 = ws + 24 * MB;
  char* S3 = ws + 33 * MB;
  char* S4 = ws + 105 * MB;
  char* S5 = ws + 129 * MB;

  f16* h_h = (f16*)S1;                       // 12,582,912 B each
  f16* h_l = (f16*)(S1 + 12 * MB);
  f16* ctx_h = (f16*)S1;                     // after qkv gemm, h dead
  f16* ctx_l = (f16*)(S1 + 12 * MB);
  f16* w1t_h = (f16*)S1;                     // after out-proj, ctx dead
  f16* w1t_l = (f16*)(S1 + 4718592);
  f16* xmh = (f16*)S1;                       // after mlp, w1t dead
  f16* xml = (f16*)(S1 + 12 * MB);

  f16* inw_h = (f16*)S2;                     // 3,538,944 B each
  f16* inw_l = (f16*)(S2 + 3538944);
  f16* outw_h = (f16*)(S2 + 7077888);        // 1,179,648 B each
  f16* outw_l = (f16*)(S2 + 8257536);
  f16* w2t_h = (f16*)S2;                     // after out-proj, inw/outw dead
  f16* w2t_l = (f16*)(S2 + 4718592);

  f16* qkv_h = (f16*)S3;                     // 37,748,736 B each
  f16* qkv_l = (f16*)(S3 + 36 * MB);
  f16* hid_h = (f16*)S3;                     // after attn, qkv dead; [8192][1536] each
  f16* hid_l = (f16*)(S3 + 24 * MB);
  f16* ehid = (f16*)S3;                      // after mlp: [16896][1536] f16 = 51.9MB
  f16* etw1 = (f16*)(S3 + 52 * MB);          // [4][3072][768] f16 = 18MB

  f16* vt_h = (f16*)S4;                      // 12,582,912 B each
  f16* vt_l = (f16*)(S4 + 12 * MB);
  f16* x1h = (f16*)S4;                       // after attn, vt dead
  f16* x1l = (f16*)(S4 + 12 * MB);
  f16* etw2 = (f16*)S4;                      // after mlp: [4][768][3072] f16 = 18MB

  float* comb = (float*)S5;                  // 131,072 B
  int* lists = (int*)(S5 + 131072);          // 4 x 8192 ints
  int* cnts = (int*)(S5 + 262144);           // 4 ints
  int* starts = (int*)(S5 + 262144 + 64);    // 5 ints

  // ---- attention ----
  convert_split_k<<<dim3(1728), dim3(256), 0, stream>>>(in_w, inw_h, inw_l, 442368);
  convert_split_k<<<dim3(576), dim3(256), 0, stream>>>(out_w, outw_h, outw_l, 147456);
  ln_kernel<<<dim3(2048), dim3(256), 0, stream>>>(x, ln1g, ln1b, h_h, h_l);
  gemm_split<0><<<dim3(18, 64), dim3(256), 0, stream>>>(
      h_h, h_l, 768, inw_h, inw_l, 768, in_b, nullptr, nullptr, nullptr, 0,
      nullptr, qkv_h, qkv_l, 2304, 768);
  vtrans_kernel<<<dim3(16, 96, 2), dim3(256), 0, stream>>>(
      (const ushort*)qkv_h, (const ushort*)qkv_l, (ushort*)vt_h, (ushort*)vt_l);
  attn_kernel<<<dim3(16, 96), dim3(256), 0, stream>>>(qkv_h, qkv_l, vt_h, vt_l, ctx_h, ctx_l);
  gemm_split<1><<<dim3(6, 64), dim3(256), 0, stream>>>(
      ctx_h, ctx_l, 768, outw_h, outw_l, 768, out_b, x, nullptr, nullptr, 0,
      nullptr, x1h, x1l, 768, 768);

  // ---- MLP (hidden in two halves of 1536; result -> out (=x2, fp32)) ----
  transpose_k<<<dim3(96, 24), dim3(256), 0, stream>>>(mlp_w1, w1t_h, w1t_l, 768, 3072);
  transpose_k<<<dim3(24, 96), dim3(256), 0, stream>>>(mlp_w2, w2t_h, w2t_l, 3072, 768);
  gemm_split<2><<<dim3(12, 64), dim3(256), 0, stream>>>(
      x1h, x1l, 768, w1t_h, w1t_l, 768, mlp_b1, nullptr, nullptr, nullptr, 0,
      nullptr, hid_h, hid_l, 1536, 768);
  gemm_split<3><<<dim3(6, 64), dim3(256), 0, stream>>>(
      hid_h, hid_l, 1536, w2t_h, w2t_l, 3072, mlp_b2, nullptr, x1h, x1l, 0,
      out, nullptr, nullptr, 768, 1536);
  gemm_split<2><<<dim3(12, 64), dim3(256), 0, stream>>>(
      x1h, x1l, 768, w1t_h + (size_t)1536 * 768, w1t_l + (size_t)1536 * 768, 768,
      mlp_b1 + 1536, nullptr, nullptr, nullptr, 0, nullptr, hid_h, hid_l, 1536, 768);
  gemm_split<3><<<dim3(6, 64), dim3(256), 0, stream>>>(
      hid_h, hid_l, 1536, w2t_h + 1536, w2t_l + 1536, 3072,
      nullptr, nullptr, nullptr, nullptr, 1, out, nullptr, nullptr, 768, 1536);

  // ---- MoE (sparse top-2, segment-mapped, dbuf + XCD-chunked) ----
  ln_kernel<<<dim3(2048), dim3(256), 0, stream>>>(out, ln2g, ln2b, xmh, xml);
  gate_kernel<<<dim3(32), dim3(256), 0, stream>>>(xmh, xml, gate_w, gate_b, comb);
  listbuild_kernel<<<dim3(1), dim3(1024), 0, stream>>>(comb, lists, cnts, starts);
  etrans_kernel<<<dim3(96, 24, 4), dim3(256), 0, stream>>>(exp_w1, etw1, 768, 3072);
  etrans_kernel<<<dim3(24, 96, 4), dim3(256), 0, stream>>>(exp_w2, etw2, 3072, 768);
  for (int hf = 0; hf < 2; hf++) {
    gemm_moe1<<<dim3(1584), dim3(256), 0, stream>>>(
        xmh, etw1, exp_b1, lists, cnts, starts, ehid, hf);
    gemm_moe2<<<dim3(792), dim3(256), 0, stream>>>(
        ehid, etw2, exp_b2, comb, lists, cnts, starts, out, hf);
  }
}

// Round 9
// 1014.408 us; speedup vs baseline: 1.1529x; 1.1529x over previous
//
#include <hip/hip_runtime.h>

// TransformerBlock (attn + MLP + top2-MoE) on MI355X.
// Pre-gate chain in split-fp16 3-term MFMA (fp32-class accuracy so the MoE
// top-2 selection matches the fp32 reference); post-gate experts in plain
// fp16 MFMA, SPARSE top-2 dispatch.
// R9: revert gemm_split to R7 single-buffer (R8's 128KB dbuf -> 1 block/CU
// regressed); keep R8 no-max attn; moe2 scatter made ATOMIC-FREE via packed
// f16 eout + inverse map (posA/posB) + final combine kernel.

typedef _Float16 f16;
typedef _Float16 f16x4 __attribute__((ext_vector_type(4)));
typedef _Float16 f16x8 __attribute__((ext_vector_type(8)));
typedef float f32x4 __attribute__((ext_vector_type(4)));
typedef unsigned short ushort;

#define MFMA16(a, b, c) __builtin_amdgcn_mfma_f32_16x16x32_f16((a), (b), (c), 0, 0, 0)

__device__ __forceinline__ void gload16(void* lds, const void* g) {
  __builtin_amdgcn_global_load_lds(
      (const __attribute__((address_space(1))) unsigned int*)g,
      (__attribute__((address_space(3))) unsigned int*)lds, 16, 0, 0);
}

__device__ __forceinline__ void split2(float t, f16& h, f16& l) {
  h = (f16)t;
  l = (f16)(t - (float)h);
}

__device__ __forceinline__ float gelu_f(float x) {  // exact (pre-gate path)
  return 0.5f * x * (1.0f + erff(x * 0.70710678118654752f));
}

__device__ __forceinline__ float gelu_fast(float x) {  // tanh-approx (post-gate experts)
  return x / (1.0f + __expf(-1.5957691216f * (x + 0.044715f * x * x * x)));
}

// ---------------- LayerNorm: one wave per row of 768; split-fp16 planes out ----------------
__global__ __launch_bounds__(256) void ln_kernel(
    const float* __restrict__ x, const float* __restrict__ gam,
    const float* __restrict__ bet, f16* __restrict__ oh, f16* __restrict__ ol) {
  const int w = threadIdx.x >> 6, lane = threadIdx.x & 63;
  const size_t row = (size_t)blockIdx.x * 4 + w;
  const float* xr = x + row * 768;
  f32x4 v[3];
  float s = 0.0f;
#pragma unroll
  for (int c = 0; c < 3; c++) {
    v[c] = *(const f32x4*)(xr + c * 256 + lane * 4);
    s += v[c][0] + v[c][1] + v[c][2] + v[c][3];
  }
#pragma unroll
  for (int off = 32; off; off >>= 1) s += __shfl_xor(s, off);
  const float mean = s * (1.0f / 768.0f);
  float q = 0.0f;
#pragma unroll
  for (int c = 0; c < 3; c++)
#pragma unroll
    for (int j = 0; j < 4; j++) {
      float d = v[c][j] - mean;
      q += d * d;
    }
#pragma unroll
  for (int off = 32; off; off >>= 1) q += __shfl_xor(q, off);
  // precise rsqrt: rsqrtf() approx (~1e-5 rel) would risk gate flips downstream
  const float rstd = 1.0f / sqrtf(q * (1.0f / 768.0f) + 1e-5f);
#pragma unroll
  for (int c = 0; c < 3; c++) {
    const int col = c * 256 + lane * 4;
    f32x4 gv = *(const f32x4*)(gam + col);
    f32x4 bv = *(const f32x4*)(bet + col);
    f16x4 yh, yl;
#pragma unroll
    for (int j = 0; j < 4; j++) {
      float y = (v[c][j] - mean) * rstd * gv[j] + bv[j];
      f16 hh, ll;
      split2(y, hh, ll);
      yh[j] = hh;
      yl[j] = ll;
    }
    *(f16x4*)(oh + row * 768 + col) = yh;
    *(f16x4*)(ol + row * 768 + col) = yl;
  }
}

// ---------------- fp32 -> split fp16 (elementwise, x4) ----------------
__global__ __launch_bounds__(256) void convert_split_k(
    const float* __restrict__ in, f16* __restrict__ oh, f16* __restrict__ ol,
    int n4) {
  const int i = blockIdx.x * 256 + threadIdx.x;
  if (i >= n4) return;
  f32x4 v = ((const f32x4*)in)[i];
  f16x4 h, l;
#pragma unroll
  for (int j = 0; j < 4; j++) {
    f16 hh, ll;
    split2(v[j], hh, ll);
    h[j] = hh;
    l[j] = ll;
  }
  ((f16x4*)oh)[i] = h;
  ((f16x4*)ol)[i] = l;
}

// ---------------- fp32 [R][ldin] (32x32 tiles) -> fp16 [C][R] split ----------------
__global__ __launch_bounds__(256) void transpose_k(
    const float* __restrict__ in, f16* __restrict__ oh, f16* __restrict__ ol,
    int R, int ldin) {
  __shared__ float t[32][33];
  const int tx = threadIdx.x & 31, ty = threadIdx.x >> 5;
  const int r0 = blockIdx.y * 32, c0 = blockIdx.x * 32;
#pragma unroll
  for (int i = 0; i < 4; i++)
    t[ty + 8 * i][tx] = in[(size_t)(r0 + ty + 8 * i) * ldin + c0 + tx];
  __syncthreads();
#pragma unroll
  for (int i = 0; i < 4; i++) {
    const float val = t[tx][ty + 8 * i];
    const size_t o = (size_t)(c0 + ty + 8 * i) * R + r0 + tx;
    f16 hh, ll;
    split2(val, hh, ll);
    oh[o] = hh;
    ol[o] = ll;
  }
}

// ---------------- per-expert fp32 [R][C] -> f16 [C][R] (blockIdx.z = expert) ----------------
__global__ __launch_bounds__(256) void etrans_kernel(
    const float* __restrict__ in0, f16* __restrict__ out0, int R, int C) {
  const size_t eoff = (size_t)blockIdx.z * R * C;
  const float* in = in0 + eoff;
  f16* out = out0 + eoff;
  __shared__ float t[32][33];
  const int tx = threadIdx.x & 31, ty = threadIdx.x >> 5;
  const int r0 = blockIdx.y * 32, c0 = blockIdx.x * 32;
#pragma unroll
  for (int i = 0; i < 4; i++)
    t[ty + 8 * i][tx] = in[(size_t)(r0 + ty + 8 * i) * C + c0 + tx];
  __syncthreads();
#pragma unroll
  for (int i = 0; i < 4; i++)
    out[(size_t)(c0 + ty + 8 * i) * R + r0 + tx] = (f16)t[tx][ty + 8 * i];
}

// ---------------- V transpose: qkv planes (v part) -> [B,H,64,1024]; z = hi/lo ----------------
__global__ __launch_bounds__(256) void vtrans_kernel(
    const ushort* __restrict__ srcH, const ushort* __restrict__ srcL,
    ushort* __restrict__ dstH, ushort* __restrict__ dstL) {
  const int nt = blockIdx.x, bh = blockIdx.y;
  const ushort* src = blockIdx.z ? srcL : srcH;
  ushort* dst = blockIdx.z ? dstL : dstH;
  const int b = bh / 12, h = bh % 12;
  __shared__ ushort t[64][65];
  const int tid = threadIdx.x;
#pragma unroll
  for (int i = 0; i < 16; i++) {
    const int idx = i * 256 + tid;
    const int r = idx >> 6, c = idx & 63;
    t[r][c] = src[((size_t)b * 1024 + nt * 64 + r) * 2304 + 1536 + h * 64 + c];
  }
  __syncthreads();
#pragma unroll
  for (int i = 0; i < 16; i++) {
    const int idx = i * 256 + tid;
    const int d = idx >> 6, n = idx & 63;
    dst[((size_t)bh * 64 + d) * 1024 + nt * 64 + n] = t[n][d];
  }
}

// ---------------- split-fp16 3-term GEMM: C = A·B^T (+bias), A[M,K] B[N,K] ----------------
// 128x128 tile, BK=64, 4 waves (2x2). Row-major LDS [128][64]f16 (=128B rows),
// XOR chunk-swizzle; staging: lane L -> row L>>3, global chunk (L&7)^((L>>3)&7).
// Single-buffered 64KB LDS (2 blocks/CU): R8's 128KB dbuf regressed (1 block/CU).
template <int MODE>
__global__ __launch_bounds__(256) void gemm_split(
    const f16* __restrict__ Ah, const f16* __restrict__ Al, int lda,
    const f16* __restrict__ Bh, const f16* __restrict__ Bl, int ldb,
    const float* __restrict__ bias, const float* __restrict__ residF,
    const f16* __restrict__ residH, const f16* __restrict__ residL, int addto,
    float* __restrict__ outF, f16* __restrict__ outH, f16* __restrict__ outL,
    int ldo, int K) {
  __shared__ __align__(16) f16 Ash[128][64];
  __shared__ __align__(16) f16 Asl[128][64];
  __shared__ __align__(16) f16 Bsh[128][64];
  __shared__ __align__(16) f16 Bsl[128][64];
  const int tid = threadIdx.x;
  const int lane = tid & 63, wid = tid >> 6;
  const int wm = wid >> 1, wn = wid & 1;
  const int g = lane >> 4, lr = lane & 15;
  const int swz = (((tid & 7) ^ ((tid >> 3) & 7)) << 3);  // element offset
  const size_t m0 = (size_t)blockIdx.y * 128, n0 = (size_t)blockIdx.x * 128;
  f32x4 acc[4][4] = {};
  for (int k0 = 0; k0 < K; k0 += 64) {
    __syncthreads();
#pragma unroll
    for (int s = 0; s < 4; s++) {
      const int u = s * 256 + tid;  // 16B unit within a 16KB plane
      const int row = u >> 3;
      const size_t ga = (m0 + row) * (size_t)lda + k0 + swz;
      const size_t gb = (n0 + row) * (size_t)ldb + k0 + swz;
      gload16(&Ash[0][0] + u * 8, Ah + ga);
      gload16(&Asl[0][0] + u * 8, Al + ga);
      gload16(&Bsh[0][0] + u * 8, Bh + gb);
      gload16(&Bsl[0][0] + u * 8, Bl + gb);
    }
    __syncthreads();
#pragma unroll
    for (int kk = 0; kk < 2; kk++) {
      f16x8 fah[4], fal[4], fbh[4], fbl[4];
#pragma unroll
      for (int mi = 0; mi < 4; mi++) {
        const int row = wm * 64 + mi * 16 + lr;
        const int c = (((kk * 4 + g) ^ (lr & 7)) << 3);
        fah[mi] = *(const f16x8*)&Ash[row][c];
        fal[mi] = *(const f16x8*)&Asl[row][c];
      }
#pragma unroll
      for (int ni = 0; ni < 4; ni++) {
        const int row = wn * 64 + ni * 16 + lr;
        const int c = (((kk * 4 + g) ^ (lr & 7)) << 3);
        fbh[ni] = *(const f16x8*)&Bsh[row][c];
        fbl[ni] = *(const f16x8*)&Bsl[row][c];
      }
#pragma unroll
      for (int mi = 0; mi < 4; mi++)
#pragma unroll
        for (int ni = 0; ni < 4; ni++) {
          acc[mi][ni] = MFMA16(fah[mi], fbh[ni], acc[mi][ni]);
          acc[mi][ni] = MFMA16(fah[mi], fbl[ni], acc[mi][ni]);
          acc[mi][ni] = MFMA16(fal[mi], fbh[ni], acc[mi][ni]);
        }
    }
  }
#pragma unroll
  for (int ni = 0; ni < 4; ni++) {
    const size_t col = n0 + wn * 64 + ni * 16 + lr;
    const float bv = bias ? bias[col] : 0.0f;
#pragma unroll
    for (int mi = 0; mi < 4; mi++) {
      const size_t rowb = m0 + wm * 64 + mi * 16 + g * 4;
      const f32x4 c = acc[mi][ni];
#pragma unroll
      for (int r = 0; r < 4; r++) {
        const size_t idx = (rowb + r) * (size_t)ldo + col;
        const float v = c[r] + bv;
        if constexpr (MODE == 0) {
          f16 hh, ll;
          split2(v, hh, ll);
          outH[idx] = hh;
          outL[idx] = ll;
        } else if constexpr (MODE == 1) {
          const float tt = v + residF[idx];
          f16 hh, ll;
          split2(tt, hh, ll);
          outH[idx] = hh;
          outL[idx] = ll;
        } else if constexpr (MODE == 2) {
          const float tt = gelu_f(v);
          f16 hh, ll;
          split2(tt, hh, ll);
          outH[idx] = hh;
          outL[idx] = ll;
        } else {
          outF[idx] = addto ? (outF[idx] + v)
                            : ((float)residH[idx] + (float)residL[idx] + v);
        }
      }
    }
  }
}

// ---------------- MoE expert GEMM 1: 2-phase dbuf, XCD-chunked, indirect A ----------------
// 1-D grid 1584 (= 12 x 132). ehid[gr][1536] = gelu_fast(xm[list] . w1t[e] + b1).
__global__ __launch_bounds__(256) void gemm_moe1(
    const f16* __restrict__ xmh, const f16* __restrict__ etw1,
    const float* __restrict__ eb1, const int* __restrict__ lists,
    const int* __restrict__ cnts, const int* __restrict__ starts,
    f16* __restrict__ ehid, int hf) {
  const int per = gridDim.x >> 3;  // 1584/8 = 198
  const int lin = (blockIdx.x & 7) * per + (blockIdx.x >> 3);
  const int bx = lin % 12, by = lin / 12;
  const int m0 = by * 128;
  if (m0 >= starts[4]) return;
  int e = 0;
  while (e < 3 && m0 >= starts[e + 1]) e++;
  const int cnt = cnts[e];
  const int loc0 = m0 - starts[e];
  const int* list = lists + e * 8192;
  const f16* Bw = etw1 + ((size_t)e * 3072 + hf * 1536) * 768;
  const float* bias = eb1 + e * 3072 + hf * 1536;
  __shared__ __align__(16) f16 As0[128][64], Bs0[128][64];
  __shared__ __align__(16) f16 As1[128][64], Bs1[128][64];
  const int tid = threadIdx.x;
  const int lane = tid & 63, wid = tid >> 6;
  const int wm = wid >> 1, wn = wid & 1;
  const int g = lane >> 4, lr = lane & 15;
  const int swz = (((tid & 7) ^ ((tid >> 3) & 7)) << 3);
  const int n0 = bx * 128;
  size_t arow[4];
#pragma unroll
  for (int s = 0; s < 4; s++) {
    const int row = (s * 256 + tid) >> 3;
    const int loc = loc0 + row;
    arow[s] = (size_t)list[loc < cnt ? loc : cnt - 1] * 768;
  }
  f32x4 acc[4][4] = {};
  auto STAGE = [&](f16 (&A)[128][64], f16 (&B)[128][64], int k0) {
#pragma unroll
    for (int s = 0; s < 4; s++) {
      const int u = s * 256 + tid;
      const int row = u >> 3;
      gload16(&A[0][0] + u * 8, xmh + arow[s] + k0 + swz);
      gload16(&B[0][0] + u * 8, Bw + (size_t)(n0 + row) * 768 + k0 + swz);
    }
  };
  auto COMPUTE = [&](f16 (&A)[128][64], f16 (&B)[128][64]) {
#pragma unroll
    for (int kk = 0; kk < 2; kk++) {
      f16x8 fa[4], fb[4];
#pragma unroll
      for (int mi = 0; mi < 4; mi++) {
        const int row = wm * 64 + mi * 16 + lr;
        fa[mi] = *(const f16x8*)&A[row][(((kk * 4 + g) ^ (lr & 7)) << 3)];
      }
#pragma unroll
      for (int ni = 0; ni < 4; ni++) {
        const int row = wn * 64 + ni * 16 + lr;
        fb[ni] = *(const f16x8*)&B[row][(((kk * 4 + g) ^ (lr & 7)) << 3)];
      }
#pragma unroll
      for (int mi = 0; mi < 4; mi++)
#pragma unroll
        for (int ni = 0; ni < 4; ni++)
          acc[mi][ni] = MFMA16(fa[mi], fb[ni], acc[mi][ni]);
    }
  };
  STAGE(As0, Bs0, 0);
#pragma unroll
  for (int t = 0; t < 12; t += 2) {
    __syncthreads();                           // drains prev stage (overlapped)
    if (t + 1 < 12) STAGE(As1, Bs1, (t + 1) * 64);
    COMPUTE(As0, Bs0);
    __syncthreads();
    if (t + 2 < 12) STAGE(As0, Bs0, (t + 2) * 64);
    COMPUTE(As1, Bs1);
  }
#pragma unroll
  for (int ni = 0; ni < 4; ni++) {
    const int col = n0 + wn * 64 + ni * 16 + lr;
    const float bv = bias[col];
#pragma unroll
    for (int mi = 0; mi < 4; mi++) {
      const int gr = m0 + wm * 64 + mi * 16 + g * 4;
      const f32x4 c = acc[mi][ni];
#pragma unroll
      for (int r = 0; r < 4; r++)
        ehid[(size_t)(gr + r) * 1536 + col] = (f16)gelu_fast(c[r] + bv);
    }
  }
}

// ---------------- MoE expert GEMM 2: 2-phase dbuf, XCD-chunked, NO atomics ----------------
// 1-D grid 792 (= 6 x 132). eout[gr] (f16, packed) = w*(acc+b2) (hf0) / += w*acc (hf1).
__global__ __launch_bounds__(256) void gemm_moe2(
    const f16* __restrict__ ehid, const f16* __restrict__ etw2,
    const float* __restrict__ eb2, const float* __restrict__ comb,
    const int* __restrict__ lists, const int* __restrict__ cnts,
    const int* __restrict__ starts, f16* __restrict__ eout, int hf) {
  const int per = gridDim.x >> 3;  // 792/8 = 99
  const int lin = (blockIdx.x & 7) * per + (blockIdx.x >> 3);
  const int bx = lin % 6, by = lin / 6;
  const int m0 = by * 128;
  if (m0 >= starts[4]) return;
  int e = 0;
  while (e < 3 && m0 >= starts[e + 1]) e++;
  const int cnt = cnts[e];
  const int st = starts[e];
  const int* list = lists + e * 8192;
  const f16* Bw = etw2 + (size_t)e * 768 * 3072 + hf * 1536;
  __shared__ __align__(16) f16 As0[128][64], Bs0[128][64];
  __shared__ __align__(16) f16 As1[128][64], Bs1[128][64];
  const int tid = threadIdx.x;
  const int lane = tid & 63, wid = tid >> 6;
  const int wm = wid >> 1, wn = wid & 1;
  const int g = lane >> 4, lr = lane & 15;
  const int swz = (((tid & 7) ^ ((tid >> 3) & 7)) << 3);
  const int n0 = bx * 128;
  f32x4 acc[4][4] = {};
  auto STAGE = [&](f16 (&A)[128][64], f16 (&B)[128][64], int k0) {
#pragma unroll
    for (int s = 0; s < 4; s++) {
      const int u = s * 256 + tid;
      const int row = u >> 3;
      gload16(&A[0][0] + u * 8, ehid + (size_t)(m0 + row) * 1536 + k0 + swz);
      gload16(&B[0][0] + u * 8, Bw + (size_t)(n0 + row) * 3072 + k0 + swz);
    }
  };
  auto COMPUTE = [&](f16 (&A)[128][64], f16 (&B)[128][64]) {
#pragma unroll
    for (int kk = 0; kk < 2; kk++) {
      f16x8 fa[4], fb[4];
#pragma unroll
      for (int mi = 0; mi < 4; mi++) {
        const int row = wm * 64 + mi * 16 + lr;
        fa[mi] = *(const f16x8*)&A[row][(((kk * 4 + g) ^ (lr & 7)) << 3)];
      }
#pragma unroll
      for (int ni = 0; ni < 4; ni++) {
        const int row = wn * 64 + ni * 16 + lr;
        fb[ni] = *(const f16x8*)&B[row][(((kk * 4 + g) ^ (lr & 7)) << 3)];
      }
#pragma unroll
      for (int mi = 0; mi < 4; mi++)
#pragma unroll
        for (int ni = 0; ni < 4; ni++)
          acc[mi][ni] = MFMA16(fa[mi], fb[ni], acc[mi][ni]);
    }
  };
  STAGE(As0, Bs0, 0);
#pragma unroll
  for (int t = 0; t < 24; t += 2) {
    __syncthreads();                           // drains prev stage (overlapped)
    if (t + 1 < 24) STAGE(As1, Bs1, (t + 1) * 64);
    COMPUTE(As0, Bs0);
    __syncthreads();
    if (t + 2 < 24) STAGE(As0, Bs0, (t + 2) * 64);
    COMPUTE(As1, Bs1);
  }
#pragma unroll
  for (int ni = 0; ni < 4; ni++) {
    const int col = n0 + wn * 64 + ni * 16 + lr;
    const float bv = hf ? 0.0f : eb2[e * 768 + col];
#pragma unroll
    for (int mi = 0; mi < 4; mi++) {
      const int gr = m0 + wm * 64 + mi * 16 + g * 4;
      const f32x4 c = acc[mi][ni];
#pragma unroll
      for (int r = 0; r < 4; r++) {
        const int loc = gr + r - st;
        if (loc < cnt) {
          const int tok = list[loc];
          const float w = comb[(size_t)tok * 4 + e];
          const size_t oi = (size_t)(gr + r) * 768 + col;
          const float v = w * (c[r] + bv);
          eout[oi] = hf ? (f16)((float)eout[oi] + v) : (f16)v;
        }
      }
    }
  }
}

// ---------------- final combine: out[t] = x2[t] + eout[posA[t]] + eout[posB[t]] ----------------
__global__ __launch_bounds__(256) void combine_kernel(
    float* __restrict__ out, const f16* __restrict__ eout,
    const int* __restrict__ posA, const int* __restrict__ posB) {
  const int w = threadIdx.x >> 6, lane = threadIdx.x & 63;
  const size_t row = (size_t)blockIdx.x * 4 + w;
  const size_t pa = (size_t)posA[row] * 768, pb = (size_t)posB[row] * 768;
#pragma unroll
  for (int c = 0; c < 3; c++) {
    const int col = c * 256 + lane * 4;
    f32x4 v = *(const f32x4*)(out + row * 768 + col);
    const f16x4 a = *(const f16x4*)(eout + pa + col);
    const f16x4 b = *(const f16x4*)(eout + pb + col);
#pragma unroll
    for (int j = 0; j < 4; j++) v[j] += (float)a[j] + (float)b[j];
    *(f32x4*)(out + row * 768 + col) = v;
  }
}

// ---------------- flash attention, split-fp16 3-term, KVBLK=64 ----------------
// 1536 blocks, XCD-swizzled. No-max softmax P=exp(s/8) (bounded: std(s)~0.31,
// f16 overflow needs s>11 = 35 sigma); row-sum via MFMA x ones.
__global__ __launch_bounds__(256) void attn_kernel(
    const f16* __restrict__ qh, const f16* __restrict__ ql,
    const f16* __restrict__ vth, const f16* __restrict__ vtl,
    f16* __restrict__ ch, f16* __restrict__ cl) {
  const int wg = blockIdx.y * 16 + blockIdx.x;          // 0..1535
  const int nid = (wg & 7) * 192 + (wg >> 3);           // bijective (1536%8==0)
  const int qt = nid & 15, bh = nid >> 4;
  const int b = bh / 12, h = bh % 12;
  const int tid = threadIdx.x;
  const int lane = tid & 63, w = tid >> 6;
  const int g = lane >> 4, lr = lane & 15;
  __shared__ __align__(16) f16 Ksh[64][64];
  __shared__ __align__(16) f16 Ksl[64][64];
  __shared__ __align__(16) f16 Vsh[64][64];
  __shared__ __align__(16) f16 Vsl[64][64];
  __shared__ __align__(16) char Psh[4][2048];  // per-wave P (16 x 64 f16), XOR-swizzled
  __shared__ __align__(16) char Psl[4][2048];
  const int swz = (((tid & 7) ^ ((tid >> 3) & 7)) << 3);
  const size_t qrow = (size_t)b * 1024 + qt * 64 + w * 16 + lr;
  const f16* qbh = qh + qrow * 2304 + h * 64;
  const f16* qbl = ql + qrow * 2304 + h * 64;
  const f16x8 qfh0 = *(const f16x8*)(qbh + g * 8);
  const f16x8 qfh1 = *(const f16x8*)(qbh + 32 + g * 8);
  const f16x8 qfl0 = *(const f16x8*)(qbl + g * 8);
  const f16x8 qfl1 = *(const f16x8*)(qbl + 32 + g * 8);
  const f16x8 ones = {(f16)1, (f16)1, (f16)1, (f16)1, (f16)1, (f16)1, (f16)1, (f16)1};
  f32x4 o[4] = {};
  f32x4 osum = {};
  const f16* kbh = qh + ((size_t)b * 1024) * 2304 + 768 + h * 64;
  const f16* kbl = ql + ((size_t)b * 1024) * 2304 + 768 + h * 64;
  const f16* vbh = vth + (size_t)bh * 64 * 1024;
  const f16* vbl = vtl + (size_t)bh * 64 * 1024;
  char* pbh = Psh[w];
  char* pbl = Psl[w];
  for (int kv0 = 0; kv0 < 1024; kv0 += 64) {
    __syncthreads();
#pragma unroll
    for (int s = 0; s < 2; s++) {
      const int u = s * 256 + tid;  // 16B unit within an 8KB plane
      const int row = u >> 3;
      const size_t ko = (size_t)(kv0 + row) * 2304 + swz;
      gload16(&Ksh[0][0] + u * 8, kbh + ko);
      gload16(&Ksl[0][0] + u * 8, kbl + ko);
      const size_t vo = (size_t)row * 1024 + kv0 + swz;  // row = d
      gload16(&Vsh[0][0] + u * 8, vbh + vo);
      gload16(&Vsl[0][0] + u * 8, vbl + vo);
    }
    __syncthreads();
    f32x4 s[4];
    __builtin_amdgcn_s_setprio(1);
#pragma unroll
    for (int nb = 0; nb < 4; nb++) {
      const int row = nb * 16 + lr;
      const int c0 = ((g ^ (lr & 7)) << 3);
      const int c1 = (((4 + g) ^ (lr & 7)) << 3);
      const f16x8 kh0 = *(const f16x8*)&Ksh[row][c0];
      const f16x8 kh1 = *(const f16x8*)&Ksh[row][c1];
      const f16x8 kl0 = *(const f16x8*)&Ksl[row][c0];
      const f16x8 kl1 = *(const f16x8*)&Ksl[row][c1];
      f32x4 t = {};
      t = MFMA16(qfh0, kh0, t);
      t = MFMA16(qfh1, kh1, t);
      t = MFMA16(qfh0, kl0, t);
      t = MFMA16(qfh1, kl1, t);
      t = MFMA16(qfl0, kh0, t);
      t = MFMA16(qfl1, kh1, t);
      s[nb] = t;
    }
    __builtin_amdgcn_s_setprio(0);
    // P = exp(s/8), no max subtraction (shift-invariant; overflow at 35 sigma)
    // -> LDS (swizzled) as split fp16
#pragma unroll
    for (int nb = 0; nb < 4; nb++)
#pragma unroll
      for (int r = 0; r < 4; r++) {
        const int row = g * 4 + r;
        const int sw = ((nb * 16 + lr) * 2) ^ ((row & 7) << 4);
        const float p = __expf(s[nb][r] * 0.125f);
        f16 hh, ll;
        split2(p, hh, ll);
        *(f16*)(pbh + row * 128 + sw) = hh;
        *(f16*)(pbl + row * 128 + sw) = ll;
      }
    // PV + row-sum via MFMA x ones
    __builtin_amdgcn_s_setprio(1);
#pragma unroll
    for (int ks = 0; ks < 2; ks++) {
      const int pc = (ks * 64 + g * 16) ^ ((lr & 7) << 4);
      const f16x8 pfh = *(const f16x8*)(pbh + lr * 128 + pc);
      const f16x8 pfl = *(const f16x8*)(pbl + lr * 128 + pc);
      osum = MFMA16(pfh, ones, osum);
      osum = MFMA16(pfl, ones, osum);
#pragma unroll
      for (int db = 0; db < 4; db++) {
        const int vrow = db * 16 + lr;
        const int vc = (((ks * 4 + g) ^ (lr & 7)) << 3);
        const f16x8 vfh = *(const f16x8*)&Vsh[vrow][vc];
        const f16x8 vfl = *(const f16x8*)&Vsl[vrow][vc];
        o[db] = MFMA16(pfh, vfh, o[db]);
        o[db] = MFMA16(pfh, vfl, o[db]);
        o[db] = MFMA16(pfl, vfh, o[db]);
      }
    }
    __builtin_amdgcn_s_setprio(0);
  }
  const size_t orow = (size_t)b * 1024 + qt * 64 + w * 16 + g * 4;
#pragma unroll
  for (int r = 0; r < 4; r++) {
    const float inv = 1.0f / osum[r];
#pragma unroll
    for (int db = 0; db < 4; db++) {
      const float val = o[db][r] * inv;
      const size_t oi = (orow + r) * 768 + h * 64 + db * 16 + lr;
      f16 hh, ll;
      split2(val, hh, ll);
      ch[oi] = hh;
      cl[oi] = ll;
    }
  }
}

// ---------------- gate: fp32 logits from split xm, top-2, softmax -> comb[T][4] ----------------
__global__ __launch_bounds__(256) void gate_kernel(
    const f16* __restrict__ xmh, const f16* __restrict__ xml,
    const float* __restrict__ gw, const float* __restrict__ gb,
    float* __restrict__ comb) {
  const int t = blockIdx.x * 256 + threadIdx.x;
  const f16* xrh = xmh + (size_t)t * 768;
  const f16* xrl = xml + (size_t)t * 768;
  float a0 = 0, a1 = 0, a2 = 0, a3 = 0;
  for (int k = 0; k < 768; k += 4) {
    const f16x4 xh = *(const f16x4*)(xrh + k);
    const f16x4 xl = *(const f16x4*)(xrl + k);
    const f32x4 w0 = *(const f32x4*)(gw + k);
    const f32x4 w1 = *(const f32x4*)(gw + 768 + k);
    const f32x4 w2 = *(const f32x4*)(gw + 1536 + k);
    const f32x4 w3 = *(const f32x4*)(gw + 2304 + k);
#pragma unroll
    for (int j = 0; j < 4; j++) {
      const float xv = (float)xh[j] + (float)xl[j];
      a0 += xv * w0[j];
      a1 += xv * w1[j];
      a2 += xv * w2[j];
      a3 += xv * w3[j];
    }
  }
  float l[4] = {a0 + gb[0], a1 + gb[1], a2 + gb[2], a3 + gb[3]};
  int i0 = 0;
#pragma unroll
  for (int e = 1; e < 4; e++)
    if (l[e] > l[i0]) i0 = e;  // strict > matches top_k tie order
  int i1 = -1;
#pragma unroll
  for (int e = 0; e < 4; e++)
    if (e != i0 && (i1 < 0 || l[e] > l[i1])) i1 = e;
  const float e1 = expf(l[i1] - l[i0]);
  const float inv = 1.0f / (1.0f + e1);
  float c[4] = {0.0f, 0.0f, 0.0f, 0.0f};
  c[i0] = inv;
  c[i1] = e1 * inv;
  f32x4 cv = {c[0], c[1], c[2], c[3]};
  *(f32x4*)(comb + (size_t)t * 4) = cv;
}

// ---------------- per-expert token lists + 128-aligned segment starts + inverse map ----------------
__global__ __launch_bounds__(1024) void listbuild_kernel(
    const float* __restrict__ comb, int* __restrict__ lists /*[4][8192]*/,
    int* __restrict__ cnts /*[4]*/, int* __restrict__ starts /*[5]*/,
    int* __restrict__ posA /*[8192]*/, int* __restrict__ posB /*[8192]*/) {
  __shared__ int wsum[16];
  const int tid = threadIdx.x;
  const int lane = tid & 63, wv = tid >> 6;
  unsigned seen = 0;  // bit c: token c*1024+tid already assigned once
  int segbase = 0;    // padded global segment base (identical on all threads)
  for (int e = 0; e < 4; e++) {
    int base = 0;
    for (int c = 0; c < 8; c++) {
      const int t = c * 1024 + tid;
      const int flag = comb[(size_t)t * 4 + e] > 0.0f ? 1 : 0;
      const unsigned long long mask = __ballot(flag);
      const int myrank = __popcll(mask & ((1ull << lane) - 1ull));
      if (lane == 0) wsum[wv] = __popcll(mask);
      __syncthreads();
      int wbase = 0, total = 0;
#pragma unroll
      for (int i = 0; i < 16; i++) {
        if (i < wv) wbase += wsum[i];
        total += wsum[i];
      }
      if (flag) {
        const int idx = base + wbase + myrank;
        lists[e * 8192 + idx] = t;
        const int gidx = segbase + idx;
        if ((seen >> c) & 1) posB[t] = gidx;
        else { posA[t] = gidx; seen |= 1u << c; }
      }
      base += total;
      __syncthreads();
    }
    if (tid == 0) cnts[e] = base;
    segbase += (base + 127) & ~127;
  }
  if (tid == 0) {
    int s = 0;
    starts[0] = 0;
#pragma unroll
    for (int e = 0; e < 4; e++) {
      s += (cnts[e] + 127) & ~127;
      starts[e + 1] = s;
    }
  }
}

extern "C" void kernel_launch(void* const* d_in, const int* in_sizes, int n_in,
                              void* d_out, int out_size, void* d_ws,
                              size_t ws_size, hipStream_t stream) {
  const float* x = (const float*)d_in[0];
  const float* ln1g = (const float*)d_in[1];
  const float* ln1b = (const float*)d_in[2];
  const float* in_w = (const float*)d_in[3];
  const float* in_b = (const float*)d_in[4];
  const float* out_w = (const float*)d_in[5];
  const float* out_b = (const float*)d_in[6];
  const float* mlp_w1 = (const float*)d_in[7];
  const float* mlp_b1 = (const float*)d_in[8];
  const float* mlp_w2 = (const float*)d_in[9];
  const float* mlp_b2 = (const float*)d_in[10];
  const float* ln2g = (const float*)d_in[11];
  const float* ln2b = (const float*)d_in[12];
  const float* gate_w = (const float*)d_in[13];
  const float* gate_b = (const float*)d_in[14];
  const float* exp_w1 = (const float*)d_in[15];
  const float* exp_b1 = (const float*)d_in[16];
  const float* exp_w2 = (const float*)d_in[17];
  const float* exp_b2 = (const float*)d_in[18];
  float* out = (float*)d_out;
  (void)in_sizes; (void)n_in; (void)out_size;

  const size_t MB = 1ull << 20;
  if (ws_size < 130 * MB) return;  // clean absmax failure (not a crash) if ws too small
  char* ws = (char*)d_ws;
  // Pre-MoE layout (as R6-R8, lifetimes hand-verified):
  // S1 [0,24MB):   h planes -> attn ctx planes -> w1t planes -> xm planes
  // S2 [24,33MB):  in_w+out_w planes -> w2t planes
  // S3 [33,105MB): qkv planes -> mlp hid planes
  // S4 [105,129MB): vt planes -> x1 planes
  // MoE phase (everything except xmh [0,12MB) is dead after gate):
  //   etw1 [12,30) etw2 [30,48) ehid [48,100) eout(f16) [100,126)
  // S5 [129MB..): comb, lists, cnts, starts, posA, posB
  char* S1 = ws;
  char* S2 = ws + 24 * MB;
  char* S3 = ws + 33 * MB;
  char* S4 = ws + 105 * MB;
  char* S5 = ws + 129 * MB;

  f16* h_h = (f16*)S1;                       // 12,582,912 B each
  f16* h_l = (f16*)(S1 + 12 * MB);
  f16* ctx_h = (f16*)S1;                     // after qkv gemm, h dead
  f16* ctx_l = (f16*)(S1 + 12 * MB);
  f16* w1t_h = (f16*)S1;                     // after out-proj, ctx dead
  f16* w1t_l = (f16*)(S1 + 4718592);
  f16* xmh = (f16*)S1;                       // after mlp, w1t dead
  f16* xml = (f16*)(S1 + 12 * MB);           // dead after gate

  f16* inw_h = (f16*)S2;                     // 3,538,944 B each
  f16* inw_l = (f16*)(S2 + 3538944);
  f16* outw_h = (f16*)(S2 + 7077888);        // 1,179,648 B each
  f16* outw_l = (f16*)(S2 + 8257536);
  f16* w2t_h = (f16*)S2;                     // after out-proj, inw/outw dead
  f16* w2t_l = (f16*)(S2 + 4718592);

  f16* qkv_h = (f16*)S3;                     // 37,748,736 B each
  f16* qkv_l = (f16*)(S3 + 36 * MB);
  f16* hid_h = (f16*)S3;                     // after attn, qkv dead; [8192][1536] each
  f16* hid_l = (f16*)(S3 + 24 * MB);

  f16* vt_h = (f16*)S4;                      // 12,582,912 B each
  f16* vt_l = (f16*)(S4 + 12 * MB);
  f16* x1h = (f16*)S4;                       // after attn, vt dead
  f16* x1l = (f16*)(S4 + 12 * MB);

  // MoE-phase scratch (xml/w2t/hid/x1 all dead by first use):
  f16* etw1 = (f16*)(ws + 12 * MB);          // [4][3072][768] f16 = 18MB
  f16* etw2 = (f16*)(ws + 30 * MB);          // [4][768][3072] f16 = 18MB
  f16* ehid = (f16*)(ws + 48 * MB);          // [16896][1536] f16 = 51.9MB
  f16* eout = (f16*)(ws + 100 * MB);         // [16896][768] f16 = 25.9MB

  float* comb = (float*)S5;                  // 131,072 B
  int* lists = (int*)(S5 + 131072);          // 4 x 8192 ints
  int* cnts = (int*)(S5 + 262144);           // 4 ints
  int* starts = (int*)(S5 + 262144 + 64);    // 5 ints
  int* posA = (int*)(S5 + 262144 + 256);     // 8192 ints
  int* posB = (int*)(S5 + 262144 + 256 + 32768);

  // ---- attention ----
  convert_split_k<<<dim3(1728), dim3(256), 0, stream>>>(in_w, inw_h, inw_l, 442368);
  convert_split_k<<<dim3(576), dim3(256), 0, stream>>>(out_w, outw_h, outw_l, 147456);
  ln_kernel<<<dim3(2048), dim3(256), 0, stream>>>(x, ln1g, ln1b, h_h, h_l);
  gemm_split<0><<<dim3(18, 64), dim3(256), 0, stream>>>(
      h_h, h_l, 768, inw_h, inw_l, 768, in_b, nullptr, nullptr, nullptr, 0,
      nullptr, qkv_h, qkv_l, 2304, 768);
  vtrans_kernel<<<dim3(16, 96, 2), dim3(256), 0, stream>>>(
      (const ushort*)qkv_h, (const ushort*)qkv_l, (ushort*)vt_h, (ushort*)vt_l);
  attn_kernel<<<dim3(16, 96), dim3(256), 0, stream>>>(qkv_h, qkv_l, vt_h, vt_l, ctx_h, ctx_l);
  gemm_split<1><<<dim3(6, 64), dim3(256), 0, stream>>>(
      ctx_h, ctx_l, 768, outw_h, outw_l, 768, out_b, x, nullptr, nullptr, 0,
      nullptr, x1h, x1l, 768, 768);

  // ---- MLP (hidden in two halves of 1536; result -> out (=x2, fp32)) ----
  transpose_k<<<dim3(96, 24), dim3(256), 0, stream>>>(mlp_w1, w1t_h, w1t_l, 768, 3072);
  transpose_k<<<dim3(24, 96), dim3(256), 0, stream>>>(mlp_w2, w2t_h, w2t_l, 3072, 768);
  gemm_split<2><<<dim3(12, 64), dim3(256), 0, stream>>>(
      x1h, x1l, 768, w1t_h, w1t_l, 768, mlp_b1, nullptr, nullptr, nullptr, 0,
      nullptr, hid_h, hid_l, 1536, 768);
  gemm_split<3><<<dim3(6, 64), dim3(256), 0, stream>>>(
      hid_h, hid_l, 1536, w2t_h, w2t_l, 3072, mlp_b2, nullptr, x1h, x1l, 0,
      out, nullptr, nullptr, 768, 1536);
  gemm_split<2><<<dim3(12, 64), dim3(256), 0, stream>>>(
      x1h, x1l, 768, w1t_h + (size_t)1536 * 768, w1t_l + (size_t)1536 * 768, 768,
      mlp_b1 + 1536, nullptr, nullptr, nullptr, 0, nullptr, hid_h, hid_l, 1536, 768);
  gemm_split<3><<<dim3(6, 64), dim3(256), 0, stream>>>(
      hid_h, hid_l, 1536, w2t_h + 1536, w2t_l + 1536, 3072,
      nullptr, nullptr, nullptr, nullptr, 1, out, nullptr, nullptr, 768, 1536);

  // ---- MoE (sparse top-2, segment-mapped, dbuf, atomic-free scatter) ----
  ln_kernel<<<dim3(2048), dim3(256), 0, stream>>>(out, ln2g, ln2b, xmh, xml);
  gate_kernel<<<dim3(32), dim3(256), 0, stream>>>(xmh, xml, gate_w, gate_b, comb);
  listbuild_kernel<<<dim3(1), dim3(1024), 0, stream>>>(comb, lists, cnts, starts, posA, posB);
  etrans_kernel<<<dim3(96, 24, 4), dim3(256), 0, stream>>>(exp_w1, etw1, 768, 3072);
  etrans_kernel<<<dim3(24, 96, 4), dim3(256), 0, stream>>>(exp_w2, etw2, 3072, 768);
  for (int hf = 0; hf < 2; hf++) {
    gemm_moe1<<<dim3(1584), dim3(256), 0, stream>>>(
        xmh, etw1, exp_b1, lists, cnts, starts, ehid, hf);
    gemm_moe2<<<dim3(792), dim3(256), 0, stream>>>(
        ehid, etw2, exp_b2, comb, lists, cnts, starts, eout, hf);
  }
  combine_kernel<<<dim3(2048), dim3(256), 0, stream>>>(out, eout, posA, posB);
}

// Round 10
// 1002.374 us; speedup vs baseline: 1.1667x; 1.0120x over previous
//
#include <hip/hip_runtime.h>

// TransformerBlock (attn + MLP + top2-MoE) on MI355X.
// Pre-gate chain in split-fp16 3-term MFMA (fp32-class accuracy so the MoE
// top-2 selection matches the fp32 reference); post-gate experts in plain
// fp16 MFMA, SPARSE top-2 dispatch, atomic-free scatter.
// R10: attn precision-trimmed where error budget allows (Q-lo dropped in QK,
// P single-plane in PV -> 34 MFMA/iter vs 52, LDS 40KB -> 4 blocks/CU);
// gemm_split gets XCD-chunked 1-D grid (A-panel L2 locality).

typedef _Float16 f16;
typedef _Float16 f16x4 __attribute__((ext_vector_type(4)));
typedef _Float16 f16x8 __attribute__((ext_vector_type(8)));
typedef float f32x4 __attribute__((ext_vector_type(4)));
typedef unsigned short ushort;

#define MFMA16(a, b, c) __builtin_amdgcn_mfma_f32_16x16x32_f16((a), (b), (c), 0, 0, 0)

__device__ __forceinline__ void gload16(void* lds, const void* g) {
  __builtin_amdgcn_global_load_lds(
      (const __attribute__((address_space(1))) unsigned int*)g,
      (__attribute__((address_space(3))) unsigned int*)lds, 16, 0, 0);
}

__device__ __forceinline__ void split2(float t, f16& h, f16& l) {
  h = (f16)t;
  l = (f16)(t - (float)h);
}

__device__ __forceinline__ float gelu_f(float x) {  // exact (pre-gate path)
  return 0.5f * x * (1.0f + erff(x * 0.70710678118654752f));
}

__device__ __forceinline__ float gelu_fast(float x) {  // tanh-approx (post-gate experts)
  return x / (1.0f + __expf(-1.5957691216f * (x + 0.044715f * x * x * x)));
}

// ---------------- LayerNorm: one wave per row of 768; split-fp16 planes out ----------------
__global__ __launch_bounds__(256) void ln_kernel(
    const float* __restrict__ x, const float* __restrict__ gam,
    const float* __restrict__ bet, f16* __restrict__ oh, f16* __restrict__ ol) {
  const int w = threadIdx.x >> 6, lane = threadIdx.x & 63;
  const size_t row = (size_t)blockIdx.x * 4 + w;
  const float* xr = x + row * 768;
  f32x4 v[3];
  float s = 0.0f;
#pragma unroll
  for (int c = 0; c < 3; c++) {
    v[c] = *(const f32x4*)(xr + c * 256 + lane * 4);
    s += v[c][0] + v[c][1] + v[c][2] + v[c][3];
  }
#pragma unroll
  for (int off = 32; off; off >>= 1) s += __shfl_xor(s, off);
  const float mean = s * (1.0f / 768.0f);
  float q = 0.0f;
#pragma unroll
  for (int c = 0; c < 3; c++)
#pragma unroll
    for (int j = 0; j < 4; j++) {
      float d = v[c][j] - mean;
      q += d * d;
    }
#pragma unroll
  for (int off = 32; off; off >>= 1) q += __shfl_xor(q, off);
  // precise rsqrt: rsqrtf() approx (~1e-5 rel) would risk gate flips downstream
  const float rstd = 1.0f / sqrtf(q * (1.0f / 768.0f) + 1e-5f);
#pragma unroll
  for (int c = 0; c < 3; c++) {
    const int col = c * 256 + lane * 4;
    f32x4 gv = *(const f32x4*)(gam + col);
    f32x4 bv = *(const f32x4*)(bet + col);
    f16x4 yh, yl;
#pragma unroll
    for (int j = 0; j < 4; j++) {
      float y = (v[c][j] - mean) * rstd * gv[j] + bv[j];
      f16 hh, ll;
      split2(y, hh, ll);
      yh[j] = hh;
      yl[j] = ll;
    }
    *(f16x4*)(oh + row * 768 + col) = yh;
    *(f16x4*)(ol + row * 768 + col) = yl;
  }
}

// ---------------- fp32 -> split fp16 (elementwise, x4) ----------------
__global__ __launch_bounds__(256) void convert_split_k(
    const float* __restrict__ in, f16* __restrict__ oh, f16* __restrict__ ol,
    int n4) {
  const int i = blockIdx.x * 256 + threadIdx.x;
  if (i >= n4) return;
  f32x4 v = ((const f32x4*)in)[i];
  f16x4 h, l;
#pragma unroll
  for (int j = 0; j < 4; j++) {
    f16 hh, ll;
    split2(v[j], hh, ll);
    h[j] = hh;
    l[j] = ll;
  }
  ((f16x4*)oh)[i] = h;
  ((f16x4*)ol)[i] = l;
}

// ---------------- fp32 [R][ldin] (32x32 tiles) -> fp16 [C][R] split ----------------
__global__ __launch_bounds__(256) void transpose_k(
    const float* __restrict__ in, f16* __restrict__ oh, f16* __restrict__ ol,
    int R, int ldin) {
  __shared__ float t[32][33];
  const int tx = threadIdx.x & 31, ty = threadIdx.x >> 5;
  const int r0 = blockIdx.y * 32, c0 = blockIdx.x * 32;
#pragma unroll
  for (int i = 0; i < 4; i++)
    t[ty + 8 * i][tx] = in[(size_t)(r0 + ty + 8 * i) * ldin + c0 + tx];
  __syncthreads();
#pragma unroll
  for (int i = 0; i < 4; i++) {
    const float val = t[tx][ty + 8 * i];
    const size_t o = (size_t)(c0 + ty + 8 * i) * R + r0 + tx;
    f16 hh, ll;
    split2(val, hh, ll);
    oh[o] = hh;
    ol[o] = ll;
  }
}

// ---------------- per-expert fp32 [R][C] -> f16 [C][R] (blockIdx.z = expert) ----------------
__global__ __launch_bounds__(256) void etrans_kernel(
    const float* __restrict__ in0, f16* __restrict__ out0, int R, int C) {
  const size_t eoff = (size_t)blockIdx.z * R * C;
  const float* in = in0 + eoff;
  f16* out = out0 + eoff;
  __shared__ float t[32][33];
  const int tx = threadIdx.x & 31, ty = threadIdx.x >> 5;
  const int r0 = blockIdx.y * 32, c0 = blockIdx.x * 32;
#pragma unroll
  for (int i = 0; i < 4; i++)
    t[ty + 8 * i][tx] = in[(size_t)(r0 + ty + 8 * i) * C + c0 + tx];
  __syncthreads();
#pragma unroll
  for (int i = 0; i < 4; i++)
    out[(size_t)(c0 + ty + 8 * i) * R + r0 + tx] = (f16)t[tx][ty + 8 * i];
}

// ---------------- V transpose: qkv planes (v part) -> [B,H,64,1024]; z = hi/lo ----------------
__global__ __launch_bounds__(256) void vtrans_kernel(
    const ushort* __restrict__ srcH, const ushort* __restrict__ srcL,
    ushort* __restrict__ dstH, ushort* __restrict__ dstL) {
  const int nt = blockIdx.x, bh = blockIdx.y;
  const ushort* src = blockIdx.z ? srcL : srcH;
  ushort* dst = blockIdx.z ? dstL : dstH;
  const int b = bh / 12, h = bh % 12;
  __shared__ ushort t[64][65];
  const int tid = threadIdx.x;
#pragma unroll
  for (int i = 0; i < 16; i++) {
    const int idx = i * 256 + tid;
    const int r = idx >> 6, c = idx & 63;
    t[r][c] = src[((size_t)b * 1024 + nt * 64 + r) * 2304 + 1536 + h * 64 + c];
  }
  __syncthreads();
#pragma unroll
  for (int i = 0; i < 16; i++) {
    const int idx = i * 256 + tid;
    const int d = idx >> 6, n = idx & 63;
    dst[((size_t)bh * 64 + d) * 1024 + nt * 64 + n] = t[n][d];
  }
}

// ---------------- split-fp16 3-term GEMM: C = A·B^T (+bias), A[M,K] B[N,K] ----------------
// 128x128 tile, BK=64, 4 waves (2x2). Row-major LDS [128][64]f16 (=128B rows),
// XOR chunk-swizzle; staging: lane L -> row L>>3, global chunk (L&7)^((L>>3)&7).
// Single-buffered 64KB LDS (2 blocks/CU). R10: XCD-chunked 1-D grid (nbx = N tiles).
template <int MODE>
__global__ __launch_bounds__(256) void gemm_split(
    const f16* __restrict__ Ah, const f16* __restrict__ Al, int lda,
    const f16* __restrict__ Bh, const f16* __restrict__ Bl, int ldb,
    const float* __restrict__ bias, const float* __restrict__ residF,
    const f16* __restrict__ residH, const f16* __restrict__ residL, int addto,
    float* __restrict__ outF, f16* __restrict__ outH, f16* __restrict__ outL,
    int ldo, int K, int nbx) {
  __shared__ __align__(16) f16 Ash[128][64];
  __shared__ __align__(16) f16 Asl[128][64];
  __shared__ __align__(16) f16 Bsh[128][64];
  __shared__ __align__(16) f16 Bsl[128][64];
  const int per = gridDim.x >> 3;
  const int lin = ((int)blockIdx.x & 7) * per + ((int)blockIdx.x >> 3);
  const int bx = lin % nbx, by = lin / nbx;
  const int tid = threadIdx.x;
  const int lane = tid & 63, wid = tid >> 6;
  const int wm = wid >> 1, wn = wid & 1;
  const int g = lane >> 4, lr = lane & 15;
  const int swz = (((tid & 7) ^ ((tid >> 3) & 7)) << 3);  // element offset
  const size_t m0 = (size_t)by * 128, n0 = (size_t)bx * 128;
  f32x4 acc[4][4] = {};
  for (int k0 = 0; k0 < K; k0 += 64) {
    __syncthreads();
#pragma unroll
    for (int s = 0; s < 4; s++) {
      const int u = s * 256 + tid;  // 16B unit within a 16KB plane
      const int row = u >> 3;
      const size_t ga = (m0 + row) * (size_t)lda + k0 + swz;
      const size_t gb = (n0 + row) * (size_t)ldb + k0 + swz;
      gload16(&Ash[0][0] + u * 8, Ah + ga);
      gload16(&Asl[0][0] + u * 8, Al + ga);
      gload16(&Bsh[0][0] + u * 8, Bh + gb);
      gload16(&Bsl[0][0] + u * 8, Bl + gb);
    }
    __syncthreads();
#pragma unroll
    for (int kk = 0; kk < 2; kk++) {
      f16x8 fah[4], fal[4], fbh[4], fbl[4];
#pragma unroll
      for (int mi = 0; mi < 4; mi++) {
        const int row = wm * 64 + mi * 16 + lr;
        const int c = (((kk * 4 + g) ^ (lr & 7)) << 3);
        fah[mi] = *(const f16x8*)&Ash[row][c];
        fal[mi] = *(const f16x8*)&Asl[row][c];
      }
#pragma unroll
      for (int ni = 0; ni < 4; ni++) {
        const int row = wn * 64 + ni * 16 + lr;
        const int c = (((kk * 4 + g) ^ (lr & 7)) << 3);
        fbh[ni] = *(const f16x8*)&Bsh[row][c];
        fbl[ni] = *(const f16x8*)&Bsl[row][c];
      }
#pragma unroll
      for (int mi = 0; mi < 4; mi++)
#pragma unroll
        for (int ni = 0; ni < 4; ni++) {
          acc[mi][ni] = MFMA16(fah[mi], fbh[ni], acc[mi][ni]);
          acc[mi][ni] = MFMA16(fah[mi], fbl[ni], acc[mi][ni]);
          acc[mi][ni] = MFMA16(fal[mi], fbh[ni], acc[mi][ni]);
        }
    }
  }
#pragma unroll
  for (int ni = 0; ni < 4; ni++) {
    const size_t col = n0 + wn * 64 + ni * 16 + lr;
    const float bv = bias ? bias[col] : 0.0f;
#pragma unroll
    for (int mi = 0; mi < 4; mi++) {
      const size_t rowb = m0 + wm * 64 + mi * 16 + g * 4;
      const f32x4 c = acc[mi][ni];
#pragma unroll
      for (int r = 0; r < 4; r++) {
        const size_t idx = (rowb + r) * (size_t)ldo + col;
        const float v = c[r] + bv;
        if constexpr (MODE == 0) {
          f16 hh, ll;
          split2(v, hh, ll);
          outH[idx] = hh;
          outL[idx] = ll;
        } else if constexpr (MODE == 1) {
          const float tt = v + residF[idx];
          f16 hh, ll;
          split2(tt, hh, ll);
          outH[idx] = hh;
          outL[idx] = ll;
        } else if constexpr (MODE == 2) {
          const float tt = gelu_f(v);
          f16 hh, ll;
          split2(tt, hh, ll);
          outH[idx] = hh;
          outL[idx] = ll;
        } else {
          outF[idx] = addto ? (outF[idx] + v)
                            : ((float)residH[idx] + (float)residL[idx] + v);
        }
      }
    }
  }
}

// ---------------- MoE expert GEMM 1: 2-phase dbuf, XCD-chunked, indirect A ----------------
// 1-D grid 1584 (= 12 x 132). ehid[gr][1536] = gelu_fast(xm[list] . w1t[e] + b1).
__global__ __launch_bounds__(256) void gemm_moe1(
    const f16* __restrict__ xmh, const f16* __restrict__ etw1,
    const float* __restrict__ eb1, const int* __restrict__ lists,
    const int* __restrict__ cnts, const int* __restrict__ starts,
    f16* __restrict__ ehid, int hf) {
  const int per = gridDim.x >> 3;  // 1584/8 = 198
  const int lin = (blockIdx.x & 7) * per + (blockIdx.x >> 3);
  const int bx = lin % 12, by = lin / 12;
  const int m0 = by * 128;
  if (m0 >= starts[4]) return;
  int e = 0;
  while (e < 3 && m0 >= starts[e + 1]) e++;
  const int cnt = cnts[e];
  const int loc0 = m0 - starts[e];
  const int* list = lists + e * 8192;
  const f16* Bw = etw1 + ((size_t)e * 3072 + hf * 1536) * 768;
  const float* bias = eb1 + e * 3072 + hf * 1536;
  __shared__ __align__(16) f16 As0[128][64], Bs0[128][64];
  __shared__ __align__(16) f16 As1[128][64], Bs1[128][64];
  const int tid = threadIdx.x;
  const int lane = tid & 63, wid = tid >> 6;
  const int wm = wid >> 1, wn = wid & 1;
  const int g = lane >> 4, lr = lane & 15;
  const int swz = (((tid & 7) ^ ((tid >> 3) & 7)) << 3);
  const int n0 = bx * 128;
  size_t arow[4];
#pragma unroll
  for (int s = 0; s < 4; s++) {
    const int row = (s * 256 + tid) >> 3;
    const int loc = loc0 + row;
    arow[s] = (size_t)list[loc < cnt ? loc : cnt - 1] * 768;
  }
  f32x4 acc[4][4] = {};
  auto STAGE = [&](f16 (&A)[128][64], f16 (&B)[128][64], int k0) {
#pragma unroll
    for (int s = 0; s < 4; s++) {
      const int u = s * 256 + tid;
      const int row = u >> 3;
      gload16(&A[0][0] + u * 8, xmh + arow[s] + k0 + swz);
      gload16(&B[0][0] + u * 8, Bw + (size_t)(n0 + row) * 768 + k0 + swz);
    }
  };
  auto COMPUTE = [&](f16 (&A)[128][64], f16 (&B)[128][64]) {
#pragma unroll
    for (int kk = 0; kk < 2; kk++) {
      f16x8 fa[4], fb[4];
#pragma unroll
      for (int mi = 0; mi < 4; mi++) {
        const int row = wm * 64 + mi * 16 + lr;
        fa[mi] = *(const f16x8*)&A[row][(((kk * 4 + g) ^ (lr & 7)) << 3)];
      }
#pragma unroll
      for (int ni = 0; ni < 4; ni++) {
        const int row = wn * 64 + ni * 16 + lr;
        fb[ni] = *(const f16x8*)&B[row][(((kk * 4 + g) ^ (lr & 7)) << 3)];
      }
#pragma unroll
      for (int mi = 0; mi < 4; mi++)
#pragma unroll
        for (int ni = 0; ni < 4; ni++)
          acc[mi][ni] = MFMA16(fa[mi], fb[ni], acc[mi][ni]);
    }
  };
  STAGE(As0, Bs0, 0);
#pragma unroll
  for (int t = 0; t < 12; t += 2) {
    __syncthreads();                           // drains prev stage (overlapped)
    if (t + 1 < 12) STAGE(As1, Bs1, (t + 1) * 64);
    COMPUTE(As0, Bs0);
    __syncthreads();
    if (t + 2 < 12) STAGE(As0, Bs0, (t + 2) * 64);
    COMPUTE(As1, Bs1);
  }
#pragma unroll
  for (int ni = 0; ni < 4; ni++) {
    const int col = n0 + wn * 64 + ni * 16 + lr;
    const float bv = bias[col];
#pragma unroll
    for (int mi = 0; mi < 4; mi++) {
      const int gr = m0 + wm * 64 + mi * 16 + g * 4;
      const f32x4 c = acc[mi][ni];
#pragma unroll
      for (int r = 0; r < 4; r++)
        ehid[(size_t)(gr + r) * 1536 + col] = (f16)gelu_fast(c[r] + bv);
    }
  }
}

// ---------------- MoE expert GEMM 2: 2-phase dbuf, XCD-chunked, NO atomics ----------------
// 1-D grid 792 (= 6 x 132). eout[gr] (f16, packed) = w*(acc+b2) (hf0) / += w*acc (hf1).
__global__ __launch_bounds__(256) void gemm_moe2(
    const f16* __restrict__ ehid, const f16* __restrict__ etw2,
    const float* __restrict__ eb2, const float* __restrict__ comb,
    const int* __restrict__ lists, const int* __restrict__ cnts,
    const int* __restrict__ starts, f16* __restrict__ eout, int hf) {
  const int per = gridDim.x >> 3;  // 792/8 = 99
  const int lin = (blockIdx.x & 7) * per + (blockIdx.x >> 3);
  const int bx = lin % 6, by = lin / 6;
  const int m0 = by * 128;
  if (m0 >= starts[4]) return;
  int e = 0;
  while (e < 3 && m0 >= starts[e + 1]) e++;
  const int cnt = cnts[e];
  const int st = starts[e];
  const int* list = lists + e * 8192;
  const f16* Bw = etw2 + (size_t)e * 768 * 3072 + hf * 1536;
  __shared__ __align__(16) f16 As0[128][64], Bs0[128][64];
  __shared__ __align__(16) f16 As1[128][64], Bs1[128][64];
  const int tid = threadIdx.x;
  const int lane = tid & 63, wid = tid >> 6;
  const int wm = wid >> 1, wn = wid & 1;
  const int g = lane >> 4, lr = lane & 15;
  const int swz = (((tid & 7) ^ ((tid >> 3) & 7)) << 3);
  const int n0 = bx * 128;
  f32x4 acc[4][4] = {};
  auto STAGE = [&](f16 (&A)[128][64], f16 (&B)[128][64], int k0) {
#pragma unroll
    for (int s = 0; s < 4; s++) {
      const int u = s * 256 + tid;
      const int row = u >> 3;
      gload16(&A[0][0] + u * 8, ehid + (size_t)(m0 + row) * 1536 + k0 + swz);
      gload16(&B[0][0] + u * 8, Bw + (size_t)(n0 + row) * 3072 + k0 + swz);
    }
  };
  auto COMPUTE = [&](f16 (&A)[128][64], f16 (&B)[128][64]) {
#pragma unroll
    for (int kk = 0; kk < 2; kk++) {
      f16x8 fa[4], fb[4];
#pragma unroll
      for (int mi = 0; mi < 4; mi++) {
        const int row = wm * 64 + mi * 16 + lr;
        fa[mi] = *(const f16x8*)&A[row][(((kk * 4 + g) ^ (lr & 7)) << 3)];
      }
#pragma unroll
      for (int ni = 0; ni < 4; ni++) {
        const int row = wn * 64 + ni * 16 + lr;
        fb[ni] = *(const f16x8*)&B[row][(((kk * 4 + g) ^ (lr & 7)) << 3)];
      }
#pragma unroll
      for (int mi = 0; mi < 4; mi++)
#pragma unroll
        for (int ni = 0; ni < 4; ni++)
          acc[mi][ni] = MFMA16(fa[mi], fb[ni], acc[mi][ni]);
    }
  };
  STAGE(As0, Bs0, 0);
#pragma unroll
  for (int t = 0; t < 24; t += 2) {
    __syncthreads();                           // drains prev stage (overlapped)
    if (t + 1 < 24) STAGE(As1, Bs1, (t + 1) * 64);
    COMPUTE(As0, Bs0);
    __syncthreads();
    if (t + 2 < 24) STAGE(As0, Bs0, (t + 2) * 64);
    COMPUTE(As1, Bs1);
  }
#pragma unroll
  for (int ni = 0; ni < 4; ni++) {
    const int col = n0 + wn * 64 + ni * 16 + lr;
    const float bv = hf ? 0.0f : eb2[e * 768 + col];
#pragma unroll
    for (int mi = 0; mi < 4; mi++) {
      const int gr = m0 + wm * 64 + mi * 16 + g * 4;
      const f32x4 c = acc[mi][ni];
#pragma unroll
      for (int r = 0; r < 4; r++) {
        const int loc = gr + r - st;
        if (loc < cnt) {
          const int tok = list[loc];
          const float w = comb[(size_t)tok * 4 + e];
          const size_t oi = (size_t)(gr + r) * 768 + col;
          const float v = w * (c[r] + bv);
          eout[oi] = hf ? (f16)((float)eout[oi] + v) : (f16)v;
        }
      }
    }
  }
}

// ---------------- final combine: out[t] = x2[t] + eout[posA[t]] + eout[posB[t]] ----------------
__global__ __launch_bounds__(256) void combine_kernel(
    float* __restrict__ out, const f16* __restrict__ eout,
    const int* __restrict__ posA, const int* __restrict__ posB) {
  const int w = threadIdx.x >> 6, lane = threadIdx.x & 63;
  const size_t row = (size_t)blockIdx.x * 4 + w;
  const size_t pa = (size_t)posA[row] * 768, pb = (size_t)posB[row] * 768;
#pragma unroll
  for (int c = 0; c < 3; c++) {
    const int col = c * 256 + lane * 4;
    f32x4 v = *(const f32x4*)(out + row * 768 + col);
    const f16x4 a = *(const f16x4*)(eout + pa + col);
    const f16x4 b = *(const f16x4*)(eout + pb + col);
#pragma unroll
    for (int j = 0; j < 4; j++) v[j] += (float)a[j] + (float)b[j];
    *(f32x4*)(out + row * 768 + col) = v;
  }
}

// ---------------- flash attention, KVBLK=64, precision-trimmed ----------------
// 1536 blocks, XCD-swizzled. No-max softmax P=exp(s/8); row-sum via MFMA x ones.
// QK: q_hi x (k_hi + k_lo) (Q-lo dropped, err ~5e-6 on ctx). PV: P single fp16
// plane x (v_hi + v_lo). 34 MFMA/iter; LDS 40KB -> 4 blocks/CU.
__global__ __launch_bounds__(256) void attn_kernel(
    const f16* __restrict__ qh, const f16* __restrict__ ql,
    const f16* __restrict__ vth, const f16* __restrict__ vtl,
    f16* __restrict__ ch, f16* __restrict__ cl) {
  const int wg = blockIdx.y * 16 + blockIdx.x;          // 0..1535
  const int nid = (wg & 7) * 192 + (wg >> 3);           // bijective (1536%8==0)
  const int qt = nid & 15, bh = nid >> 4;
  const int b = bh / 12, h = bh % 12;
  const int tid = threadIdx.x;
  const int lane = tid & 63, w = tid >> 6;
  const int g = lane >> 4, lr = lane & 15;
  __shared__ __align__(16) f16 Ksh[64][64];
  __shared__ __align__(16) f16 Ksl[64][64];
  __shared__ __align__(16) f16 Vsh[64][64];
  __shared__ __align__(16) f16 Vsl[64][64];
  __shared__ __align__(16) char Psh[4][2048];  // per-wave P (16 x 64 f16), XOR-swizzled
  const int swz = (((tid & 7) ^ ((tid >> 3) & 7)) << 3);
  const size_t qrow = (size_t)b * 1024 + qt * 64 + w * 16 + lr;
  const f16* qbh = qh + qrow * 2304 + h * 64;
  const f16x8 qfh0 = *(const f16x8*)(qbh + g * 8);
  const f16x8 qfh1 = *(const f16x8*)(qbh + 32 + g * 8);
  const f16x8 ones = {(f16)1, (f16)1, (f16)1, (f16)1, (f16)1, (f16)1, (f16)1, (f16)1};
  f32x4 o[4] = {};
  f32x4 osum = {};
  const f16* kbh = qh + ((size_t)b * 1024) * 2304 + 768 + h * 64;
  const f16* kbl = ql + ((size_t)b * 1024) * 2304 + 768 + h * 64;
  const f16* vbh = vth + (size_t)bh * 64 * 1024;
  const f16* vbl = vtl + (size_t)bh * 64 * 1024;
  char* pbh = Psh[w];
  for (int kv0 = 0; kv0 < 1024; kv0 += 64) {
    __syncthreads();
#pragma unroll
    for (int s = 0; s < 2; s++) {
      const int u = s * 256 + tid;  // 16B unit within an 8KB plane
      const int row = u >> 3;
      const size_t ko = (size_t)(kv0 + row) * 2304 + swz;
      gload16(&Ksh[0][0] + u * 8, kbh + ko);
      gload16(&Ksl[0][0] + u * 8, kbl + ko);
      const size_t vo = (size_t)row * 1024 + kv0 + swz;  // row = d
      gload16(&Vsh[0][0] + u * 8, vbh + vo);
      gload16(&Vsl[0][0] + u * 8, vbl + vo);
    }
    __syncthreads();
    f32x4 s[4];
    __builtin_amdgcn_s_setprio(1);
#pragma unroll
    for (int nb = 0; nb < 4; nb++) {
      const int row = nb * 16 + lr;
      const int c0 = ((g ^ (lr & 7)) << 3);
      const int c1 = (((4 + g) ^ (lr & 7)) << 3);
      const f16x8 kh0 = *(const f16x8*)&Ksh[row][c0];
      const f16x8 kh1 = *(const f16x8*)&Ksh[row][c1];
      const f16x8 kl0 = *(const f16x8*)&Ksl[row][c0];
      const f16x8 kl1 = *(const f16x8*)&Ksl[row][c1];
      f32x4 t = {};
      t = MFMA16(qfh0, kh0, t);
      t = MFMA16(qfh1, kh1, t);
      t = MFMA16(qfh0, kl0, t);
      t = MFMA16(qfh1, kl1, t);
      s[nb] = t;
    }
    __builtin_amdgcn_s_setprio(0);
    // P = exp(s/8), no max subtraction (shift-invariant; overflow at 35 sigma)
    // -> LDS (swizzled) as single fp16 plane
#pragma unroll
    for (int nb = 0; nb < 4; nb++)
#pragma unroll
      for (int r = 0; r < 4; r++) {
        const int row = g * 4 + r;
        const int sw = ((nb * 16 + lr) * 2) ^ ((row & 7) << 4);
        *(f16*)(pbh + row * 128 + sw) = (f16)__expf(s[nb][r] * 0.125f);
      }
    // PV + row-sum via MFMA x ones
    __builtin_amdgcn_s_setprio(1);
#pragma unroll
    for (int ks = 0; ks < 2; ks++) {
      const int pc = (ks * 64 + g * 16) ^ ((lr & 7) << 4);
      const f16x8 pfh = *(const f16x8*)(pbh + lr * 128 + pc);
      osum = MFMA16(pfh, ones, osum);
#pragma unroll
      for (int db = 0; db < 4; db++) {
        const int vrow = db * 16 + lr;
        const int vc = (((ks * 4 + g) ^ (lr & 7)) << 3);
        const f16x8 vfh = *(const f16x8*)&Vsh[vrow][vc];
        const f16x8 vfl = *(const f16x8*)&Vsl[vrow][vc];
        o[db] = MFMA16(pfh, vfh, o[db]);
        o[db] = MFMA16(pfh, vfl, o[db]);
      }
    }
    __builtin_amdgcn_s_setprio(0);
  }
  const size_t orow = (size_t)b * 1024 + qt * 64 + w * 16 + g * 4;
#pragma unroll
  for (int r = 0; r < 4; r++) {
    const float inv = 1.0f / osum[r];
#pragma unroll
    for (int db = 0; db < 4; db++) {
      const float val = o[db][r] * inv;
      const size_t oi = (orow + r) * 768 + h * 64 + db * 16 + lr;
      f16 hh, ll;
      split2(val, hh, ll);
      ch[oi] = hh;
      cl[oi] = ll;
    }
  }
}

// ---------------- gate: fp32 logits from split xm, top-2, softmax -> comb[T][4] ----------------
__global__ __launch_bounds__(256) void gate_kernel(
    const f16* __restrict__ xmh, const f16* __restrict__ xml,
    const float* __restrict__ gw, const float* __restrict__ gb,
    float* __restrict__ comb) {
  const int t = blockIdx.x * 256 + threadIdx.x;
  const f16* xrh = xmh + (size_t)t * 768;
  const f16* xrl = xml + (size_t)t * 768;
  float a0 = 0, a1 = 0, a2 = 0, a3 = 0;
  for (int k = 0; k < 768; k += 4) {
    const f16x4 xh = *(const f16x4*)(xrh + k);
    const f16x4 xl = *(const f16x4*)(xrl + k);
    const f32x4 w0 = *(const f32x4*)(gw + k);
    const f32x4 w1 = *(const f32x4*)(gw + 768 + k);
    const f32x4 w2 = *(const f32x4*)(gw + 1536 + k);
    const f32x4 w3 = *(const f32x4*)(gw + 2304 + k);
#pragma unroll
    for (int j = 0; j < 4; j++) {
      const float xv = (float)xh[j] + (float)xl[j];
      a0 += xv * w0[j];
      a1 += xv * w1[j];
      a2 += xv * w2[j];
      a3 += xv * w3[j];
    }
  }
  float l[4] = {a0 + gb[0], a1 + gb[1], a2 + gb[2], a3 + gb[3]};
  int i0 = 0;
#pragma unroll
  for (int e = 1; e < 4; e++)
    if (l[e] > l[i0]) i0 = e;  // strict > matches top_k tie order
  int i1 = -1;
#pragma unroll
  for (int e = 0; e < 4; e++)
    if (e != i0 && (i1 < 0 || l[e] > l[i1])) i1 = e;
  const float e1 = expf(l[i1] - l[i0]);
  const float inv = 1.0f / (1.0f + e1);
  float c[4] = {0.0f, 0.0f, 0.0f, 0.0f};
  c[i0] = inv;
  c[i1] = e1 * inv;
  f32x4 cv = {c[0], c[1], c[2], c[3]};
  *(f32x4*)(comb + (size_t)t * 4) = cv;
}

// ---------------- per-expert token lists + 128-aligned segment starts + inverse map ----------------
__global__ __launch_bounds__(1024) void listbuild_kernel(
    const float* __restrict__ comb, int* __restrict__ lists /*[4][8192]*/,
    int* __restrict__ cnts /*[4]*/, int* __restrict__ starts /*[5]*/,
    int* __restrict__ posA /*[8192]*/, int* __restrict__ posB /*[8192]*/) {
  __shared__ int wsum[16];
  const int tid = threadIdx.x;
  const int lane = tid & 63, wv = tid >> 6;
  unsigned seen = 0;  // bit c: token c*1024+tid already assigned once
  int segbase = 0;    // padded global segment base (identical on all threads)
  for (int e = 0; e < 4; e++) {
    int base = 0;
    for (int c = 0; c < 8; c++) {
      const int t = c * 1024 + tid;
      const int flag = comb[(size_t)t * 4 + e] > 0.0f ? 1 : 0;
      const unsigned long long mask = __ballot(flag);
      const int myrank = __popcll(mask & ((1ull << lane) - 1ull));
      if (lane == 0) wsum[wv] = __popcll(mask);
      __syncthreads();
      int wbase = 0, total = 0;
#pragma unroll
      for (int i = 0; i < 16; i++) {
        if (i < wv) wbase += wsum[i];
        total += wsum[i];
      }
      if (flag) {
        const int idx = base + wbase + myrank;
        lists[e * 8192 + idx] = t;
        const int gidx = segbase + idx;
        if ((seen >> c) & 1) posB[t] = gidx;
        else { posA[t] = gidx; seen |= 1u << c; }
      }
      base += total;
      __syncthreads();
    }
    if (tid == 0) cnts[e] = base;
    segbase += (base + 127) & ~127;
  }
  if (tid == 0) {
    int s = 0;
    starts[0] = 0;
#pragma unroll
    for (int e = 0; e < 4; e++) {
      s += (cnts[e] + 127) & ~127;
      starts[e + 1] = s;
    }
  }
}

extern "C" void kernel_launch(void* const* d_in, const int* in_sizes, int n_in,
                              void* d_out, int out_size, void* d_ws,
                              size_t ws_size, hipStream_t stream) {
  const float* x = (const float*)d_in[0];
  const float* ln1g = (const float*)d_in[1];
  const float* ln1b = (const float*)d_in[2];
  const float* in_w = (const float*)d_in[3];
  const float* in_b = (const float*)d_in[4];
  const float* out_w = (const float*)d_in[5];
  const float* out_b = (const float*)d_in[6];
  const float* mlp_w1 = (const float*)d_in[7];
  const float* mlp_b1 = (const float*)d_in[8];
  const float* mlp_w2 = (const float*)d_in[9];
  const float* mlp_b2 = (const float*)d_in[10];
  const float* ln2g = (const float*)d_in[11];
  const float* ln2b = (const float*)d_in[12];
  const float* gate_w = (const float*)d_in[13];
  const float* gate_b = (const float*)d_in[14];
  const float* exp_w1 = (const float*)d_in[15];
  const float* exp_b1 = (const float*)d_in[16];
  const float* exp_w2 = (const float*)d_in[17];
  const float* exp_b2 = (const float*)d_in[18];
  float* out = (float*)d_out;
  (void)in_sizes; (void)n_in; (void)out_size;

  const size_t MB = 1ull << 20;
  if (ws_size < 130 * MB) return;  // clean absmax failure (not a crash) if ws too small
  char* ws = (char*)d_ws;
  // Pre-MoE layout (as R6-R9, lifetimes hand-verified):
  // S1 [0,24MB):   h planes -> attn ctx planes -> w1t planes -> xm planes
  // S2 [24,33MB):  in_w+out_w planes -> w2t planes
  // S3 [33,105MB): qkv planes -> mlp hid planes
  // S4 [105,129MB): vt planes -> x1 planes
  // MoE phase (everything except xmh [0,12MB) is dead after gate):
  //   etw1 [12,30) etw2 [30,48) ehid [48,100) eout(f16) [100,126)
  // S5 [129MB..): comb, lists, cnts, starts, posA, posB
  char* S1 = ws;
  char* S2 = ws + 24 * MB;
  char* S3 = ws + 33 * MB;
  char* S4 = ws + 105 * MB;
  char* S5 = ws + 129 * MB;

  f16* h_h = (f16*)S1;                       // 12,582,912 B each
  f16* h_l = (f16*)(S1 + 12 * MB);
  f16* ctx_h = (f16*)S1;                     // after qkv gemm, h dead
  f16* ctx_l = (f16*)(S1 + 12 * MB);
  f16* w1t_h = (f16*)S1;                     // after out-proj, ctx dead
  f16* w1t_l = (f16*)(S1 + 4718592);
  f16* xmh = (f16*)S1;                       // after mlp, w1t dead
  f16* xml = (f16*)(S1 + 12 * MB);           // dead after gate

  f16* inw_h = (f16*)S2;                     // 3,538,944 B each
  f16* inw_l = (f16*)(S2 + 3538944);
  f16* outw_h = (f16*)(S2 + 7077888);        // 1,179,648 B each
  f16* outw_l = (f16*)(S2 + 8257536);
  f16* w2t_h = (f16*)S2;                     // after out-proj, inw/outw dead
  f16* w2t_l = (f16*)(S2 + 4718592);

  f16* qkv_h = (f16*)S3;                     // 37,748,736 B each
  f16* qkv_l = (f16*)(S3 + 36 * MB);
  f16* hid_h = (f16*)S3;                     // after attn, qkv dead; [8192][1536] each
  f16* hid_l = (f16*)(S3 + 24 * MB);

  f16* vt_h = (f16*)S4;                      // 12,582,912 B each
  f16* vt_l = (f16*)(S4 + 12 * MB);
  f16* x1h = (f16*)S4;                       // after attn, vt dead
  f16* x1l = (f16*)(S4 + 12 * MB);

  // MoE-phase scratch (xml/w2t/hid/x1 all dead by first use):
  f16* etw1 = (f16*)(ws + 12 * MB);          // [4][3072][768] f16 = 18MB
  f16* etw2 = (f16*)(ws + 30 * MB);          // [4][768][3072] f16 = 18MB
  f16* ehid = (f16*)(ws + 48 * MB);          // [16896][1536] f16 = 51.9MB
  f16* eout = (f16*)(ws + 100 * MB);         // [16896][768] f16 = 25.9MB

  float* comb = (float*)S5;                  // 131,072 B
  int* lists = (int*)(S5 + 131072);          // 4 x 8192 ints
  int* cnts = (int*)(S5 + 262144);           // 4 ints
  int* starts = (int*)(S5 + 262144 + 64);    // 5 ints
  int* posA = (int*)(S5 + 262144 + 256);     // 8192 ints
  int* posB = (int*)(S5 + 262144 + 256 + 32768);

  // ---- attention ----
  convert_split_k<<<dim3(1728), dim3(256), 0, stream>>>(in_w, inw_h, inw_l, 442368);
  convert_split_k<<<dim3(576), dim3(256), 0, stream>>>(out_w, outw_h, outw_l, 147456);
  ln_kernel<<<dim3(2048), dim3(256), 0, stream>>>(x, ln1g, ln1b, h_h, h_l);
  gemm_split<0><<<dim3(1152), dim3(256), 0, stream>>>(
      h_h, h_l, 768, inw_h, inw_l, 768, in_b, nullptr, nullptr, nullptr, 0,
      nullptr, qkv_h, qkv_l, 2304, 768, 18);
  vtrans_kernel<<<dim3(16, 96, 2), dim3(256), 0, stream>>>(
      (const ushort*)qkv_h, (const ushort*)qkv_l, (ushort*)vt_h, (ushort*)vt_l);
  attn_kernel<<<dim3(16, 96), dim3(256), 0, stream>>>(qkv_h, qkv_l, vt_h, vt_l, ctx_h, ctx_l);
  gemm_split<1><<<dim3(384), dim3(256), 0, stream>>>(
      ctx_h, ctx_l, 768, outw_h, outw_l, 768, out_b, x, nullptr, nullptr, 0,
      nullptr, x1h, x1l, 768, 768, 6);

  // ---- MLP (hidden in two halves of 1536; result -> out (=x2, fp32)) ----
  transpose_k<<<dim3(96, 24), dim3(256), 0, stream>>>(mlp_w1, w1t_h, w1t_l, 768, 3072);
  transpose_k<<<dim3(24, 96), dim3(256), 0, stream>>>(mlp_w2, w2t_h, w2t_l, 3072, 768);
  gemm_split<2><<<dim3(768), dim3(256), 0, stream>>>(
      x1h, x1l, 768, w1t_h, w1t_l, 768, mlp_b1, nullptr, nullptr, nullptr, 0,
      nullptr, hid_h, hid_l, 1536, 768, 12);
  gemm_split<3><<<dim3(384), dim3(256), 0, stream>>>(
      hid_h, hid_l, 1536, w2t_h, w2t_l, 3072, mlp_b2, nullptr, x1h, x1l, 0,
      out, nullptr, nullptr, 768, 1536, 6);
  gemm_split<2><<<dim3(768), dim3(256), 0, stream>>>(
      x1h, x1l, 768, w1t_h + (size_t)1536 * 768, w1t_l + (size_t)1536 * 768, 768,
      mlp_b1 + 1536, nullptr, nullptr, nullptr, 0, nullptr, hid_h, hid_l, 1536, 768, 12);
  gemm_split<3><<<dim3(384), dim3(256), 0, stream>>>(
      hid_h, hid_l, 1536, w2t_h + 1536, w2t_l + 1536, 3072,
      nullptr, nullptr, nullptr, nullptr, 1, out, nullptr, nullptr, 768, 1536, 6);

  // ---- MoE (sparse top-2, segment-mapped, dbuf, atomic-free scatter) ----
  ln_kernel<<<dim3(2048), dim3(256), 0, stream>>>(out, ln2g, ln2b, xmh, xml);
  gate_kernel<<<dim3(32), dim3(256), 0, stream>>>(xmh, xml, gate_w, gate_b, comb);
  listbuild_kernel<<<dim3(1), dim3(1024), 0, stream>>>(comb, lists, cnts, starts, posA, posB);
  etrans_kernel<<<dim3(96, 24, 4), dim3(256), 0, stream>>>(exp_w1, etw1, 768, 3072);
  etrans_kernel<<<dim3(24, 96, 4), dim3(256), 0, stream>>>(exp_w2, etw2, 3072, 768);
  for (int hf = 0; hf < 2; hf++) {
    gemm_moe1<<<dim3(1584), dim3(256), 0, stream>>>(
        xmh, etw1, exp_b1, lists, cnts, starts, ehid, hf);
    gemm_moe2<<<dim3(792), dim3(256), 0, stream>>>(
        ehid, etw2, exp_b2, comb, lists, cnts, starts, eout, hf);
  }
  combine_kernel<<<dim3(2048), dim3(256), 0, stream>>>(out, eout, posA, posB);
}

// Round 11
// 937.246 us; speedup vs baseline: 1.2478x; 1.0695x over previous
//
#include <hip/hip_runtime.h>

// TransformerBlock (attn + MLP + top2-MoE) on MI355X.
// Pre-gate chain in split-fp16 3-term MFMA (fp32-class accuracy so the MoE
// top-2 selection matches the fp32 reference); post-gate experts in plain
// fp16 MFMA, SPARSE top-2 dispatch, atomic-free scatter.
// R11: moe1/moe2 retiled 64x128, single-buffer 24KB LDS -> 6 blocks/CU
// (m97/m114 lesson: occupancy-driven implicit overlap beats 2-deep dbuf
// when the grid is block-starved). Grids 4x wider, XCD-chunked.

typedef _Float16 f16;
typedef _Float16 f16x4 __attribute__((ext_vector_type(4)));
typedef _Float16 f16x8 __attribute__((ext_vector_type(8)));
typedef float f32x4 __attribute__((ext_vector_type(4)));
typedef unsigned short ushort;

#define MFMA16(a, b, c) __builtin_amdgcn_mfma_f32_16x16x32_f16((a), (b), (c), 0, 0, 0)

__device__ __forceinline__ void gload16(void* lds, const void* g) {
  __builtin_amdgcn_global_load_lds(
      (const __attribute__((address_space(1))) unsigned int*)g,
      (__attribute__((address_space(3))) unsigned int*)lds, 16, 0, 0);
}

__device__ __forceinline__ void split2(float t, f16& h, f16& l) {
  h = (f16)t;
  l = (f16)(t - (float)h);
}

__device__ __forceinline__ float gelu_f(float x) {  // exact (pre-gate path)
  return 0.5f * x * (1.0f + erff(x * 0.70710678118654752f));
}

__device__ __forceinline__ float gelu_fast(float x) {  // tanh-approx (post-gate experts)
  return x / (1.0f + __expf(-1.5957691216f * (x + 0.044715f * x * x * x)));
}

// ---------------- LayerNorm: one wave per row of 768; split-fp16 planes out ----------------
__global__ __launch_bounds__(256) void ln_kernel(
    const float* __restrict__ x, const float* __restrict__ gam,
    const float* __restrict__ bet, f16* __restrict__ oh, f16* __restrict__ ol) {
  const int w = threadIdx.x >> 6, lane = threadIdx.x & 63;
  const size_t row = (size_t)blockIdx.x * 4 + w;
  const float* xr = x + row * 768;
  f32x4 v[3];
  float s = 0.0f;
#pragma unroll
  for (int c = 0; c < 3; c++) {
    v[c] = *(const f32x4*)(xr + c * 256 + lane * 4);
    s += v[c][0] + v[c][1] + v[c][2] + v[c][3];
  }
#pragma unroll
  for (int off = 32; off; off >>= 1) s += __shfl_xor(s, off);
  const float mean = s * (1.0f / 768.0f);
  float q = 0.0f;
#pragma unroll
  for (int c = 0; c < 3; c++)
#pragma unroll
    for (int j = 0; j < 4; j++) {
      float d = v[c][j] - mean;
      q += d * d;
    }
#pragma unroll
  for (int off = 32; off; off >>= 1) q += __shfl_xor(q, off);
  // precise rsqrt: rsqrtf() approx (~1e-5 rel) would risk gate flips downstream
  const float rstd = 1.0f / sqrtf(q * (1.0f / 768.0f) + 1e-5f);
#pragma unroll
  for (int c = 0; c < 3; c++) {
    const int col = c * 256 + lane * 4;
    f32x4 gv = *(const f32x4*)(gam + col);
    f32x4 bv = *(const f32x4*)(bet + col);
    f16x4 yh, yl;
#pragma unroll
    for (int j = 0; j < 4; j++) {
      float y = (v[c][j] - mean) * rstd * gv[j] + bv[j];
      f16 hh, ll;
      split2(y, hh, ll);
      yh[j] = hh;
      yl[j] = ll;
    }
    *(f16x4*)(oh + row * 768 + col) = yh;
    *(f16x4*)(ol + row * 768 + col) = yl;
  }
}

// ---------------- fp32 -> split fp16 (elementwise, x4) ----------------
__global__ __launch_bounds__(256) void convert_split_k(
    const float* __restrict__ in, f16* __restrict__ oh, f16* __restrict__ ol,
    int n4) {
  const int i = blockIdx.x * 256 + threadIdx.x;
  if (i >= n4) return;
  f32x4 v = ((const f32x4*)in)[i];
  f16x4 h, l;
#pragma unroll
  for (int j = 0; j < 4; j++) {
    f16 hh, ll;
    split2(v[j], hh, ll);
    h[j] = hh;
    l[j] = ll;
  }
  ((f16x4*)oh)[i] = h;
  ((f16x4*)ol)[i] = l;
}

// ---------------- fp32 [R][ldin] (32x32 tiles) -> fp16 [C][R] split ----------------
__global__ __launch_bounds__(256) void transpose_k(
    const float* __restrict__ in, f16* __restrict__ oh, f16* __restrict__ ol,
    int R, int ldin) {
  __shared__ float t[32][33];
  const int tx = threadIdx.x & 31, ty = threadIdx.x >> 5;
  const int r0 = blockIdx.y * 32, c0 = blockIdx.x * 32;
#pragma unroll
  for (int i = 0; i < 4; i++)
    t[ty + 8 * i][tx] = in[(size_t)(r0 + ty + 8 * i) * ldin + c0 + tx];
  __syncthreads();
#pragma unroll
  for (int i = 0; i < 4; i++) {
    const float val = t[tx][ty + 8 * i];
    const size_t o = (size_t)(c0 + ty + 8 * i) * R + r0 + tx;
    f16 hh, ll;
    split2(val, hh, ll);
    oh[o] = hh;
    ol[o] = ll;
  }
}

// ---------------- per-expert fp32 [R][C] -> f16 [C][R] (blockIdx.z = expert) ----------------
__global__ __launch_bounds__(256) void etrans_kernel(
    const float* __restrict__ in0, f16* __restrict__ out0, int R, int C) {
  const size_t eoff = (size_t)blockIdx.z * R * C;
  const float* in = in0 + eoff;
  f16* out = out0 + eoff;
  __shared__ float t[32][33];
  const int tx = threadIdx.x & 31, ty = threadIdx.x >> 5;
  const int r0 = blockIdx.y * 32, c0 = blockIdx.x * 32;
#pragma unroll
  for (int i = 0; i < 4; i++)
    t[ty + 8 * i][tx] = in[(size_t)(r0 + ty + 8 * i) * C + c0 + tx];
  __syncthreads();
#pragma unroll
  for (int i = 0; i < 4; i++)
    out[(size_t)(c0 + ty + 8 * i) * R + r0 + tx] = (f16)t[tx][ty + 8 * i];
}

// ---------------- V transpose: qkv planes (v part) -> [B,H,64,1024]; z = hi/lo ----------------
__global__ __launch_bounds__(256) void vtrans_kernel(
    const ushort* __restrict__ srcH, const ushort* __restrict__ srcL,
    ushort* __restrict__ dstH, ushort* __restrict__ dstL) {
  const int nt = blockIdx.x, bh = blockIdx.y;
  const ushort* src = blockIdx.z ? srcL : srcH;
  ushort* dst = blockIdx.z ? dstL : dstH;
  const int b = bh / 12, h = bh % 12;
  __shared__ ushort t[64][65];
  const int tid = threadIdx.x;
#pragma unroll
  for (int i = 0; i < 16; i++) {
    const int idx = i * 256 + tid;
    const int r = idx >> 6, c = idx & 63;
    t[r][c] = src[((size_t)b * 1024 + nt * 64 + r) * 2304 + 1536 + h * 64 + c];
  }
  __syncthreads();
#pragma unroll
  for (int i = 0; i < 16; i++) {
    const int idx = i * 256 + tid;
    const int d = idx >> 6, n = idx & 63;
    dst[((size_t)bh * 64 + d) * 1024 + nt * 64 + n] = t[n][d];
  }
}

// ---------------- split-fp16 3-term GEMM: C = A·B^T (+bias), A[M,K] B[N,K] ----------------
// 128x128 tile, BK=64, 4 waves (2x2). Row-major LDS [128][64]f16 (=128B rows),
// XOR chunk-swizzle; staging: lane L -> row L>>3, global chunk (L&7)^((L>>3)&7).
// Single-buffered 64KB LDS (2 blocks/CU). XCD-chunked 1-D grid (nbx = N tiles).
template <int MODE>
__global__ __launch_bounds__(256) void gemm_split(
    const f16* __restrict__ Ah, const f16* __restrict__ Al, int lda,
    const f16* __restrict__ Bh, const f16* __restrict__ Bl, int ldb,
    const float* __restrict__ bias, const float* __restrict__ residF,
    const f16* __restrict__ residH, const f16* __restrict__ residL, int addto,
    float* __restrict__ outF, f16* __restrict__ outH, f16* __restrict__ outL,
    int ldo, int K, int nbx) {
  __shared__ __align__(16) f16 Ash[128][64];
  __shared__ __align__(16) f16 Asl[128][64];
  __shared__ __align__(16) f16 Bsh[128][64];
  __shared__ __align__(16) f16 Bsl[128][64];
  const int per = gridDim.x >> 3;
  const int lin = ((int)blockIdx.x & 7) * per + ((int)blockIdx.x >> 3);
  const int bx = lin % nbx, by = lin / nbx;
  const int tid = threadIdx.x;
  const int lane = tid & 63, wid = tid >> 6;
  const int wm = wid >> 1, wn = wid & 1;
  const int g = lane >> 4, lr = lane & 15;
  const int swz = (((tid & 7) ^ ((tid >> 3) & 7)) << 3);  // element offset
  const size_t m0 = (size_t)by * 128, n0 = (size_t)bx * 128;
  f32x4 acc[4][4] = {};
  for (int k0 = 0; k0 < K; k0 += 64) {
    __syncthreads();
#pragma unroll
    for (int s = 0; s < 4; s++) {
      const int u = s * 256 + tid;  // 16B unit within a 16KB plane
      const int row = u >> 3;
      const size_t ga = (m0 + row) * (size_t)lda + k0 + swz;
      const size_t gb = (n0 + row) * (size_t)ldb + k0 + swz;
      gload16(&Ash[0][0] + u * 8, Ah + ga);
      gload16(&Asl[0][0] + u * 8, Al + ga);
      gload16(&Bsh[0][0] + u * 8, Bh + gb);
      gload16(&Bsl[0][0] + u * 8, Bl + gb);
    }
    __syncthreads();
#pragma unroll
    for (int kk = 0; kk < 2; kk++) {
      f16x8 fah[4], fal[4], fbh[4], fbl[4];
#pragma unroll
      for (int mi = 0; mi < 4; mi++) {
        const int row = wm * 64 + mi * 16 + lr;
        const int c = (((kk * 4 + g) ^ (lr & 7)) << 3);
        fah[mi] = *(const f16x8*)&Ash[row][c];
        fal[mi] = *(const f16x8*)&Asl[row][c];
      }
#pragma unroll
      for (int ni = 0; ni < 4; ni++) {
        const int row = wn * 64 + ni * 16 + lr;
        const int c = (((kk * 4 + g) ^ (lr & 7)) << 3);
        fbh[ni] = *(const f16x8*)&Bsh[row][c];
        fbl[ni] = *(const f16x8*)&Bsl[row][c];
      }
#pragma unroll
      for (int mi = 0; mi < 4; mi++)
#pragma unroll
        for (int ni = 0; ni < 4; ni++) {
          acc[mi][ni] = MFMA16(fah[mi], fbh[ni], acc[mi][ni]);
          acc[mi][ni] = MFMA16(fah[mi], fbl[ni], acc[mi][ni]);
          acc[mi][ni] = MFMA16(fal[mi], fbh[ni], acc[mi][ni]);
        }
    }
  }
#pragma unroll
  for (int ni = 0; ni < 4; ni++) {
    const size_t col = n0 + wn * 64 + ni * 16 + lr;
    const float bv = bias ? bias[col] : 0.0f;
#pragma unroll
    for (int mi = 0; mi < 4; mi++) {
      const size_t rowb = m0 + wm * 64 + mi * 16 + g * 4;
      const f32x4 c = acc[mi][ni];
#pragma unroll
      for (int r = 0; r < 4; r++) {
        const size_t idx = (rowb + r) * (size_t)ldo + col;
        const float v = c[r] + bv;
        if constexpr (MODE == 0) {
          f16 hh, ll;
          split2(v, hh, ll);
          outH[idx] = hh;
          outL[idx] = ll;
        } else if constexpr (MODE == 1) {
          const float tt = v + residF[idx];
          f16 hh, ll;
          split2(tt, hh, ll);
          outH[idx] = hh;
          outL[idx] = ll;
        } else if constexpr (MODE == 2) {
          const float tt = gelu_f(v);
          f16 hh, ll;
          split2(tt, hh, ll);
          outH[idx] = hh;
          outL[idx] = ll;
        } else {
          outF[idx] = addto ? (outF[idx] + v)
                            : ((float)residH[idx] + (float)residL[idx] + v);
        }
      }
    }
  }
}

// ---------------- MoE expert GEMM 1: 64x128 tile, single-buffer 24KB, indirect A ----------------
// 1-D grid 3168 (= 12 x 264). ehid[gr][1536] = gelu_fast(xm[list] . w1t[e] + b1).
__global__ __launch_bounds__(256) void gemm_moe1(
    const f16* __restrict__ xmh, const f16* __restrict__ etw1,
    const float* __restrict__ eb1, const int* __restrict__ lists,
    const int* __restrict__ cnts, const int* __restrict__ starts,
    f16* __restrict__ ehid, int hf) {
  const int per = gridDim.x >> 3;  // 3168/8 = 396
  const int lin = (blockIdx.x & 7) * per + (blockIdx.x >> 3);
  const int bx = lin % 12, by = lin / 12;
  const int m0 = by * 64;
  if (m0 >= starts[4]) return;
  int e = 0;
  while (e < 3 && m0 >= starts[e + 1]) e++;
  const int cnt = cnts[e];
  const int loc0 = m0 - starts[e];
  const int* list = lists + e * 8192;
  const f16* Bw = etw1 + ((size_t)e * 3072 + hf * 1536) * 768;
  const float* bias = eb1 + e * 3072 + hf * 1536;
  __shared__ __align__(16) f16 As[64][64];   // 8 KB
  __shared__ __align__(16) f16 Bs[128][64];  // 16 KB
  const int tid = threadIdx.x;
  const int lane = tid & 63, wn = tid >> 6;  // wave -> 32-col slice
  const int g = lane >> 4, lr = lane & 15;
  const int swz = (((tid & 7) ^ ((tid >> 3) & 7)) << 3);
  const int n0 = bx * 128;
  size_t arow[2];
#pragma unroll
  for (int s = 0; s < 2; s++) {
    const int row = (s * 256 + tid) >> 3;
    const int loc = loc0 + row;
    arow[s] = (size_t)list[loc < cnt ? loc : cnt - 1] * 768;
  }
  f32x4 acc[4][2] = {};
  for (int k0 = 0; k0 < 768; k0 += 64) {
    __syncthreads();
#pragma unroll
    for (int s = 0; s < 2; s++) {
      const int u = s * 256 + tid;
      gload16(&As[0][0] + u * 8, xmh + arow[s] + k0 + swz);
    }
#pragma unroll
    for (int s = 0; s < 4; s++) {
      const int u = s * 256 + tid;
      const int row = u >> 3;
      gload16(&Bs[0][0] + u * 8, Bw + (size_t)(n0 + row) * 768 + k0 + swz);
    }
    __syncthreads();
#pragma unroll
    for (int kk = 0; kk < 2; kk++) {
      const int c = (((kk * 4 + g) ^ (lr & 7)) << 3);
      f16x8 fa[4], fb[2];
#pragma unroll
      for (int mi = 0; mi < 4; mi++) fa[mi] = *(const f16x8*)&As[mi * 16 + lr][c];
#pragma unroll
      for (int ni = 0; ni < 2; ni++)
        fb[ni] = *(const f16x8*)&Bs[wn * 32 + ni * 16 + lr][c];
#pragma unroll
      for (int mi = 0; mi < 4; mi++)
#pragma unroll
        for (int ni = 0; ni < 2; ni++)
          acc[mi][ni] = MFMA16(fa[mi], fb[ni], acc[mi][ni]);
    }
  }
#pragma unroll
  for (int ni = 0; ni < 2; ni++) {
    const int col = n0 + wn * 32 + ni * 16 + lr;
    const float bv = bias[col];
#pragma unroll
    for (int mi = 0; mi < 4; mi++) {
      const int gr = m0 + mi * 16 + g * 4;
      const f32x4 c = acc[mi][ni];
#pragma unroll
      for (int r = 0; r < 4; r++)
        ehid[(size_t)(gr + r) * 1536 + col] = (f16)gelu_fast(c[r] + bv);
    }
  }
}

// ---------------- MoE expert GEMM 2: 64x128 tile, single-buffer 24KB, NO atomics ----------------
// 1-D grid 1584 (= 6 x 264). eout[gr] (f16) = w*(acc+b2) (hf0) / += w*acc (hf1).
__global__ __launch_bounds__(256) void gemm_moe2(
    const f16* __restrict__ ehid, const f16* __restrict__ etw2,
    const float* __restrict__ eb2, const float* __restrict__ comb,
    const int* __restrict__ lists, const int* __restrict__ cnts,
    const int* __restrict__ starts, f16* __restrict__ eout, int hf) {
  const int per = gridDim.x >> 3;  // 1584/8 = 198
  const int lin = (blockIdx.x & 7) * per + (blockIdx.x >> 3);
  const int bx = lin % 6, by = lin / 6;
  const int m0 = by * 64;
  if (m0 >= starts[4]) return;
  int e = 0;
  while (e < 3 && m0 >= starts[e + 1]) e++;
  const int cnt = cnts[e];
  const int st = starts[e];
  const int* list = lists + e * 8192;
  const f16* Bw = etw2 + (size_t)e * 768 * 3072 + hf * 1536;
  __shared__ __align__(16) f16 As[64][64];   // 8 KB
  __shared__ __align__(16) f16 Bs[128][64];  // 16 KB
  const int tid = threadIdx.x;
  const int lane = tid & 63, wn = tid >> 6;
  const int g = lane >> 4, lr = lane & 15;
  const int swz = (((tid & 7) ^ ((tid >> 3) & 7)) << 3);
  const int n0 = bx * 128;
  f32x4 acc[4][2] = {};
  for (int k0 = 0; k0 < 1536; k0 += 64) {
    __syncthreads();
#pragma unroll
    for (int s = 0; s < 2; s++) {
      const int u = s * 256 + tid;
      const int row = u >> 3;
      gload16(&As[0][0] + u * 8, ehid + (size_t)(m0 + row) * 1536 + k0 + swz);
    }
#pragma unroll
    for (int s = 0; s < 4; s++) {
      const int u = s * 256 + tid;
      const int row = u >> 3;
      gload16(&Bs[0][0] + u * 8, Bw + (size_t)(n0 + row) * 3072 + k0 + swz);
    }
    __syncthreads();
#pragma unroll
    for (int kk = 0; kk < 2; kk++) {
      const int c = (((kk * 4 + g) ^ (lr & 7)) << 3);
      f16x8 fa[4], fb[2];
#pragma unroll
      for (int mi = 0; mi < 4; mi++) fa[mi] = *(const f16x8*)&As[mi * 16 + lr][c];
#pragma unroll
      for (int ni = 0; ni < 2; ni++)
        fb[ni] = *(const f16x8*)&Bs[wn * 32 + ni * 16 + lr][c];
#pragma unroll
      for (int mi = 0; mi < 4; mi++)
#pragma unroll
        for (int ni = 0; ni < 2; ni++)
          acc[mi][ni] = MFMA16(fa[mi], fb[ni], acc[mi][ni]);
    }
  }
#pragma unroll
  for (int ni = 0; ni < 2; ni++) {
    const int col = n0 + wn * 32 + ni * 16 + lr;
    const float bv = hf ? 0.0f : eb2[e * 768 + col];
#pragma unroll
    for (int mi = 0; mi < 4; mi++) {
      const int gr = m0 + mi * 16 + g * 4;
      const f32x4 c = acc[mi][ni];
#pragma unroll
      for (int r = 0; r < 4; r++) {
        const int loc = gr + r - st;
        if (loc < cnt) {
          const int tok = list[loc];
          const float w = comb[(size_t)tok * 4 + e];
          const size_t oi = (size_t)(gr + r) * 768 + col;
          const float v = w * (c[r] + bv);
          eout[oi] = hf ? (f16)((float)eout[oi] + v) : (f16)v;
        }
      }
    }
  }
}

// ---------------- final combine: out[t] = x2[t] + eout[posA[t]] + eout[posB[t]] ----------------
__global__ __launch_bounds__(256) void combine_kernel(
    float* __restrict__ out, const f16* __restrict__ eout,
    const int* __restrict__ posA, const int* __restrict__ posB) {
  const int w = threadIdx.x >> 6, lane = threadIdx.x & 63;
  const size_t row = (size_t)blockIdx.x * 4 + w;
  const size_t pa = (size_t)posA[row] * 768, pb = (size_t)posB[row] * 768;
#pragma unroll
  for (int c = 0; c < 3; c++) {
    const int col = c * 256 + lane * 4;
    f32x4 v = *(const f32x4*)(out + row * 768 + col);
    const f16x4 a = *(const f16x4*)(eout + pa + col);
    const f16x4 b = *(const f16x4*)(eout + pb + col);
#pragma unroll
    for (int j = 0; j < 4; j++) v[j] += (float)a[j] + (float)b[j];
    *(f32x4*)(out + row * 768 + col) = v;
  }
}

// ---------------- flash attention, KVBLK=64, precision-trimmed ----------------
// 1536 blocks, XCD-swizzled. No-max softmax P=exp(s/8); row-sum via MFMA x ones.
// QK: q_hi x (k_hi + k_lo). PV: P single fp16 plane x (v_hi + v_lo).
__global__ __launch_bounds__(256) void attn_kernel(
    const f16* __restrict__ qh, const f16* __restrict__ ql,
    const f16* __restrict__ vth, const f16* __restrict__ vtl,
    f16* __restrict__ ch, f16* __restrict__ cl) {
  const int wg = blockIdx.y * 16 + blockIdx.x;          // 0..1535
  const int nid = (wg & 7) * 192 + (wg >> 3);           // bijective (1536%8==0)
  const int qt = nid & 15, bh = nid >> 4;
  const int b = bh / 12, h = bh % 12;
  const int tid = threadIdx.x;
  const int lane = tid & 63, w = tid >> 6;
  const int g = lane >> 4, lr = lane & 15;
  __shared__ __align__(16) f16 Ksh[64][64];
  __shared__ __align__(16) f16 Ksl[64][64];
  __shared__ __align__(16) f16 Vsh[64][64];
  __shared__ __align__(16) f16 Vsl[64][64];
  __shared__ __align__(16) char Psh[4][2048];  // per-wave P (16 x 64 f16), XOR-swizzled
  const int swz = (((tid & 7) ^ ((tid >> 3) & 7)) << 3);
  const size_t qrow = (size_t)b * 1024 + qt * 64 + w * 16 + lr;
  const f16* qbh = qh + qrow * 2304 + h * 64;
  const f16x8 qfh0 = *(const f16x8*)(qbh + g * 8);
  const f16x8 qfh1 = *(const f16x8*)(qbh + 32 + g * 8);
  const f16x8 ones = {(f16)1, (f16)1, (f16)1, (f16)1, (f16)1, (f16)1, (f16)1, (f16)1};
  f32x4 o[4] = {};
  f32x4 osum = {};
  const f16* kbh = qh + ((size_t)b * 1024) * 2304 + 768 + h * 64;
  const f16* kbl = ql + ((size_t)b * 1024) * 2304 + 768 + h * 64;
  const f16* vbh = vth + (size_t)bh * 64 * 1024;
  const f16* vbl = vtl + (size_t)bh * 64 * 1024;
  char* pbh = Psh[w];
  for (int kv0 = 0; kv0 < 1024; kv0 += 64) {
    __syncthreads();
#pragma unroll
    for (int s = 0; s < 2; s++) {
      const int u = s * 256 + tid;  // 16B unit within an 8KB plane
      const int row = u >> 3;
      const size_t ko = (size_t)(kv0 + row) * 2304 + swz;
      gload16(&Ksh[0][0] + u * 8, kbh + ko);
      gload16(&Ksl[0][0] + u * 8, kbl + ko);
      const size_t vo = (size_t)row * 1024 + kv0 + swz;  // row = d
      gload16(&Vsh[0][0] + u * 8, vbh + vo);
      gload16(&Vsl[0][0] + u * 8, vbl + vo);
    }
    __syncthreads();
    f32x4 s[4];
    __builtin_amdgcn_s_setprio(1);
#pragma unroll
    for (int nb = 0; nb < 4; nb++) {
      const int row = nb * 16 + lr;
      const int c0 = ((g ^ (lr & 7)) << 3);
      const int c1 = (((4 + g) ^ (lr & 7)) << 3);
      const f16x8 kh0 = *(const f16x8*)&Ksh[row][c0];
      const f16x8 kh1 = *(const f16x8*)&Ksh[row][c1];
      const f16x8 kl0 = *(const f16x8*)&Ksl[row][c0];
      const f16x8 kl1 = *(const f16x8*)&Ksl[row][c1];
      f32x4 t = {};
      t = MFMA16(qfh0, kh0, t);
      t = MFMA16(qfh1, kh1, t);
      t = MFMA16(qfh0, kl0, t);
      t = MFMA16(qfh1, kl1, t);
      s[nb] = t;
    }
    __builtin_amdgcn_s_setprio(0);
    // P = exp(s/8), no max subtraction (shift-invariant; overflow at 35 sigma)
#pragma unroll
    for (int nb = 0; nb < 4; nb++)
#pragma unroll
      for (int r = 0; r < 4; r++) {
        const int row = g * 4 + r;
        const int sw = ((nb * 16 + lr) * 2) ^ ((row & 7) << 4);
        *(f16*)(pbh + row * 128 + sw) = (f16)__expf(s[nb][r] * 0.125f);
      }
    // PV + row-sum via MFMA x ones
    __builtin_amdgcn_s_setprio(1);
#pragma unroll
    for (int ks = 0; ks < 2; ks++) {
      const int pc = (ks * 64 + g * 16) ^ ((lr & 7) << 4);
      const f16x8 pfh = *(const f16x8*)(pbh + lr * 128 + pc);
      osum = MFMA16(pfh, ones, osum);
#pragma unroll
      for (int db = 0; db < 4; db++) {
        const int vrow = db * 16 + lr;
        const int vc = (((ks * 4 + g) ^ (lr & 7)) << 3);
        const f16x8 vfh = *(const f16x8*)&Vsh[vrow][vc];
        const f16x8 vfl = *(const f16x8*)&Vsl[vrow][vc];
        o[db] = MFMA16(pfh, vfh, o[db]);
        o[db] = MFMA16(pfh, vfl, o[db]);
      }
    }
    __builtin_amdgcn_s_setprio(0);
  }
  const size_t orow = (size_t)b * 1024 + qt * 64 + w * 16 + g * 4;
#pragma unroll
  for (int r = 0; r < 4; r++) {
    const float inv = 1.0f / osum[r];
#pragma unroll
    for (int db = 0; db < 4; db++) {
      const float val = o[db][r] * inv;
      const size_t oi = (orow + r) * 768 + h * 64 + db * 16 + lr;
      f16 hh, ll;
      split2(val, hh, ll);
      ch[oi] = hh;
      cl[oi] = ll;
    }
  }
}

// ---------------- gate: fp32 logits from split xm, top-2, softmax -> comb[T][4] ----------------
__global__ __launch_bounds__(256) void gate_kernel(
    const f16* __restrict__ xmh, const f16* __restrict__ xml,
    const float* __restrict__ gw, const float* __restrict__ gb,
    float* __restrict__ comb) {
  const int t = blockIdx.x * 256 + threadIdx.x;
  const f16* xrh = xmh + (size_t)t * 768;
  const f16* xrl = xml + (size_t)t * 768;
  float a0 = 0, a1 = 0, a2 = 0, a3 = 0;
  for (int k = 0; k < 768; k += 4) {
    const f16x4 xh = *(const f16x4*)(xrh + k);
    const f16x4 xl = *(const f16x4*)(xrl + k);
    const f32x4 w0 = *(const f32x4*)(gw + k);
    const f32x4 w1 = *(const f32x4*)(gw + 768 + k);
    const f32x4 w2 = *(const f32x4*)(gw + 1536 + k);
    const f32x4 w3 = *(const f32x4*)(gw + 2304 + k);
#pragma unroll
    for (int j = 0; j < 4; j++) {
      const float xv = (float)xh[j] + (float)xl[j];
      a0 += xv * w0[j];
      a1 += xv * w1[j];
      a2 += xv * w2[j];
      a3 += xv * w3[j];
    }
  }
  float l[4] = {a0 + gb[0], a1 + gb[1], a2 + gb[2], a3 + gb[3]};
  int i0 = 0;
#pragma unroll
  for (int e = 1; e < 4; e++)
    if (l[e] > l[i0]) i0 = e;  // strict > matches top_k tie order
  int i1 = -1;
#pragma unroll
  for (int e = 0; e < 4; e++)
    if (e != i0 && (i1 < 0 || l[e] > l[i1])) i1 = e;
  const float e1 = expf(l[i1] - l[i0]);
  const float inv = 1.0f / (1.0f + e1);
  float c[4] = {0.0f, 0.0f, 0.0f, 0.0f};
  c[i0] = inv;
  c[i1] = e1 * inv;
  f32x4 cv = {c[0], c[1], c[2], c[3]};
  *(f32x4*)(comb + (size_t)t * 4) = cv;
}

// ---------------- per-expert token lists + 128-aligned segment starts + inverse map ----------------
__global__ __launch_bounds__(1024) void listbuild_kernel(
    const float* __restrict__ comb, int* __restrict__ lists /*[4][8192]*/,
    int* __restrict__ cnts /*[4]*/, int* __restrict__ starts /*[5]*/,
    int* __restrict__ posA /*[8192]*/, int* __restrict__ posB /*[8192]*/) {
  __shared__ int wsum[16];
  const int tid = threadIdx.x;
  const int lane = tid & 63, wv = tid >> 6;
  unsigned seen = 0;  // bit c: token c*1024+tid already assigned once
  int segbase = 0;    // padded global segment base (identical on all threads)
  for (int e = 0; e < 4; e++) {
    int base = 0;
    for (int c = 0; c < 8; c++) {
      const int t = c * 1024 + tid;
      const int flag = comb[(size_t)t * 4 + e] > 0.0f ? 1 : 0;
      const unsigned long long mask = __ballot(flag);
      const int myrank = __popcll(mask & ((1ull << lane) - 1ull));
      if (lane == 0) wsum[wv] = __popcll(mask);
      __syncthreads();
      int wbase = 0, total = 0;
#pragma unroll
      for (int i = 0; i < 16; i++) {
        if (i < wv) wbase += wsum[i];
        total += wsum[i];
      }
      if (flag) {
        const int idx = base + wbase + myrank;
        lists[e * 8192 + idx] = t;
        const int gidx = segbase + idx;
        if ((seen >> c) & 1) posB[t] = gidx;
        else { posA[t] = gidx; seen |= 1u << c; }
      }
      base += total;
      __syncthreads();
    }
    if (tid == 0) cnts[e] = base;
    segbase += (base + 127) & ~127;
  }
  if (tid == 0) {
    int s = 0;
    starts[0] = 0;
#pragma unroll
    for (int e = 0; e < 4; e++) {
      s += (cnts[e] + 127) & ~127;
      starts[e + 1] = s;
    }
  }
}

extern "C" void kernel_launch(void* const* d_in, const int* in_sizes, int n_in,
                              void* d_out, int out_size, void* d_ws,
                              size_t ws_size, hipStream_t stream) {
  const float* x = (const float*)d_in[0];
  const float* ln1g = (const float*)d_in[1];
  const float* ln1b = (const float*)d_in[2];
  const float* in_w = (const float*)d_in[3];
  const float* in_b = (const float*)d_in[4];
  const float* out_w = (const float*)d_in[5];
  const float* out_b = (const float*)d_in[6];
  const float* mlp_w1 = (const float*)d_in[7];
  const float* mlp_b1 = (const float*)d_in[8];
  const float* mlp_w2 = (const float*)d_in[9];
  const float* mlp_b2 = (const float*)d_in[10];
  const float* ln2g = (const float*)d_in[11];
  const float* ln2b = (const float*)d_in[12];
  const float* gate_w = (const float*)d_in[13];
  const float* gate_b = (const float*)d_in[14];
  const float* exp_w1 = (const float*)d_in[15];
  const float* exp_b1 = (const float*)d_in[16];
  const float* exp_w2 = (const float*)d_in[17];
  const float* exp_b2 = (const float*)d_in[18];
  float* out = (float*)d_out;
  (void)in_sizes; (void)n_in; (void)out_size;

  const size_t MB = 1ull << 20;
  if (ws_size < 130 * MB) return;  // clean absmax failure (not a crash) if ws too small
  char* ws = (char*)d_ws;
  // Pre-MoE layout (as R6-R10, lifetimes hand-verified):
  // S1 [0,24MB):   h planes -> attn ctx planes -> w1t planes -> xm planes
  // S2 [24,33MB):  in_w+out_w planes -> w2t planes
  // S3 [33,105MB): qkv planes -> mlp hid planes
  // S4 [105,129MB): vt planes -> x1 planes
  // MoE phase (everything except xmh [0,12MB) is dead after gate):
  //   etw1 [12,30) etw2 [30,48) ehid [48,100) eout(f16) [100,126)
  // S5 [129MB..): comb, lists, cnts, starts, posA, posB
  char* S1 = ws;
  char* S2 = ws + 24 * MB;
  char* S3 = ws + 33 * MB;
  char* S4 = ws + 105 * MB;
  char* S5 = ws + 129 * MB;

  f16* h_h = (f16*)S1;                       // 12,582,912 B each
  f16* h_l = (f16*)(S1 + 12 * MB);
  f16* ctx_h = (f16*)S1;                     // after qkv gemm, h dead
  f16* ctx_l = (f16*)(S1 + 12 * MB);
  f16* w1t_h = (f16*)S1;                     // after out-proj, ctx dead
  f16* w1t_l = (f16*)(S1 + 4718592);
  f16* xmh = (f16*)S1;                       // after mlp, w1t dead
  f16* xml = (f16*)(S1 + 12 * MB);           // dead after gate

  f16* inw_h = (f16*)S2;                     // 3,538,944 B each
  f16* inw_l = (f16*)(S2 + 3538944);
  f16* outw_h = (f16*)(S2 + 7077888);        // 1,179,648 B each
  f16* outw_l = (f16*)(S2 + 8257536);
  f16* w2t_h = (f16*)S2;                     // after out-proj, inw/outw dead
  f16* w2t_l = (f16*)(S2 + 4718592);

  f16* qkv_h = (f16*)S3;                     // 37,748,736 B each
  f16* qkv_l = (f16*)(S3 + 36 * MB);
  f16* hid_h = (f16*)S3;                     // after attn, qkv dead; [8192][1536] each
  f16* hid_l = (f16*)(S3 + 24 * MB);

  f16* vt_h = (f16*)S4;                      // 12,582,912 B each
  f16* vt_l = (f16*)(S4 + 12 * MB);
  f16* x1h = (f16*)S4;                       // after attn, vt dead
  f16* x1l = (f16*)(S4 + 12 * MB);

  // MoE-phase scratch (xml/w2t/hid/x1 all dead by first use):
  f16* etw1 = (f16*)(ws + 12 * MB);          // [4][3072][768] f16 = 18MB
  f16* etw2 = (f16*)(ws + 30 * MB);          // [4][768][3072] f16 = 18MB
  f16* ehid = (f16*)(ws + 48 * MB);          // [16896][1536] f16 = 51.9MB
  f16* eout = (f16*)(ws + 100 * MB);         // [16896][768] f16 = 25.9MB

  float* comb = (float*)S5;                  // 131,072 B
  int* lists = (int*)(S5 + 131072);          // 4 x 8192 ints
  int* cnts = (int*)(S5 + 262144);           // 4 ints
  int* starts = (int*)(S5 + 262144 + 64);    // 5 ints
  int* posA = (int*)(S5 + 262144 + 256);     // 8192 ints
  int* posB = (int*)(S5 + 262144 + 256 + 32768);

  // ---- attention ----
  convert_split_k<<<dim3(1728), dim3(256), 0, stream>>>(in_w, inw_h, inw_l, 442368);
  convert_split_k<<<dim3(576), dim3(256), 0, stream>>>(out_w, outw_h, outw_l, 147456);
  ln_kernel<<<dim3(2048), dim3(256), 0, stream>>>(x, ln1g, ln1b, h_h, h_l);
  gemm_split<0><<<dim3(1152), dim3(256), 0, stream>>>(
      h_h, h_l, 768, inw_h, inw_l, 768, in_b, nullptr, nullptr, nullptr, 0,
      nullptr, qkv_h, qkv_l, 2304, 768, 18);
  vtrans_kernel<<<dim3(16, 96, 2), dim3(256), 0, stream>>>(
      (const ushort*)qkv_h, (const ushort*)qkv_l, (ushort*)vt_h, (ushort*)vt_l);
  attn_kernel<<<dim3(16, 96), dim3(256), 0, stream>>>(qkv_h, qkv_l, vt_h, vt_l, ctx_h, ctx_l);
  gemm_split<1><<<dim3(384), dim3(256), 0, stream>>>(
      ctx_h, ctx_l, 768, outw_h, outw_l, 768, out_b, x, nullptr, nullptr, 0,
      nullptr, x1h, x1l, 768, 768, 6);

  // ---- MLP (hidden in two halves of 1536; result -> out (=x2, fp32)) ----
  transpose_k<<<dim3(96, 24), dim3(256), 0, stream>>>(mlp_w1, w1t_h, w1t_l, 768, 3072);
  transpose_k<<<dim3(24, 96), dim3(256), 0, stream>>>(mlp_w2, w2t_h, w2t_l, 3072, 768);
  gemm_split<2><<<dim3(768), dim3(256), 0, stream>>>(
      x1h, x1l, 768, w1t_h, w1t_l, 768, mlp_b1, nullptr, nullptr, nullptr, 0,
      nullptr, hid_h, hid_l, 1536, 768, 12);
  gemm_split<3><<<dim3(384), dim3(256), 0, stream>>>(
      hid_h, hid_l, 1536, w2t_h, w2t_l, 3072, mlp_b2, nullptr, x1h, x1l, 0,
      out, nullptr, nullptr, 768, 1536, 6);
  gemm_split<2><<<dim3(768), dim3(256), 0, stream>>>(
      x1h, x1l, 768, w1t_h + (size_t)1536 * 768, w1t_l + (size_t)1536 * 768, 768,
      mlp_b1 + 1536, nullptr, nullptr, nullptr, 0, nullptr, hid_h, hid_l, 1536, 768, 12);
  gemm_split<3><<<dim3(384), dim3(256), 0, stream>>>(
      hid_h, hid_l, 1536, w2t_h + 1536, w2t_l + 1536, 3072,
      nullptr, nullptr, nullptr, nullptr, 1, out, nullptr, nullptr, 768, 1536, 6);

  // ---- MoE (sparse top-2, segment-mapped, 64x128 tiles, atomic-free scatter) ----
  ln_kernel<<<dim3(2048), dim3(256), 0, stream>>>(out, ln2g, ln2b, xmh, xml);
  gate_kernel<<<dim3(32), dim3(256), 0, stream>>>(xmh, xml, gate_w, gate_b, comb);
  listbuild_kernel<<<dim3(1), dim3(1024), 0, stream>>>(comb, lists, cnts, starts, posA, posB);
  etrans_kernel<<<dim3(96, 24, 4), dim3(256), 0, stream>>>(exp_w1, etw1, 768, 3072);
  etrans_kernel<<<dim3(24, 96, 4), dim3(256), 0, stream>>>(exp_w2, etw2, 3072, 768);
  for (int hf = 0; hf < 2; hf++) {
    gemm_moe1<<<dim3(3168), dim3(256), 0, stream>>>(
        xmh, etw1, exp_b1, lists, cnts, starts, ehid, hf);
    gemm_moe2<<<dim3(1584), dim3(256), 0, stream>>>(
        ehid, etw2, exp_b2, comb, lists, cnts, starts, eout, hf);
  }
  combine_kernel<<<dim3(2048), dim3(256), 0, stream>>>(out, eout, posA, posB);
}

// Round 12
// 891.297 us; speedup vs baseline: 1.3121x; 1.0516x over previous
//
#include <hip/hip_runtime.h>

// TransformerBlock (attn + MLP + top2-MoE) on MI355X.
// Pre-gate chain in split-fp16 3-term MFMA (fp32-class accuracy so the MoE
// top-2 selection matches the fp32 reference); post-gate experts in plain
// fp16 MFMA, SPARSE top-2 dispatch, atomic-free scatter.
// R12: gemm_split retiled 64x128 / 48KB LDS -> 3 blocks/CU (same move that
// fixed moe2 in R11: occupancy covers the per-step vmcnt+barrier drain).

typedef _Float16 f16;
typedef _Float16 f16x4 __attribute__((ext_vector_type(4)));
typedef _Float16 f16x8 __attribute__((ext_vector_type(8)));
typedef float f32x4 __attribute__((ext_vector_type(4)));
typedef unsigned short ushort;

#define MFMA16(a, b, c) __builtin_amdgcn_mfma_f32_16x16x32_f16((a), (b), (c), 0, 0, 0)

__device__ __forceinline__ void gload16(void* lds, const void* g) {
  __builtin_amdgcn_global_load_lds(
      (const __attribute__((address_space(1))) unsigned int*)g,
      (__attribute__((address_space(3))) unsigned int*)lds, 16, 0, 0);
}

__device__ __forceinline__ void split2(float t, f16& h, f16& l) {
  h = (f16)t;
  l = (f16)(t - (float)h);
}

__device__ __forceinline__ float gelu_f(float x) {  // exact (pre-gate path)
  return 0.5f * x * (1.0f + erff(x * 0.70710678118654752f));
}

__device__ __forceinline__ float gelu_fast(float x) {  // tanh-approx (post-gate experts)
  return x / (1.0f + __expf(-1.5957691216f * (x + 0.044715f * x * x * x)));
}

// ---------------- LayerNorm: one wave per row of 768; split-fp16 planes out ----------------
__global__ __launch_bounds__(256) void ln_kernel(
    const float* __restrict__ x, const float* __restrict__ gam,
    const float* __restrict__ bet, f16* __restrict__ oh, f16* __restrict__ ol) {
  const int w = threadIdx.x >> 6, lane = threadIdx.x & 63;
  const size_t row = (size_t)blockIdx.x * 4 + w;
  const float* xr = x + row * 768;
  f32x4 v[3];
  float s = 0.0f;
#pragma unroll
  for (int c = 0; c < 3; c++) {
    v[c] = *(const f32x4*)(xr + c * 256 + lane * 4);
    s += v[c][0] + v[c][1] + v[c][2] + v[c][3];
  }
#pragma unroll
  for (int off = 32; off; off >>= 1) s += __shfl_xor(s, off);
  const float mean = s * (1.0f / 768.0f);
  float q = 0.0f;
#pragma unroll
  for (int c = 0; c < 3; c++)
#pragma unroll
    for (int j = 0; j < 4; j++) {
      float d = v[c][j] - mean;
      q += d * d;
    }
#pragma unroll
  for (int off = 32; off; off >>= 1) q += __shfl_xor(q, off);
  // precise rsqrt: rsqrtf() approx (~1e-5 rel) would risk gate flips downstream
  const float rstd = 1.0f / sqrtf(q * (1.0f / 768.0f) + 1e-5f);
#pragma unroll
  for (int c = 0; c < 3; c++) {
    const int col = c * 256 + lane * 4;
    f32x4 gv = *(const f32x4*)(gam + col);
    f32x4 bv = *(const f32x4*)(bet + col);
    f16x4 yh, yl;
#pragma unroll
    for (int j = 0; j < 4; j++) {
      float y = (v[c][j] - mean) * rstd * gv[j] + bv[j];
      f16 hh, ll;
      split2(y, hh, ll);
      yh[j] = hh;
      yl[j] = ll;
    }
    *(f16x4*)(oh + row * 768 + col) = yh;
    *(f16x4*)(ol + row * 768 + col) = yl;
  }
}

// ---------------- fp32 -> split fp16 (elementwise, x4) ----------------
__global__ __launch_bounds__(256) void convert_split_k(
    const float* __restrict__ in, f16* __restrict__ oh, f16* __restrict__ ol,
    int n4) {
  const int i = blockIdx.x * 256 + threadIdx.x;
  if (i >= n4) return;
  f32x4 v = ((const f32x4*)in)[i];
  f16x4 h, l;
#pragma unroll
  for (int j = 0; j < 4; j++) {
    f16 hh, ll;
    split2(v[j], hh, ll);
    h[j] = hh;
    l[j] = ll;
  }
  ((f16x4*)oh)[i] = h;
  ((f16x4*)ol)[i] = l;
}

// ---------------- fp32 [R][ldin] (32x32 tiles) -> fp16 [C][R] split ----------------
__global__ __launch_bounds__(256) void transpose_k(
    const float* __restrict__ in, f16* __restrict__ oh, f16* __restrict__ ol,
    int R, int ldin) {
  __shared__ float t[32][33];
  const int tx = threadIdx.x & 31, ty = threadIdx.x >> 5;
  const int r0 = blockIdx.y * 32, c0 = blockIdx.x * 32;
#pragma unroll
  for (int i = 0; i < 4; i++)
    t[ty + 8 * i][tx] = in[(size_t)(r0 + ty + 8 * i) * ldin + c0 + tx];
  __syncthreads();
#pragma unroll
  for (int i = 0; i < 4; i++) {
    const float val = t[tx][ty + 8 * i];
    const size_t o = (size_t)(c0 + ty + 8 * i) * R + r0 + tx;
    f16 hh, ll;
    split2(val, hh, ll);
    oh[o] = hh;
    ol[o] = ll;
  }
}

// ---------------- per-expert fp32 [R][C] -> f16 [C][R] (blockIdx.z = expert) ----------------
__global__ __launch_bounds__(256) void etrans_kernel(
    const float* __restrict__ in0, f16* __restrict__ out0, int R, int C) {
  const size_t eoff = (size_t)blockIdx.z * R * C;
  const float* in = in0 + eoff;
  f16* out = out0 + eoff;
  __shared__ float t[32][33];
  const int tx = threadIdx.x & 31, ty = threadIdx.x >> 5;
  const int r0 = blockIdx.y * 32, c0 = blockIdx.x * 32;
#pragma unroll
  for (int i = 0; i < 4; i++)
    t[ty + 8 * i][tx] = in[(size_t)(r0 + ty + 8 * i) * C + c0 + tx];
  __syncthreads();
#pragma unroll
  for (int i = 0; i < 4; i++)
    out[(size_t)(c0 + ty + 8 * i) * R + r0 + tx] = (f16)t[tx][ty + 8 * i];
}

// ---------------- V transpose: qkv planes (v part) -> [B,H,64,1024]; z = hi/lo ----------------
__global__ __launch_bounds__(256) void vtrans_kernel(
    const ushort* __restrict__ srcH, const ushort* __restrict__ srcL,
    ushort* __restrict__ dstH, ushort* __restrict__ dstL) {
  const int nt = blockIdx.x, bh = blockIdx.y;
  const ushort* src = blockIdx.z ? srcL : srcH;
  ushort* dst = blockIdx.z ? dstL : dstH;
  const int b = bh / 12, h = bh % 12;
  __shared__ ushort t[64][65];
  const int tid = threadIdx.x;
#pragma unroll
  for (int i = 0; i < 16; i++) {
    const int idx = i * 256 + tid;
    const int r = idx >> 6, c = idx & 63;
    t[r][c] = src[((size_t)b * 1024 + nt * 64 + r) * 2304 + 1536 + h * 64 + c];
  }
  __syncthreads();
#pragma unroll
  for (int i = 0; i < 16; i++) {
    const int idx = i * 256 + tid;
    const int d = idx >> 6, n = idx & 63;
    dst[((size_t)bh * 64 + d) * 1024 + nt * 64 + n] = t[n][d];
  }
}

// ---------------- split-fp16 3-term GEMM: C = A·B^T (+bias), A[M,K] B[N,K] ----------------
// R12: 64x128 tile, BK=64, 4 waves (1x4, 32-col slices). LDS A[64][64]x2 +
// B[128][64]x2 = 48KB -> 3 blocks/CU. Full-128B-row staging, XOR chunk-swizzle
// (pre-swizzled source + same-involution read). XCD-chunked 1-D grid.
template <int MODE>
__global__ __launch_bounds__(256) void gemm_split(
    const f16* __restrict__ Ah, const f16* __restrict__ Al, int lda,
    const f16* __restrict__ Bh, const f16* __restrict__ Bl, int ldb,
    const float* __restrict__ bias, const float* __restrict__ residF,
    const f16* __restrict__ residH, const f16* __restrict__ residL, int addto,
    float* __restrict__ outF, f16* __restrict__ outH, f16* __restrict__ outL,
    int ldo, int K, int nbx) {
  __shared__ __align__(16) f16 Ash[64][64];
  __shared__ __align__(16) f16 Asl[64][64];
  __shared__ __align__(16) f16 Bsh[128][64];
  __shared__ __align__(16) f16 Bsl[128][64];
  const int per = gridDim.x >> 3;
  const int lin = ((int)blockIdx.x & 7) * per + ((int)blockIdx.x >> 3);
  const int bx = lin % nbx, by = lin / nbx;
  const int tid = threadIdx.x;
  const int lane = tid & 63, w4 = tid >> 6;  // wave -> 32-col slice
  const int g = lane >> 4, lr = lane & 15;
  const int swz = (((tid & 7) ^ ((tid >> 3) & 7)) << 3);  // element offset
  const size_t m0 = (size_t)by * 64, n0 = (size_t)bx * 128;
  f32x4 acc[4][2] = {};
  for (int k0 = 0; k0 < K; k0 += 64) {
    __syncthreads();
#pragma unroll
    for (int s = 0; s < 2; s++) {
      const int u = s * 256 + tid;  // 16B unit within an 8KB plane
      const int row = u >> 3;
      const size_t ga = (m0 + row) * (size_t)lda + k0 + swz;
      gload16(&Ash[0][0] + u * 8, Ah + ga);
      gload16(&Asl[0][0] + u * 8, Al + ga);
    }
#pragma unroll
    for (int s = 0; s < 4; s++) {
      const int u = s * 256 + tid;  // 16B unit within a 16KB plane
      const int row = u >> 3;
      const size_t gb = (n0 + row) * (size_t)ldb + k0 + swz;
      gload16(&Bsh[0][0] + u * 8, Bh + gb);
      gload16(&Bsl[0][0] + u * 8, Bl + gb);
    }
    __syncthreads();
#pragma unroll
    for (int kk = 0; kk < 2; kk++) {
      const int c = (((kk * 4 + g) ^ (lr & 7)) << 3);
      f16x8 fah[4], fal[4], fbh[2], fbl[2];
#pragma unroll
      for (int mi = 0; mi < 4; mi++) {
        const int row = mi * 16 + lr;
        fah[mi] = *(const f16x8*)&Ash[row][c];
        fal[mi] = *(const f16x8*)&Asl[row][c];
      }
#pragma unroll
      for (int ni = 0; ni < 2; ni++) {
        const int row = w4 * 32 + ni * 16 + lr;
        fbh[ni] = *(const f16x8*)&Bsh[row][c];
        fbl[ni] = *(const f16x8*)&Bsl[row][c];
      }
#pragma unroll
      for (int mi = 0; mi < 4; mi++)
#pragma unroll
        for (int ni = 0; ni < 2; ni++) {
          acc[mi][ni] = MFMA16(fah[mi], fbh[ni], acc[mi][ni]);
          acc[mi][ni] = MFMA16(fah[mi], fbl[ni], acc[mi][ni]);
          acc[mi][ni] = MFMA16(fal[mi], fbh[ni], acc[mi][ni]);
        }
    }
  }
#pragma unroll
  for (int ni = 0; ni < 2; ni++) {
    const size_t col = n0 + w4 * 32 + ni * 16 + lr;
    const float bv = bias ? bias[col] : 0.0f;
#pragma unroll
    for (int mi = 0; mi < 4; mi++) {
      const size_t rowb = m0 + mi * 16 + g * 4;
      const f32x4 c = acc[mi][ni];
#pragma unroll
      for (int r = 0; r < 4; r++) {
        const size_t idx = (rowb + r) * (size_t)ldo + col;
        const float v = c[r] + bv;
        if constexpr (MODE == 0) {
          f16 hh, ll;
          split2(v, hh, ll);
          outH[idx] = hh;
          outL[idx] = ll;
        } else if constexpr (MODE == 1) {
          const float tt = v + residF[idx];
          f16 hh, ll;
          split2(tt, hh, ll);
          outH[idx] = hh;
          outL[idx] = ll;
        } else if constexpr (MODE == 2) {
          const float tt = gelu_f(v);
          f16 hh, ll;
          split2(tt, hh, ll);
          outH[idx] = hh;
          outL[idx] = ll;
        } else {
          outF[idx] = addto ? (outF[idx] + v)
                            : ((float)residH[idx] + (float)residL[idx] + v);
        }
      }
    }
  }
}

// ---------------- MoE expert GEMM 1: 64x128 tile, single-buffer 24KB, indirect A ----------------
// 1-D grid 3168 (= 12 x 264). ehid[gr][1536] = gelu_fast(xm[list] . w1t[e] + b1).
__global__ __launch_bounds__(256) void gemm_moe1(
    const f16* __restrict__ xmh, const f16* __restrict__ etw1,
    const float* __restrict__ eb1, const int* __restrict__ lists,
    const int* __restrict__ cnts, const int* __restrict__ starts,
    f16* __restrict__ ehid, int hf) {
  const int per = gridDim.x >> 3;  // 3168/8 = 396
  const int lin = (blockIdx.x & 7) * per + (blockIdx.x >> 3);
  const int bx = lin % 12, by = lin / 12;
  const int m0 = by * 64;
  if (m0 >= starts[4]) return;
  int e = 0;
  while (e < 3 && m0 >= starts[e + 1]) e++;
  const int cnt = cnts[e];
  const int loc0 = m0 - starts[e];
  const int* list = lists + e * 8192;
  const f16* Bw = etw1 + ((size_t)e * 3072 + hf * 1536) * 768;
  const float* bias = eb1 + e * 3072 + hf * 1536;
  __shared__ __align__(16) f16 As[64][64];   // 8 KB
  __shared__ __align__(16) f16 Bs[128][64];  // 16 KB
  const int tid = threadIdx.x;
  const int lane = tid & 63, wn = tid >> 6;  // wave -> 32-col slice
  const int g = lane >> 4, lr = lane & 15;
  const int swz = (((tid & 7) ^ ((tid >> 3) & 7)) << 3);
  const int n0 = bx * 128;
  size_t arow[2];
#pragma unroll
  for (int s = 0; s < 2; s++) {
    const int row = (s * 256 + tid) >> 3;
    const int loc = loc0 + row;
    arow[s] = (size_t)list[loc < cnt ? loc : cnt - 1] * 768;
  }
  f32x4 acc[4][2] = {};
  for (int k0 = 0; k0 < 768; k0 += 64) {
    __syncthreads();
#pragma unroll
    for (int s = 0; s < 2; s++) {
      const int u = s * 256 + tid;
      gload16(&As[0][0] + u * 8, xmh + arow[s] + k0 + swz);
    }
#pragma unroll
    for (int s = 0; s < 4; s++) {
      const int u = s * 256 + tid;
      const int row = u >> 3;
      gload16(&Bs[0][0] + u * 8, Bw + (size_t)(n0 + row) * 768 + k0 + swz);
    }
    __syncthreads();
#pragma unroll
    for (int kk = 0; kk < 2; kk++) {
      const int c = (((kk * 4 + g) ^ (lr & 7)) << 3);
      f16x8 fa[4], fb[2];
#pragma unroll
      for (int mi = 0; mi < 4; mi++) fa[mi] = *(const f16x8*)&As[mi * 16 + lr][c];
#pragma unroll
      for (int ni = 0; ni < 2; ni++)
        fb[ni] = *(const f16x8*)&Bs[wn * 32 + ni * 16 + lr][c];
#pragma unroll
      for (int mi = 0; mi < 4; mi++)
#pragma unroll
        for (int ni = 0; ni < 2; ni++)
          acc[mi][ni] = MFMA16(fa[mi], fb[ni], acc[mi][ni]);
    }
  }
#pragma unroll
  for (int ni = 0; ni < 2; ni++) {
    const int col = n0 + wn * 32 + ni * 16 + lr;
    const float bv = bias[col];
#pragma unroll
    for (int mi = 0; mi < 4; mi++) {
      const int gr = m0 + mi * 16 + g * 4;
      const f32x4 c = acc[mi][ni];
#pragma unroll
      for (int r = 0; r < 4; r++)
        ehid[(size_t)(gr + r) * 1536 + col] = (f16)gelu_fast(c[r] + bv);
    }
  }
}

// ---------------- MoE expert GEMM 2: 64x128 tile, single-buffer 24KB, NO atomics ----------------
// 1-D grid 1584 (= 6 x 264). eout[gr] (f16) = w*(acc+b2) (hf0) / += w*acc (hf1).
__global__ __launch_bounds__(256) void gemm_moe2(
    const f16* __restrict__ ehid, const f16* __restrict__ etw2,
    const float* __restrict__ eb2, const float* __restrict__ comb,
    const int* __restrict__ lists, const int* __restrict__ cnts,
    const int* __restrict__ starts, f16* __restrict__ eout, int hf) {
  const int per = gridDim.x >> 3;  // 1584/8 = 198
  const int lin = (blockIdx.x & 7) * per + (blockIdx.x >> 3);
  const int bx = lin % 6, by = lin / 6;
  const int m0 = by * 64;
  if (m0 >= starts[4]) return;
  int e = 0;
  while (e < 3 && m0 >= starts[e + 1]) e++;
  const int cnt = cnts[e];
  const int st = starts[e];
  const int* list = lists + e * 8192;
  const f16* Bw = etw2 + (size_t)e * 768 * 3072 + hf * 1536;
  __shared__ __align__(16) f16 As[64][64];   // 8 KB
  __shared__ __align__(16) f16 Bs[128][64];  // 16 KB
  const int tid = threadIdx.x;
  const int lane = tid & 63, wn = tid >> 6;
  const int g = lane >> 4, lr = lane & 15;
  const int swz = (((tid & 7) ^ ((tid >> 3) & 7)) << 3);
  const int n0 = bx * 128;
  f32x4 acc[4][2] = {};
  for (int k0 = 0; k0 < 1536; k0 += 64) {
    __syncthreads();
#pragma unroll
    for (int s = 0; s < 2; s++) {
      const int u = s * 256 + tid;
      const int row = u >> 3;
      gload16(&As[0][0] + u * 8, ehid + (size_t)(m0 + row) * 1536 + k0 + swz);
    }
#pragma unroll
    for (int s = 0; s < 4; s++) {
      const int u = s * 256 + tid;
      const int row = u >> 3;
      gload16(&Bs[0][0] + u * 8, Bw + (size_t)(n0 + row) * 3072 + k0 + swz);
    }
    __syncthreads();
#pragma unroll
    for (int kk = 0; kk < 2; kk++) {
      const int c = (((kk * 4 + g) ^ (lr & 7)) << 3);
      f16x8 fa[4], fb[2];
#pragma unroll
      for (int mi = 0; mi < 4; mi++) fa[mi] = *(const f16x8*)&As[mi * 16 + lr][c];
#pragma unroll
      for (int ni = 0; ni < 2; ni++)
        fb[ni] = *(const f16x8*)&Bs[wn * 32 + ni * 16 + lr][c];
#pragma unroll
      for (int mi = 0; mi < 4; mi++)
#pragma unroll
        for (int ni = 0; ni < 2; ni++)
          acc[mi][ni] = MFMA16(fa[mi], fb[ni], acc[mi][ni]);
    }
  }
#pragma unroll
  for (int ni = 0; ni < 2; ni++) {
    const int col = n0 + wn * 32 + ni * 16 + lr;
    const float bv = hf ? 0.0f : eb2[e * 768 + col];
#pragma unroll
    for (int mi = 0; mi < 4; mi++) {
      const int gr = m0 + mi * 16 + g * 4;
      const f32x4 c = acc[mi][ni];
#pragma unroll
      for (int r = 0; r < 4; r++) {
        const int loc = gr + r - st;
        if (loc < cnt) {
          const int tok = list[loc];
          const float w = comb[(size_t)tok * 4 + e];
          const size_t oi = (size_t)(gr + r) * 768 + col;
          const float v = w * (c[r] + bv);
          eout[oi] = hf ? (f16)((float)eout[oi] + v) : (f16)v;
        }
      }
    }
  }
}

// ---------------- final combine: out[t] = x2[t] + eout[posA[t]] + eout[posB[t]] ----------------
__global__ __launch_bounds__(256) void combine_kernel(
    float* __restrict__ out, const f16* __restrict__ eout,
    const int* __restrict__ posA, const int* __restrict__ posB) {
  const int w = threadIdx.x >> 6, lane = threadIdx.x & 63;
  const size_t row = (size_t)blockIdx.x * 4 + w;
  const size_t pa = (size_t)posA[row] * 768, pb = (size_t)posB[row] * 768;
#pragma unroll
  for (int c = 0; c < 3; c++) {
    const int col = c * 256 + lane * 4;
    f32x4 v = *(const f32x4*)(out + row * 768 + col);
    const f16x4 a = *(const f16x4*)(eout + pa + col);
    const f16x4 b = *(const f16x4*)(eout + pb + col);
#pragma unroll
    for (int j = 0; j < 4; j++) v[j] += (float)a[j] + (float)b[j];
    *(f32x4*)(out + row * 768 + col) = v;
  }
}

// ---------------- flash attention, KVBLK=64, precision-trimmed ----------------
// 1536 blocks, XCD-swizzled. No-max softmax P=exp(s/8); row-sum via MFMA x ones.
// QK: q_hi x (k_hi + k_lo). PV: P single fp16 plane x (v_hi + v_lo).
__global__ __launch_bounds__(256) void attn_kernel(
    const f16* __restrict__ qh, const f16* __restrict__ ql,
    const f16* __restrict__ vth, const f16* __restrict__ vtl,
    f16* __restrict__ ch, f16* __restrict__ cl) {
  const int wg = blockIdx.y * 16 + blockIdx.x;          // 0..1535
  const int nid = (wg & 7) * 192 + (wg >> 3);           // bijective (1536%8==0)
  const int qt = nid & 15, bh = nid >> 4;
  const int b = bh / 12, h = bh % 12;
  const int tid = threadIdx.x;
  const int lane = tid & 63, w = tid >> 6;
  const int g = lane >> 4, lr = lane & 15;
  __shared__ __align__(16) f16 Ksh[64][64];
  __shared__ __align__(16) f16 Ksl[64][64];
  __shared__ __align__(16) f16 Vsh[64][64];
  __shared__ __align__(16) f16 Vsl[64][64];
  __shared__ __align__(16) char Psh[4][2048];  // per-wave P (16 x 64 f16), XOR-swizzled
  const int swz = (((tid & 7) ^ ((tid >> 3) & 7)) << 3);
  const size_t qrow = (size_t)b * 1024 + qt * 64 + w * 16 + lr;
  const f16* qbh = qh + qrow * 2304 + h * 64;
  const f16x8 qfh0 = *(const f16x8*)(qbh + g * 8);
  const f16x8 qfh1 = *(const f16x8*)(qbh + 32 + g * 8);
  const f16x8 ones = {(f16)1, (f16)1, (f16)1, (f16)1, (f16)1, (f16)1, (f16)1, (f16)1};
  f32x4 o[4] = {};
  f32x4 osum = {};
  const f16* kbh = qh + ((size_t)b * 1024) * 2304 + 768 + h * 64;
  const f16* kbl = ql + ((size_t)b * 1024) * 2304 + 768 + h * 64;
  const f16* vbh = vth + (size_t)bh * 64 * 1024;
  const f16* vbl = vtl + (size_t)bh * 64 * 1024;
  char* pbh = Psh[w];
  for (int kv0 = 0; kv0 < 1024; kv0 += 64) {
    __syncthreads();
#pragma unroll
    for (int s = 0; s < 2; s++) {
      const int u = s * 256 + tid;  // 16B unit within an 8KB plane
      const int row = u >> 3;
      const size_t ko = (size_t)(kv0 + row) * 2304 + swz;
      gload16(&Ksh[0][0] + u * 8, kbh + ko);
      gload16(&Ksl[0][0] + u * 8, kbl + ko);
      const size_t vo = (size_t)row * 1024 + kv0 + swz;  // row = d
      gload16(&Vsh[0][0] + u * 8, vbh + vo);
      gload16(&Vsl[0][0] + u * 8, vbl + vo);
    }
    __syncthreads();
    f32x4 s[4];
    __builtin_amdgcn_s_setprio(1);
#pragma unroll
    for (int nb = 0; nb < 4; nb++) {
      const int row = nb * 16 + lr;
      const int c0 = ((g ^ (lr & 7)) << 3);
      const int c1 = (((4 + g) ^ (lr & 7)) << 3);
      const f16x8 kh0 = *(const f16x8*)&Ksh[row][c0];
      const f16x8 kh1 = *(const f16x8*)&Ksh[row][c1];
      const f16x8 kl0 = *(const f16x8*)&Ksl[row][c0];
      const f16x8 kl1 = *(const f16x8*)&Ksl[row][c1];
      f32x4 t = {};
      t = MFMA16(qfh0, kh0, t);
      t = MFMA16(qfh1, kh1, t);
      t = MFMA16(qfh0, kl0, t);
      t = MFMA16(qfh1, kl1, t);
      s[nb] = t;
    }
    __builtin_amdgcn_s_setprio(0);
    // P = exp(s/8), no max subtraction (shift-invariant; overflow at 35 sigma)
#pragma unroll
    for (int nb = 0; nb < 4; nb++)
#pragma unroll
      for (int r = 0; r < 4; r++) {
        const int row = g * 4 + r;
        const int sw = ((nb * 16 + lr) * 2) ^ ((row & 7) << 4);
        *(f16*)(pbh + row * 128 + sw) = (f16)__expf(s[nb][r] * 0.125f);
      }
    // PV + row-sum via MFMA x ones
    __builtin_amdgcn_s_setprio(1);
#pragma unroll
    for (int ks = 0; ks < 2; ks++) {
      const int pc = (ks * 64 + g * 16) ^ ((lr & 7) << 4);
      const f16x8 pfh = *(const f16x8*)(pbh + lr * 128 + pc);
      osum = MFMA16(pfh, ones, osum);
#pragma unroll
      for (int db = 0; db < 4; db++) {
        const int vrow = db * 16 + lr;
        const int vc = (((ks * 4 + g) ^ (lr & 7)) << 3);
        const f16x8 vfh = *(const f16x8*)&Vsh[vrow][vc];
        const f16x8 vfl = *(const f16x8*)&Vsl[vrow][vc];
        o[db] = MFMA16(pfh, vfh, o[db]);
        o[db] = MFMA16(pfh, vfl, o[db]);
      }
    }
    __builtin_amdgcn_s_setprio(0);
  }
  const size_t orow = (size_t)b * 1024 + qt * 64 + w * 16 + g * 4;
#pragma unroll
  for (int r = 0; r < 4; r++) {
    const float inv = 1.0f / osum[r];
#pragma unroll
    for (int db = 0; db < 4; db++) {
      const float val = o[db][r] * inv;
      const size_t oi = (orow + r) * 768 + h * 64 + db * 16 + lr;
      f16 hh, ll;
      split2(val, hh, ll);
      ch[oi] = hh;
      cl[oi] = ll;
    }
  }
}

// ---------------- gate: fp32 logits from split xm, top-2, softmax -> comb[T][4] ----------------
__global__ __launch_bounds__(256) void gate_kernel(
    const f16* __restrict__ xmh, const f16* __restrict__ xml,
    const float* __restrict__ gw, const float* __restrict__ gb,
    float* __restrict__ comb) {
  const int t = blockIdx.x * 256 + threadIdx.x;
  const f16* xrh = xmh + (size_t)t * 768;
  const f16* xrl = xml + (size_t)t * 768;
  float a0 = 0, a1 = 0, a2 = 0, a3 = 0;
  for (int k = 0; k < 768; k += 4) {
    const f16x4 xh = *(const f16x4*)(xrh + k);
    const f16x4 xl = *(const f16x4*)(xrl + k);
    const f32x4 w0 = *(const f32x4*)(gw + k);
    const f32x4 w1 = *(const f32x4*)(gw + 768 + k);
    const f32x4 w2 = *(const f32x4*)(gw + 1536 + k);
    const f32x4 w3 = *(const f32x4*)(gw + 2304 + k);
#pragma unroll
    for (int j = 0; j < 4; j++) {
      const float xv = (float)xh[j] + (float)xl[j];
      a0 += xv * w0[j];
      a1 += xv * w1[j];
      a2 += xv * w2[j];
      a3 += xv * w3[j];
    }
  }
  float l[4] = {a0 + gb[0], a1 + gb[1], a2 + gb[2], a3 + gb[3]};
  int i0 = 0;
#pragma unroll
  for (int e = 1; e < 4; e++)
    if (l[e] > l[i0]) i0 = e;  // strict > matches top_k tie order
  int i1 = -1;
#pragma unroll
  for (int e = 0; e < 4; e++)
    if (e != i0 && (i1 < 0 || l[e] > l[i1])) i1 = e;
  const float e1 = expf(l[i1] - l[i0]);
  const float inv = 1.0f / (1.0f + e1);
  float c[4] = {0.0f, 0.0f, 0.0f, 0.0f};
  c[i0] = inv;
  c[i1] = e1 * inv;
  f32x4 cv = {c[0], c[1], c[2], c[3]};
  *(f32x4*)(comb + (size_t)t * 4) = cv;
}

// ---------------- per-expert token lists + 128-aligned segment starts + inverse map ----------------
__global__ __launch_bounds__(1024) void listbuild_kernel(
    const float* __restrict__ comb, int* __restrict__ lists /*[4][8192]*/,
    int* __restrict__ cnts /*[4]*/, int* __restrict__ starts /*[5]*/,
    int* __restrict__ posA /*[8192]*/, int* __restrict__ posB /*[8192]*/) {
  __shared__ int wsum[16];
  const int tid = threadIdx.x;
  const int lane = tid & 63, wv = tid >> 6;
  unsigned seen = 0;  // bit c: token c*1024+tid already assigned once
  int segbase = 0;    // padded global segment base (identical on all threads)
  for (int e = 0; e < 4; e++) {
    int base = 0;
    for (int c = 0; c < 8; c++) {
      const int t = c * 1024 + tid;
      const int flag = comb[(size_t)t * 4 + e] > 0.0f ? 1 : 0;
      const unsigned long long mask = __ballot(flag);
      const int myrank = __popcll(mask & ((1ull << lane) - 1ull));
      if (lane == 0) wsum[wv] = __popcll(mask);
      __syncthreads();
      int wbase = 0, total = 0;
#pragma unroll
      for (int i = 0; i < 16; i++) {
        if (i < wv) wbase += wsum[i];
        total += wsum[i];
      }
      if (flag) {
        const int idx = base + wbase + myrank;
        lists[e * 8192 + idx] = t;
        const int gidx = segbase + idx;
        if ((seen >> c) & 1) posB[t] = gidx;
        else { posA[t] = gidx; seen |= 1u << c; }
      }
      base += total;
      __syncthreads();
    }
    if (tid == 0) cnts[e] = base;
    segbase += (base + 127) & ~127;
  }
  if (tid == 0) {
    int s = 0;
    starts[0] = 0;
#pragma unroll
    for (int e = 0; e < 4; e++) {
      s += (cnts[e] + 127) & ~127;
      starts[e + 1] = s;
    }
  }
}

extern "C" void kernel_launch(void* const* d_in, const int* in_sizes, int n_in,
                              void* d_out, int out_size, void* d_ws,
                              size_t ws_size, hipStream_t stream) {
  const float* x = (const float*)d_in[0];
  const float* ln1g = (const float*)d_in[1];
  const float* ln1b = (const float*)d_in[2];
  const float* in_w = (const float*)d_in[3];
  const float* in_b = (const float*)d_in[4];
  const float* out_w = (const float*)d_in[5];
  const float* out_b = (const float*)d_in[6];
  const float* mlp_w1 = (const float*)d_in[7];
  const float* mlp_b1 = (const float*)d_in[8];
  const float* mlp_w2 = (const float*)d_in[9];
  const float* mlp_b2 = (const float*)d_in[10];
  const float* ln2g = (const float*)d_in[11];
  const float* ln2b = (const float*)d_in[12];
  const float* gate_w = (const float*)d_in[13];
  const float* gate_b = (const float*)d_in[14];
  const float* exp_w1 = (const float*)d_in[15];
  const float* exp_b1 = (const float*)d_in[16];
  const float* exp_w2 = (const float*)d_in[17];
  const float* exp_b2 = (const float*)d_in[18];
  float* out = (float*)d_out;
  (void)in_sizes; (void)n_in; (void)out_size;

  const size_t MB = 1ull << 20;
  if (ws_size < 130 * MB) return;  // clean absmax failure (not a crash) if ws too small
  char* ws = (char*)d_ws;
  // Pre-MoE layout (as R6-R11, lifetimes hand-verified):
  // S1 [0,24MB):   h planes -> attn ctx planes -> w1t planes -> xm planes
  // S2 [24,33MB):  in_w+out_w planes -> w2t planes
  // S3 [33,105MB): qkv planes -> mlp hid planes
  // S4 [105,129MB): vt planes -> x1 planes
  // MoE phase (everything except xmh [0,12MB) is dead after gate):
  //   etw1 [12,30) etw2 [30,48) ehid [48,100) eout(f16) [100,126)
  // S5 [129MB..): comb, lists, cnts, starts, posA, posB
  char* S1 = ws;
  char* S2 = ws + 24 * MB;
  char* S3 = ws + 33 * MB;
  char* S4 = ws + 105 * MB;
  char* S5 = ws + 129 * MB;

  f16* h_h = (f16*)S1;                       // 12,582,912 B each
  f16* h_l = (f16*)(S1 + 12 * MB);
  f16* ctx_h = (f16*)S1;                     // after qkv gemm, h dead
  f16* ctx_l = (f16*)(S1 + 12 * MB);
  f16* w1t_h = (f16*)S1;                     // after out-proj, ctx dead
  f16* w1t_l = (f16*)(S1 + 4718592);
  f16* xmh = (f16*)S1;                       // after mlp, w1t dead
  f16* xml = (f16*)(S1 + 12 * MB);           // dead after gate

  f16* inw_h = (f16*)S2;                     // 3,538,944 B each
  f16* inw_l = (f16*)(S2 + 3538944);
  f16* outw_h = (f16*)(S2 + 7077888);        // 1,179,648 B each
  f16* outw_l = (f16*)(S2 + 8257536);
  f16* w2t_h = (f16*)S2;                     // after out-proj, inw/outw dead
  f16* w2t_l = (f16*)(S2 + 4718592);

  f16* qkv_h = (f16*)S3;                     // 37,748,736 B each
  f16* qkv_l = (f16*)(S3 + 36 * MB);
  f16* hid_h = (f16*)S3;                     // after attn, qkv dead; [8192][1536] each
  f16* hid_l = (f16*)(S3 + 24 * MB);

  f16* vt_h = (f16*)S4;                      // 12,582,912 B each
  f16* vt_l = (f16*)(S4 + 12 * MB);
  f16* x1h = (f16*)S4;                       // after attn, vt dead
  f16* x1l = (f16*)(S4 + 12 * MB);

  // MoE-phase scratch (xml/w2t/hid/x1 all dead by first use):
  f16* etw1 = (f16*)(ws + 12 * MB);          // [4][3072][768] f16 = 18MB
  f16* etw2 = (f16*)(ws + 30 * MB);          // [4][768][3072] f16 = 18MB
  f16* ehid = (f16*)(ws + 48 * MB);          // [16896][1536] f16 = 51.9MB
  f16* eout = (f16*)(ws + 100 * MB);         // [16896][768] f16 = 25.9MB

  float* comb = (float*)S5;                  // 131,072 B
  int* lists = (int*)(S5 + 131072);          // 4 x 8192 ints
  int* cnts = (int*)(S5 + 262144);           // 4 ints
  int* starts = (int*)(S5 + 262144 + 64);    // 5 ints
  int* posA = (int*)(S5 + 262144 + 256);     // 8192 ints
  int* posB = (int*)(S5 + 262144 + 256 + 32768);

  // ---- attention ----
  convert_split_k<<<dim3(1728), dim3(256), 0, stream>>>(in_w, inw_h, inw_l, 442368);
  convert_split_k<<<dim3(576), dim3(256), 0, stream>>>(out_w, outw_h, outw_l, 147456);
  ln_kernel<<<dim3(2048), dim3(256), 0, stream>>>(x, ln1g, ln1b, h_h, h_l);
  gemm_split<0><<<dim3(2304), dim3(256), 0, stream>>>(
      h_h, h_l, 768, inw_h, inw_l, 768, in_b, nullptr, nullptr, nullptr, 0,
      nullptr, qkv_h, qkv_l, 2304, 768, 18);
  vtrans_kernel<<<dim3(16, 96, 2), dim3(256), 0, stream>>>(
      (const ushort*)qkv_h, (const ushort*)qkv_l, (ushort*)vt_h, (ushort*)vt_l);
  attn_kernel<<<dim3(16, 96), dim3(256), 0, stream>>>(qkv_h, qkv_l, vt_h, vt_l, ctx_h, ctx_l);
  gemm_split<1><<<dim3(768), dim3(256), 0, stream>>>(
      ctx_h, ctx_l, 768, outw_h, outw_l, 768, out_b, x, nullptr, nullptr, 0,
      nullptr, x1h, x1l, 768, 768, 6);

  // ---- MLP (hidden in two halves of 1536; result -> out (=x2, fp32)) ----
  transpose_k<<<dim3(96, 24), dim3(256), 0, stream>>>(mlp_w1, w1t_h, w1t_l, 768, 3072);
  transpose_k<<<dim3(24, 96), dim3(256), 0, stream>>>(mlp_w2, w2t_h, w2t_l, 3072, 768);
  gemm_split<2><<<dim3(1536), dim3(256), 0, stream>>>(
      x1h, x1l, 768, w1t_h, w1t_l, 768, mlp_b1, nullptr, nullptr, nullptr, 0,
      nullptr, hid_h, hid_l, 1536, 768, 12);
  gemm_split<3><<<dim3(768), dim3(256), 0, stream>>>(
      hid_h, hid_l, 1536, w2t_h, w2t_l, 3072, mlp_b2, nullptr, x1h, x1l, 0,
      out, nullptr, nullptr, 768, 1536, 6);
  gemm_split<2><<<dim3(1536), dim3(256), 0, stream>>>(
      x1h, x1l, 768, w1t_h + (size_t)1536 * 768, w1t_l + (size_t)1536 * 768, 768,
      mlp_b1 + 1536, nullptr, nullptr, nullptr, 0, nullptr, hid_h, hid_l, 1536, 768, 12);
  gemm_split<3><<<dim3(768), dim3(256), 0, stream>>>(
      hid_h, hid_l, 1536, w2t_h + 1536, w2t_l + 1536, 3072,
      nullptr, nullptr, nullptr, nullptr, 1, out, nullptr, nullptr, 768, 1536, 6);

  // ---- MoE (sparse top-2, segment-mapped, 64x128 tiles, atomic-free scatter) ----
  ln_kernel<<<dim3(2048), dim3(256), 0, stream>>>(out, ln2g, ln2b, xmh, xml);
  gate_kernel<<<dim3(32), dim3(256), 0, stream>>>(xmh, xml, gate_w, gate_b, comb);
  listbuild_kernel<<<dim3(1), dim3(1024), 0, stream>>>(comb, lists, cnts, starts, posA, posB);
  etrans_kernel<<<dim3(96, 24, 4), dim3(256), 0, stream>>>(exp_w1, etw1, 768, 3072);
  etrans_kernel<<<dim3(24, 96, 4), dim3(256), 0, stream>>>(exp_w2, etw2, 3072, 768);
  for (int hf = 0; hf < 2; hf++) {
    gemm_moe1<<<dim3(3168), dim3(256), 0, stream>>>(
        xmh, etw1, exp_b1, lists, cnts, starts, ehid, hf);
    gemm_moe2<<<dim3(1584), dim3(256), 0, stream>>>(
        ehid, etw2, exp_b2, comb, lists, cnts, starts, eout, hf);
  }
  combine_kernel<<<dim3(2048), dim3(256), 0, stream>>>(out, eout, posA, posB);
}

// Round 13
// 870.936 us; speedup vs baseline: 1.3428x; 1.0234x over previous
//
#include <hip/hip_runtime.h>

// TransformerBlock (attn + MLP + top2-MoE) on MI355X.
// Pre-gate chain in split-fp16 3-term MFMA (fp32-class accuracy so the MoE
// top-2 selection matches the fp32 reference); post-gate experts in plain
// fp16 MFMA, SPARSE top-2 dispatch, atomic-free scatter.
// R13: gemm_split -> 128x128 tile with 8 waves (512 threads), 64KB LDS,
// 2 blocks/CU = 16 waves/CU: R12's occupancy PLUS R4's halved global
// traffic (195->~110MB FETCH) and fewer LDS reads per MFMA.

typedef _Float16 f16;
typedef _Float16 f16x4 __attribute__((ext_vector_type(4)));
typedef _Float16 f16x8 __attribute__((ext_vector_type(8)));
typedef float f32x4 __attribute__((ext_vector_type(4)));
typedef unsigned short ushort;

#define MFMA16(a, b, c) __builtin_amdgcn_mfma_f32_16x16x32_f16((a), (b), (c), 0, 0, 0)

__device__ __forceinline__ void gload16(void* lds, const void* g) {
  __builtin_amdgcn_global_load_lds(
      (const __attribute__((address_space(1))) unsigned int*)g,
      (__attribute__((address_space(3))) unsigned int*)lds, 16, 0, 0);
}

__device__ __forceinline__ void split2(float t, f16& h, f16& l) {
  h = (f16)t;
  l = (f16)(t - (float)h);
}

__device__ __forceinline__ float gelu_f(float x) {  // exact (pre-gate path)
  return 0.5f * x * (1.0f + erff(x * 0.70710678118654752f));
}

__device__ __forceinline__ float gelu_fast(float x) {  // tanh-approx (post-gate experts)
  return x / (1.0f + __expf(-1.5957691216f * (x + 0.044715f * x * x * x)));
}

// ---------------- LayerNorm: one wave per row of 768; split-fp16 planes out ----------------
__global__ __launch_bounds__(256) void ln_kernel(
    const float* __restrict__ x, const float* __restrict__ gam,
    const float* __restrict__ bet, f16* __restrict__ oh, f16* __restrict__ ol) {
  const int w = threadIdx.x >> 6, lane = threadIdx.x & 63;
  const size_t row = (size_t)blockIdx.x * 4 + w;
  const float* xr = x + row * 768;
  f32x4 v[3];
  float s = 0.0f;
#pragma unroll
  for (int c = 0; c < 3; c++) {
    v[c] = *(const f32x4*)(xr + c * 256 + lane * 4);
    s += v[c][0] + v[c][1] + v[c][2] + v[c][3];
  }
#pragma unroll
  for (int off = 32; off; off >>= 1) s += __shfl_xor(s, off);
  const float mean = s * (1.0f / 768.0f);
  float q = 0.0f;
#pragma unroll
  for (int c = 0; c < 3; c++)
#pragma unroll
    for (int j = 0; j < 4; j++) {
      float d = v[c][j] - mean;
      q += d * d;
    }
#pragma unroll
  for (int off = 32; off; off >>= 1) q += __shfl_xor(q, off);
  // precise rsqrt: rsqrtf() approx (~1e-5 rel) would risk gate flips downstream
  const float rstd = 1.0f / sqrtf(q * (1.0f / 768.0f) + 1e-5f);
#pragma unroll
  for (int c = 0; c < 3; c++) {
    const int col = c * 256 + lane * 4;
    f32x4 gv = *(const f32x4*)(gam + col);
    f32x4 bv = *(const f32x4*)(bet + col);
    f16x4 yh, yl;
#pragma unroll
    for (int j = 0; j < 4; j++) {
      float y = (v[c][j] - mean) * rstd * gv[j] + bv[j];
      f16 hh, ll;
      split2(y, hh, ll);
      yh[j] = hh;
      yl[j] = ll;
    }
    *(f16x4*)(oh + row * 768 + col) = yh;
    *(f16x4*)(ol + row * 768 + col) = yl;
  }
}

// ---------------- fp32 -> split fp16 (elementwise, x4) ----------------
__global__ __launch_bounds__(256) void convert_split_k(
    const float* __restrict__ in, f16* __restrict__ oh, f16* __restrict__ ol,
    int n4) {
  const int i = blockIdx.x * 256 + threadIdx.x;
  if (i >= n4) return;
  f32x4 v = ((const f32x4*)in)[i];
  f16x4 h, l;
#pragma unroll
  for (int j = 0; j < 4; j++) {
    f16 hh, ll;
    split2(v[j], hh, ll);
    h[j] = hh;
    l[j] = ll;
  }
  ((f16x4*)oh)[i] = h;
  ((f16x4*)ol)[i] = l;
}

// ---------------- fp32 [R][ldin] (32x32 tiles) -> fp16 [C][R] split ----------------
__global__ __launch_bounds__(256) void transpose_k(
    const float* __restrict__ in, f16* __restrict__ oh, f16* __restrict__ ol,
    int R, int ldin) {
  __shared__ float t[32][33];
  const int tx = threadIdx.x & 31, ty = threadIdx.x >> 5;
  const int r0 = blockIdx.y * 32, c0 = blockIdx.x * 32;
#pragma unroll
  for (int i = 0; i < 4; i++)
    t[ty + 8 * i][tx] = in[(size_t)(r0 + ty + 8 * i) * ldin + c0 + tx];
  __syncthreads();
#pragma unroll
  for (int i = 0; i < 4; i++) {
    const float val = t[tx][ty + 8 * i];
    const size_t o = (size_t)(c0 + ty + 8 * i) * R + r0 + tx;
    f16 hh, ll;
    split2(val, hh, ll);
    oh[o] = hh;
    ol[o] = ll;
  }
}

// ---------------- per-expert fp32 [R][C] -> f16 [C][R] (blockIdx.z = expert) ----------------
__global__ __launch_bounds__(256) void etrans_kernel(
    const float* __restrict__ in0, f16* __restrict__ out0, int R, int C) {
  const size_t eoff = (size_t)blockIdx.z * R * C;
  const float* in = in0 + eoff;
  f16* out = out0 + eoff;
  __shared__ float t[32][33];
  const int tx = threadIdx.x & 31, ty = threadIdx.x >> 5;
  const int r0 = blockIdx.y * 32, c0 = blockIdx.x * 32;
#pragma unroll
  for (int i = 0; i < 4; i++)
    t[ty + 8 * i][tx] = in[(size_t)(r0 + ty + 8 * i) * C + c0 + tx];
  __syncthreads();
#pragma unroll
  for (int i = 0; i < 4; i++)
    out[(size_t)(c0 + ty + 8 * i) * R + r0 + tx] = (f16)t[tx][ty + 8 * i];
}

// ---------------- V transpose: qkv planes (v part) -> [B,H,64,1024]; z = hi/lo ----------------
__global__ __launch_bounds__(256) void vtrans_kernel(
    const ushort* __restrict__ srcH, const ushort* __restrict__ srcL,
    ushort* __restrict__ dstH, ushort* __restrict__ dstL) {
  const int nt = blockIdx.x, bh = blockIdx.y;
  const ushort* src = blockIdx.z ? srcL : srcH;
  ushort* dst = blockIdx.z ? dstL : dstH;
  const int b = bh / 12, h = bh % 12;
  __shared__ ushort t[64][65];
  const int tid = threadIdx.x;
#pragma unroll
  for (int i = 0; i < 16; i++) {
    const int idx = i * 256 + tid;
    const int r = idx >> 6, c = idx & 63;
    t[r][c] = src[((size_t)b * 1024 + nt * 64 + r) * 2304 + 1536 + h * 64 + c];
  }
  __syncthreads();
#pragma unroll
  for (int i = 0; i < 16; i++) {
    const int idx = i * 256 + tid;
    const int d = idx >> 6, n = idx & 63;
    dst[((size_t)bh * 64 + d) * 1024 + nt * 64 + n] = t[n][d];
  }
}

// ---------------- split-fp16 3-term GEMM: C = A·B^T (+bias), A[M,K] B[N,K] ----------------
// R13: 128x128 tile, BK=64, 8 waves (2m x 4n, 512 thr), acc[4][2]/thread.
// LDS 4 planes x [128][64] = 64KB -> 2 blocks/CU (16 waves/CU). Full-128B-row
// staging, XOR chunk-swizzle (pre-swizzled source + same-involution read).
// XCD-chunked 1-D grid (nbx = N tiles).
template <int MODE>
__global__ __launch_bounds__(512) void gemm_split(
    const f16* __restrict__ Ah, const f16* __restrict__ Al, int lda,
    const f16* __restrict__ Bh, const f16* __restrict__ Bl, int ldb,
    const float* __restrict__ bias, const float* __restrict__ residF,
    const f16* __restrict__ residH, const f16* __restrict__ residL, int addto,
    float* __restrict__ outF, f16* __restrict__ outH, f16* __restrict__ outL,
    int ldo, int K, int nbx) {
  __shared__ __align__(16) f16 Ash[128][64];
  __shared__ __align__(16) f16 Asl[128][64];
  __shared__ __align__(16) f16 Bsh[128][64];
  __shared__ __align__(16) f16 Bsl[128][64];
  const int per = gridDim.x >> 3;
  const int lin = ((int)blockIdx.x & 7) * per + ((int)blockIdx.x >> 3);
  const int bx = lin % nbx, by = lin / nbx;
  const int tid = threadIdx.x;
  const int lane = tid & 63, wid = tid >> 6;
  const int wm = wid >> 2, wn4 = wid & 3;  // 2m x 4n wave grid
  const int g = lane >> 4, lr = lane & 15;
  const int swz = (((tid & 7) ^ ((tid >> 3) & 7)) << 3);  // element offset
  const size_t m0 = (size_t)by * 128, n0 = (size_t)bx * 128;
  f32x4 acc[4][2] = {};
  for (int k0 = 0; k0 < K; k0 += 64) {
    __syncthreads();
#pragma unroll
    for (int s = 0; s < 2; s++) {
      const int u = s * 512 + tid;  // 16B unit within a 16KB plane
      const int row = u >> 3;       // s*512 = 64 rows: row&7 invariant vs tid
      const size_t ga = (m0 + row) * (size_t)lda + k0 + swz;
      const size_t gb = (n0 + row) * (size_t)ldb + k0 + swz;
      gload16(&Ash[0][0] + u * 8, Ah + ga);
      gload16(&Asl[0][0] + u * 8, Al + ga);
      gload16(&Bsh[0][0] + u * 8, Bh + gb);
      gload16(&Bsl[0][0] + u * 8, Bl + gb);
    }
    __syncthreads();
#pragma unroll
    for (int kk = 0; kk < 2; kk++) {
      const int c = (((kk * 4 + g) ^ (lr & 7)) << 3);
      f16x8 fah[4], fal[4], fbh[2], fbl[2];
#pragma unroll
      for (int mi = 0; mi < 4; mi++) {
        const int row = wm * 64 + mi * 16 + lr;
        fah[mi] = *(const f16x8*)&Ash[row][c];
        fal[mi] = *(const f16x8*)&Asl[row][c];
      }
#pragma unroll
      for (int ni = 0; ni < 2; ni++) {
        const int row = wn4 * 32 + ni * 16 + lr;
        fbh[ni] = *(const f16x8*)&Bsh[row][c];
        fbl[ni] = *(const f16x8*)&Bsl[row][c];
      }
#pragma unroll
      for (int mi = 0; mi < 4; mi++)
#pragma unroll
        for (int ni = 0; ni < 2; ni++) {
          acc[mi][ni] = MFMA16(fah[mi], fbh[ni], acc[mi][ni]);
          acc[mi][ni] = MFMA16(fah[mi], fbl[ni], acc[mi][ni]);
          acc[mi][ni] = MFMA16(fal[mi], fbh[ni], acc[mi][ni]);
        }
    }
  }
#pragma unroll
  for (int ni = 0; ni < 2; ni++) {
    const size_t col = n0 + wn4 * 32 + ni * 16 + lr;
    const float bv = bias ? bias[col] : 0.0f;
#pragma unroll
    for (int mi = 0; mi < 4; mi++) {
      const size_t rowb = m0 + wm * 64 + mi * 16 + g * 4;
      const f32x4 c = acc[mi][ni];
#pragma unroll
      for (int r = 0; r < 4; r++) {
        const size_t idx = (rowb + r) * (size_t)ldo + col;
        const float v = c[r] + bv;
        if constexpr (MODE == 0) {
          f16 hh, ll;
          split2(v, hh, ll);
          outH[idx] = hh;
          outL[idx] = ll;
        } else if constexpr (MODE == 1) {
          const float tt = v + residF[idx];
          f16 hh, ll;
          split2(tt, hh, ll);
          outH[idx] = hh;
          outL[idx] = ll;
        } else if constexpr (MODE == 2) {
          const float tt = gelu_f(v);
          f16 hh, ll;
          split2(tt, hh, ll);
          outH[idx] = hh;
          outL[idx] = ll;
        } else {
          outF[idx] = addto ? (outF[idx] + v)
                            : ((float)residH[idx] + (float)residL[idx] + v);
        }
      }
    }
  }
}

// ---------------- MoE expert GEMM 1: 64x128 tile, single-buffer 24KB, indirect A ----------------
// 1-D grid 3168 (= 12 x 264). ehid[gr][1536] = gelu_fast(xm[list] . w1t[e] + b1).
__global__ __launch_bounds__(256) void gemm_moe1(
    const f16* __restrict__ xmh, const f16* __restrict__ etw1,
    const float* __restrict__ eb1, const int* __restrict__ lists,
    const int* __restrict__ cnts, const int* __restrict__ starts,
    f16* __restrict__ ehid, int hf) {
  const int per = gridDim.x >> 3;  // 3168/8 = 396
  const int lin = (blockIdx.x & 7) * per + (blockIdx.x >> 3);
  const int bx = lin % 12, by = lin / 12;
  const int m0 = by * 64;
  if (m0 >= starts[4]) return;
  int e = 0;
  while (e < 3 && m0 >= starts[e + 1]) e++;
  const int cnt = cnts[e];
  const int loc0 = m0 - starts[e];
  const int* list = lists + e * 8192;
  const f16* Bw = etw1 + ((size_t)e * 3072 + hf * 1536) * 768;
  const float* bias = eb1 + e * 3072 + hf * 1536;
  __shared__ __align__(16) f16 As[64][64];   // 8 KB
  __shared__ __align__(16) f16 Bs[128][64];  // 16 KB
  const int tid = threadIdx.x;
  const int lane = tid & 63, wn = tid >> 6;  // wave -> 32-col slice
  const int g = lane >> 4, lr = lane & 15;
  const int swz = (((tid & 7) ^ ((tid >> 3) & 7)) << 3);
  const int n0 = bx * 128;
  size_t arow[2];
#pragma unroll
  for (int s = 0; s < 2; s++) {
    const int row = (s * 256 + tid) >> 3;
    const int loc = loc0 + row;
    arow[s] = (size_t)list[loc < cnt ? loc : cnt - 1] * 768;
  }
  f32x4 acc[4][2] = {};
  for (int k0 = 0; k0 < 768; k0 += 64) {
    __syncthreads();
#pragma unroll
    for (int s = 0; s < 2; s++) {
      const int u = s * 256 + tid;
      gload16(&As[0][0] + u * 8, xmh + arow[s] + k0 + swz);
    }
#pragma unroll
    for (int s = 0; s < 4; s++) {
      const int u = s * 256 + tid;
      const int row = u >> 3;
      gload16(&Bs[0][0] + u * 8, Bw + (size_t)(n0 + row) * 768 + k0 + swz);
    }
    __syncthreads();
#pragma unroll
    for (int kk = 0; kk < 2; kk++) {
      const int c = (((kk * 4 + g) ^ (lr & 7)) << 3);
      f16x8 fa[4], fb[2];
#pragma unroll
      for (int mi = 0; mi < 4; mi++) fa[mi] = *(const f16x8*)&As[mi * 16 + lr][c];
#pragma unroll
      for (int ni = 0; ni < 2; ni++)
        fb[ni] = *(const f16x8*)&Bs[wn * 32 + ni * 16 + lr][c];
#pragma unroll
      for (int mi = 0; mi < 4; mi++)
#pragma unroll
        for (int ni = 0; ni < 2; ni++)
          acc[mi][ni] = MFMA16(fa[mi], fb[ni], acc[mi][ni]);
    }
  }
#pragma unroll
  for (int ni = 0; ni < 2; ni++) {
    const int col = n0 + wn * 32 + ni * 16 + lr;
    const float bv = bias[col];
#pragma unroll
    for (int mi = 0; mi < 4; mi++) {
      const int gr = m0 + mi * 16 + g * 4;
      const f32x4 c = acc[mi][ni];
#pragma unroll
      for (int r = 0; r < 4; r++)
        ehid[(size_t)(gr + r) * 1536 + col] = (f16)gelu_fast(c[r] + bv);
    }
  }
}

// ---------------- MoE expert GEMM 2: 64x128 tile, single-buffer 24KB, NO atomics ----------------
// 1-D grid 1584 (= 6 x 264). eout[gr] (f16) = w*(acc+b2) (hf0) / += w*acc (hf1).
__global__ __launch_bounds__(256) void gemm_moe2(
    const f16* __restrict__ ehid, const f16* __restrict__ etw2,
    const float* __restrict__ eb2, const float* __restrict__ comb,
    const int* __restrict__ lists, const int* __restrict__ cnts,
    const int* __restrict__ starts, f16* __restrict__ eout, int hf) {
  const int per = gridDim.x >> 3;  // 1584/8 = 198
  const int lin = (blockIdx.x & 7) * per + (blockIdx.x >> 3);
  const int bx = lin % 6, by = lin / 6;
  const int m0 = by * 64;
  if (m0 >= starts[4]) return;
  int e = 0;
  while (e < 3 && m0 >= starts[e + 1]) e++;
  const int cnt = cnts[e];
  const int st = starts[e];
  const int* list = lists + e * 8192;
  const f16* Bw = etw2 + (size_t)e * 768 * 3072 + hf * 1536;
  __shared__ __align__(16) f16 As[64][64];   // 8 KB
  __shared__ __align__(16) f16 Bs[128][64];  // 16 KB
  const int tid = threadIdx.x;
  const int lane = tid & 63, wn = tid >> 6;
  const int g = lane >> 4, lr = lane & 15;
  const int swz = (((tid & 7) ^ ((tid >> 3) & 7)) << 3);
  const int n0 = bx * 128;
  f32x4 acc[4][2] = {};
  for (int k0 = 0; k0 < 1536; k0 += 64) {
    __syncthreads();
#pragma unroll
    for (int s = 0; s < 2; s++) {
      const int u = s * 256 + tid;
      const int row = u >> 3;
      gload16(&As[0][0] + u * 8, ehid + (size_t)(m0 + row) * 1536 + k0 + swz);
    }
#pragma unroll
    for (int s = 0; s < 4; s++) {
      const int u = s * 256 + tid;
      const int row = u >> 3;
      gload16(&Bs[0][0] + u * 8, Bw + (size_t)(n0 + row) * 3072 + k0 + swz);
    }
    __syncthreads();
#pragma unroll
    for (int kk = 0; kk < 2; kk++) {
      const int c = (((kk * 4 + g) ^ (lr & 7)) << 3);
      f16x8 fa[4], fb[2];
#pragma unroll
      for (int mi = 0; mi < 4; mi++) fa[mi] = *(const f16x8*)&As[mi * 16 + lr][c];
#pragma unroll
      for (int ni = 0; ni < 2; ni++)
        fb[ni] = *(const f16x8*)&Bs[wn * 32 + ni * 16 + lr][c];
#pragma unroll
      for (int mi = 0; mi < 4; mi++)
#pragma unroll
        for (int ni = 0; ni < 2; ni++)
          acc[mi][ni] = MFMA16(fa[mi], fb[ni], acc[mi][ni]);
    }
  }
#pragma unroll
  for (int ni = 0; ni < 2; ni++) {
    const int col = n0 + wn * 32 + ni * 16 + lr;
    const float bv = hf ? 0.0f : eb2[e * 768 + col];
#pragma unroll
    for (int mi = 0; mi < 4; mi++) {
      const int gr = m0 + mi * 16 + g * 4;
      const f32x4 c = acc[mi][ni];
#pragma unroll
      for (int r = 0; r < 4; r++) {
        const int loc = gr + r - st;
        if (loc < cnt) {
          const int tok = list[loc];
          const float w = comb[(size_t)tok * 4 + e];
          const size_t oi = (size_t)(gr + r) * 768 + col;
          const float v = w * (c[r] + bv);
          eout[oi] = hf ? (f16)((float)eout[oi] + v) : (f16)v;
        }
      }
    }
  }
}

// ---------------- final combine: out[t] = x2[t] + eout[posA[t]] + eout[posB[t]] ----------------
__global__ __launch_bounds__(256) void combine_kernel(
    float* __restrict__ out, const f16* __restrict__ eout,
    const int* __restrict__ posA, const int* __restrict__ posB) {
  const int w = threadIdx.x >> 6, lane = threadIdx.x & 63;
  const size_t row = (size_t)blockIdx.x * 4 + w;
  const size_t pa = (size_t)posA[row] * 768, pb = (size_t)posB[row] * 768;
#pragma unroll
  for (int c = 0; c < 3; c++) {
    const int col = c * 256 + lane * 4;
    f32x4 v = *(const f32x4*)(out + row * 768 + col);
    const f16x4 a = *(const f16x4*)(eout + pa + col);
    const f16x4 b = *(const f16x4*)(eout + pb + col);
#pragma unroll
    for (int j = 0; j < 4; j++) v[j] += (float)a[j] + (float)b[j];
    *(f32x4*)(out + row * 768 + col) = v;
  }
}

// ---------------- flash attention, KVBLK=64, precision-trimmed ----------------
// 1536 blocks, XCD-swizzled. No-max softmax P=exp(s/8); row-sum via MFMA x ones.
// QK: q_hi x (k_hi + k_lo). PV: P single fp16 plane x (v_hi + v_lo).
__global__ __launch_bounds__(256) void attn_kernel(
    const f16* __restrict__ qh, const f16* __restrict__ ql,
    const f16* __restrict__ vth, const f16* __restrict__ vtl,
    f16* __restrict__ ch, f16* __restrict__ cl) {
  const int wg = blockIdx.y * 16 + blockIdx.x;          // 0..1535
  const int nid = (wg & 7) * 192 + (wg >> 3);           // bijective (1536%8==0)
  const int qt = nid & 15, bh = nid >> 4;
  const int b = bh / 12, h = bh % 12;
  const int tid = threadIdx.x;
  const int lane = tid & 63, w = tid >> 6;
  const int g = lane >> 4, lr = lane & 15;
  __shared__ __align__(16) f16 Ksh[64][64];
  __shared__ __align__(16) f16 Ksl[64][64];
  __shared__ __align__(16) f16 Vsh[64][64];
  __shared__ __align__(16) f16 Vsl[64][64];
  __shared__ __align__(16) char Psh[4][2048];  // per-wave P (16 x 64 f16), XOR-swizzled
  const int swz = (((tid & 7) ^ ((tid >> 3) & 7)) << 3);
  const size_t qrow = (size_t)b * 1024 + qt * 64 + w * 16 + lr;
  const f16* qbh = qh + qrow * 2304 + h * 64;
  const f16x8 qfh0 = *(const f16x8*)(qbh + g * 8);
  const f16x8 qfh1 = *(const f16x8*)(qbh + 32 + g * 8);
  const f16x8 ones = {(f16)1, (f16)1, (f16)1, (f16)1, (f16)1, (f16)1, (f16)1, (f16)1};
  f32x4 o[4] = {};
  f32x4 osum = {};
  const f16* kbh = qh + ((size_t)b * 1024) * 2304 + 768 + h * 64;
  const f16* kbl = ql + ((size_t)b * 1024) * 2304 + 768 + h * 64;
  const f16* vbh = vth + (size_t)bh * 64 * 1024;
  const f16* vbl = vtl + (size_t)bh * 64 * 1024;
  char* pbh = Psh[w];
  for (int kv0 = 0; kv0 < 1024; kv0 += 64) {
    __syncthreads();
#pragma unroll
    for (int s = 0; s < 2; s++) {
      const int u = s * 256 + tid;  // 16B unit within an 8KB plane
      const int row = u >> 3;
      const size_t ko = (size_t)(kv0 + row) * 2304 + swz;
      gload16(&Ksh[0][0] + u * 8, kbh + ko);
      gload16(&Ksl[0][0] + u * 8, kbl + ko);
      const size_t vo = (size_t)row * 1024 + kv0 + swz;  // row = d
      gload16(&Vsh[0][0] + u * 8, vbh + vo);
      gload16(&Vsl[0][0] + u * 8, vbl + vo);
    }
    __syncthreads();
    f32x4 s[4];
    __builtin_amdgcn_s_setprio(1);
#pragma unroll
    for (int nb = 0; nb < 4; nb++) {
      const int row = nb * 16 + lr;
      const int c0 = ((g ^ (lr & 7)) << 3);
      const int c1 = (((4 + g) ^ (lr & 7)) << 3);
      const f16x8 kh0 = *(const f16x8*)&Ksh[row][c0];
      const f16x8 kh1 = *(const f16x8*)&Ksh[row][c1];
      const f16x8 kl0 = *(const f16x8*)&Ksl[row][c0];
      const f16x8 kl1 = *(const f16x8*)&Ksl[row][c1];
      f32x4 t = {};
      t = MFMA16(qfh0, kh0, t);
      t = MFMA16(qfh1, kh1, t);
      t = MFMA16(qfh0, kl0, t);
      t = MFMA16(qfh1, kl1, t);
      s[nb] = t;
    }
    __builtin_amdgcn_s_setprio(0);
    // P = exp(s/8), no max subtraction (shift-invariant; overflow at 35 sigma)
#pragma unroll
    for (int nb = 0; nb < 4; nb++)
#pragma unroll
      for (int r = 0; r < 4; r++) {
        const int row = g * 4 + r;
        const int sw = ((nb * 16 + lr) * 2) ^ ((row & 7) << 4);
        *(f16*)(pbh + row * 128 + sw) = (f16)__expf(s[nb][r] * 0.125f);
      }
    // PV + row-sum via MFMA x ones
    __builtin_amdgcn_s_setprio(1);
#pragma unroll
    for (int ks = 0; ks < 2; ks++) {
      const int pc = (ks * 64 + g * 16) ^ ((lr & 7) << 4);
      const f16x8 pfh = *(const f16x8*)(pbh + lr * 128 + pc);
      osum = MFMA16(pfh, ones, osum);
#pragma unroll
      for (int db = 0; db < 4; db++) {
        const int vrow = db * 16 + lr;
        const int vc = (((ks * 4 + g) ^ (lr & 7)) << 3);
        const f16x8 vfh = *(const f16x8*)&Vsh[vrow][vc];
        const f16x8 vfl = *(const f16x8*)&Vsl[vrow][vc];
        o[db] = MFMA16(pfh, vfh, o[db]);
        o[db] = MFMA16(pfh, vfl, o[db]);
      }
    }
    __builtin_amdgcn_s_setprio(0);
  }
  const size_t orow = (size_t)b * 1024 + qt * 64 + w * 16 + g * 4;
#pragma unroll
  for (int r = 0; r < 4; r++) {
    const float inv = 1.0f / osum[r];
#pragma unroll
    for (int db = 0; db < 4; db++) {
      const float val = o[db][r] * inv;
      const size_t oi = (orow + r) * 768 + h * 64 + db * 16 + lr;
      f16 hh, ll;
      split2(val, hh, ll);
      ch[oi] = hh;
      cl[oi] = ll;
    }
  }
}

// ---------------- gate: fp32 logits from split xm, top-2, softmax -> comb[T][4] ----------------
__global__ __launch_bounds__(256) void gate_kernel(
    const f16* __restrict__ xmh, const f16* __restrict__ xml,
    const float* __restrict__ gw, const float* __restrict__ gb,
    float* __restrict__ comb) {
  const int t = blockIdx.x * 256 + threadIdx.x;
  const f16* xrh = xmh + (size_t)t * 768;
  const f16* xrl = xml + (size_t)t * 768;
  float a0 = 0, a1 = 0, a2 = 0, a3 = 0;
  for (int k = 0; k < 768; k += 4) {
    const f16x4 xh = *(const f16x4*)(xrh + k);
    const f16x4 xl = *(const f16x4*)(xrl + k);
    const f32x4 w0 = *(const f32x4*)(gw + k);
    const f32x4 w1 = *(const f32x4*)(gw + 768 + k);
    const f32x4 w2 = *(const f32x4*)(gw + 1536 + k);
    const f32x4 w3 = *(const f32x4*)(gw + 2304 + k);
#pragma unroll
    for (int j = 0; j < 4; j++) {
      const float xv = (float)xh[j] + (float)xl[j];
      a0 += xv * w0[j];
      a1 += xv * w1[j];
      a2 += xv * w2[j];
      a3 += xv * w3[j];
    }
  }
  float l[4] = {a0 + gb[0], a1 + gb[1], a2 + gb[2], a3 + gb[3]};
  int i0 = 0;
#pragma unroll
  for (int e = 1; e < 4; e++)
    if (l[e] > l[i0]) i0 = e;  // strict > matches top_k tie order
  int i1 = -1;
#pragma unroll
  for (int e = 0; e < 4; e++)
    if (e != i0 && (i1 < 0 || l[e] > l[i1])) i1 = e;
  const float e1 = expf(l[i1] - l[i0]);
  const float inv = 1.0f / (1.0f + e1);
  float c[4] = {0.0f, 0.0f, 0.0f, 0.0f};
  c[i0] = inv;
  c[i1] = e1 * inv;
  f32x4 cv = {c[0], c[1], c[2], c[3]};
  *(f32x4*)(comb + (size_t)t * 4) = cv;
}

// ---------------- per-expert token lists + 128-aligned segment starts + inverse map ----------------
__global__ __launch_bounds__(1024) void listbuild_kernel(
    const float* __restrict__ comb, int* __restrict__ lists /*[4][8192]*/,
    int* __restrict__ cnts /*[4]*/, int* __restrict__ starts /*[5]*/,
    int* __restrict__ posA /*[8192]*/, int* __restrict__ posB /*[8192]*/) {
  __shared__ int wsum[16];
  const int tid = threadIdx.x;
  const int lane = tid & 63, wv = tid >> 6;
  unsigned seen = 0;  // bit c: token c*1024+tid already assigned once
  int segbase = 0;    // padded global segment base (identical on all threads)
  for (int e = 0; e < 4; e++) {
    int base = 0;
    for (int c = 0; c < 8; c++) {
      const int t = c * 1024 + tid;
      const int flag = comb[(size_t)t * 4 + e] > 0.0f ? 1 : 0;
      const unsigned long long mask = __ballot(flag);
      const int myrank = __popcll(mask & ((1ull << lane) - 1ull));
      if (lane == 0) wsum[wv] = __popcll(mask);
      __syncthreads();
      int wbase = 0, total = 0;
#pragma unroll
      for (int i = 0; i < 16; i++) {
        if (i < wv) wbase += wsum[i];
        total += wsum[i];
      }
      if (flag) {
        const int idx = base + wbase + myrank;
        lists[e * 8192 + idx] = t;
        const int gidx = segbase + idx;
        if ((seen >> c) & 1) posB[t] = gidx;
        else { posA[t] = gidx; seen |= 1u << c; }
      }
      base += total;
      __syncthreads();
    }
    if (tid == 0) cnts[e] = base;
    segbase += (base + 127) & ~127;
  }
  if (tid == 0) {
    int s = 0;
    starts[0] = 0;
#pragma unroll
    for (int e = 0; e < 4; e++) {
      s += (cnts[e] + 127) & ~127;
      starts[e + 1] = s;
    }
  }
}

extern "C" void kernel_launch(void* const* d_in, const int* in_sizes, int n_in,
                              void* d_out, int out_size, void* d_ws,
                              size_t ws_size, hipStream_t stream) {
  const float* x = (const float*)d_in[0];
  const float* ln1g = (const float*)d_in[1];
  const float* ln1b = (const float*)d_in[2];
  const float* in_w = (const float*)d_in[3];
  const float* in_b = (const float*)d_in[4];
  const float* out_w = (const float*)d_in[5];
  const float* out_b = (const float*)d_in[6];
  const float* mlp_w1 = (const float*)d_in[7];
  const float* mlp_b1 = (const float*)d_in[8];
  const float* mlp_w2 = (const float*)d_in[9];
  const float* mlp_b2 = (const float*)d_in[10];
  const float* ln2g = (const float*)d_in[11];
  const float* ln2b = (const float*)d_in[12];
  const float* gate_w = (const float*)d_in[13];
  const float* gate_b = (const float*)d_in[14];
  const float* exp_w1 = (const float*)d_in[15];
  const float* exp_b1 = (const float*)d_in[16];
  const float* exp_w2 = (const float*)d_in[17];
  const float* exp_b2 = (const float*)d_in[18];
  float* out = (float*)d_out;
  (void)in_sizes; (void)n_in; (void)out_size;

  const size_t MB = 1ull << 20;
  if (ws_size < 130 * MB) return;  // clean absmax failure (not a crash) if ws too small
  char* ws = (char*)d_ws;
  // Pre-MoE layout (as R6-R12, lifetimes hand-verified):
  // S1 [0,24MB):   h planes -> attn ctx planes -> w1t planes -> xm planes
  // S2 [24,33MB):  in_w+out_w planes -> w2t planes
  // S3 [33,105MB): qkv planes -> mlp hid planes
  // S4 [105,129MB): vt planes -> x1 planes
  // MoE phase (everything except xmh [0,12MB) is dead after gate):
  //   etw1 [12,30) etw2 [30,48) ehid [48,100) eout(f16) [100,126)
  // S5 [129MB..): comb, lists, cnts, starts, posA, posB
  char* S1 = ws;
  char* S2 = ws + 24 * MB;
  char* S3 = ws + 33 * MB;
  char* S4 = ws + 105 * MB;
  char* S5 = ws + 129 * MB;

  f16* h_h = (f16*)S1;                       // 12,582,912 B each
  f16* h_l = (f16*)(S1 + 12 * MB);
  f16* ctx_h = (f16*)S1;                     // after qkv gemm, h dead
  f16* ctx_l = (f16*)(S1 + 12 * MB);
  f16* w1t_h = (f16*)S1;                     // after out-proj, ctx dead
  f16* w1t_l = (f16*)(S1 + 4718592);
  f16* xmh = (f16*)S1;                       // after mlp, w1t dead
  f16* xml = (f16*)(S1 + 12 * MB);           // dead after gate

  f16* inw_h = (f16*)S2;                     // 3,538,944 B each
  f16* inw_l = (f16*)(S2 + 3538944);
  f16* outw_h = (f16*)(S2 + 7077888);        // 1,179,648 B each
  f16* outw_l = (f16*)(S2 + 8257536);
  f16* w2t_h = (f16*)S2;                     // after out-proj, inw/outw dead
  f16* w2t_l = (f16*)(S2 + 4718592);

  f16* qkv_h = (f16*)S3;                     // 37,748,736 B each
  f16* qkv_l = (f16*)(S3 + 36 * MB);
  f16* hid_h = (f16*)S3;                     // after attn, qkv dead; [8192][1536] each
  f16* hid_l = (f16*)(S3 + 24 * MB);

  f16* vt_h = (f16*)S4;                      // 12,582,912 B each
  f16* vt_l = (f16*)(S4 + 12 * MB);
  f16* x1h = (f16*)S4;                       // after attn, vt dead
  f16* x1l = (f16*)(S4 + 12 * MB);

  // MoE-phase scratch (xml/w2t/hid/x1 all dead by first use):
  f16* etw1 = (f16*)(ws + 12 * MB);          // [4][3072][768] f16 = 18MB
  f16* etw2 = (f16*)(ws + 30 * MB);          // [4][768][3072] f16 = 18MB
  f16* ehid = (f16*)(ws + 48 * MB);          // [16896][1536] f16 = 51.9MB
  f16* eout = (f16*)(ws + 100 * MB);         // [16896][768] f16 = 25.9MB

  float* comb = (float*)S5;                  // 131,072 B
  int* lists = (int*)(S5 + 131072);          // 4 x 8192 ints
  int* cnts = (int*)(S5 + 262144);           // 4 ints
  int* starts = (int*)(S5 + 262144 + 64);    // 5 ints
  int* posA = (int*)(S5 + 262144 + 256);     // 8192 ints
  int* posB = (int*)(S5 + 262144 + 256 + 32768);

  // ---- attention ----
  convert_split_k<<<dim3(1728), dim3(256), 0, stream>>>(in_w, inw_h, inw_l, 442368);
  convert_split_k<<<dim3(576), dim3(256), 0, stream>>>(out_w, outw_h, outw_l, 147456);
  ln_kernel<<<dim3(2048), dim3(256), 0, stream>>>(x, ln1g, ln1b, h_h, h_l);
  gemm_split<0><<<dim3(1152), dim3(512), 0, stream>>>(
      h_h, h_l, 768, inw_h, inw_l, 768, in_b, nullptr, nullptr, nullptr, 0,
      nullptr, qkv_h, qkv_l, 2304, 768, 18);
  vtrans_kernel<<<dim3(16, 96, 2), dim3(256), 0, stream>>>(
      (const ushort*)qkv_h, (const ushort*)qkv_l, (ushort*)vt_h, (ushort*)vt_l);
  attn_kernel<<<dim3(16, 96), dim3(256), 0, stream>>>(qkv_h, qkv_l, vt_h, vt_l, ctx_h, ctx_l);
  gemm_split<1><<<dim3(384), dim3(512), 0, stream>>>(
      ctx_h, ctx_l, 768, outw_h, outw_l, 768, out_b, x, nullptr, nullptr, 0,
      nullptr, x1h, x1l, 768, 768, 6);

  // ---- MLP (hidden in two halves of 1536; result -> out (=x2, fp32)) ----
  transpose_k<<<dim3(96, 24), dim3(256), 0, stream>>>(mlp_w1, w1t_h, w1t_l, 768, 3072);
  transpose_k<<<dim3(24, 96), dim3(256), 0, stream>>>(mlp_w2, w2t_h, w2t_l, 3072, 768);
  gemm_split<2><<<dim3(768), dim3(512), 0, stream>>>(
      x1h, x1l, 768, w1t_h, w1t_l, 768, mlp_b1, nullptr, nullptr, nullptr, 0,
      nullptr, hid_h, hid_l, 1536, 768, 12);
  gemm_split<3><<<dim3(384), dim3(512), 0, stream>>>(
      hid_h, hid_l, 1536, w2t_h, w2t_l, 3072, mlp_b2, nullptr, x1h, x1l, 0,
      out, nullptr, nullptr, 768, 1536, 6);
  gemm_split<2><<<dim3(768), dim3(512), 0, stream>>>(
      x1h, x1l, 768, w1t_h + (size_t)1536 * 768, w1t_l + (size_t)1536 * 768, 768,
      mlp_b1 + 1536, nullptr, nullptr, nullptr, 0, nullptr, hid_h, hid_l, 1536, 768, 12);
  gemm_split<3><<<dim3(384), dim3(512), 0, stream>>>(
      hid_h, hid_l, 1536, w2t_h + 1536, w2t_l + 1536, 3072,
      nullptr, nullptr, nullptr, nullptr, 1, out, nullptr, nullptr, 768, 1536, 6);

  // ---- MoE (sparse top-2, segment-mapped, 64x128 tiles, atomic-free scatter) ----
  ln_kernel<<<dim3(2048), dim3(256), 0, stream>>>(out, ln2g, ln2b, xmh, xml);
  gate_kernel<<<dim3(32), dim3(256), 0, stream>>>(xmh, xml, gate_w, gate_b, comb);
  listbuild_kernel<<<dim3(1), dim3(1024), 0, stream>>>(comb, lists, cnts, starts, posA, posB);
  etrans_kernel<<<dim3(96, 24, 4), dim3(256), 0, stream>>>(exp_w1, etw1, 768, 3072);
  etrans_kernel<<<dim3(24, 96, 4), dim3(256), 0, stream>>>(exp_w2, etw2, 3072, 768);
  for (int hf = 0; hf < 2; hf++) {
    gemm_moe1<<<dim3(3168), dim3(256), 0, stream>>>(
        xmh, etw1, exp_b1, lists, cnts, starts, ehid, hf);
    gemm_moe2<<<dim3(1584), dim3(256), 0, stream>>>(
        ehid, etw2, exp_b2, comb, lists, cnts, starts, eout, hf);
  }
  combine_kernel<<<dim3(2048), dim3(256), 0, stream>>>(out, eout, posA, posB);
}

// Round 14
// 864.304 us; speedup vs baseline: 1.3531x; 1.0077x over previous
//
#include <hip/hip_runtime.h>

// TransformerBlock (attn + MLP + top2-MoE) on MI355X.
// Pre-gate chain in split-fp16 3-term MFMA (fp32-class accuracy so the MoE
// top-2 selection matches the fp32 reference); post-gate experts in plain
// fp16 MFMA, SPARSE top-2 dispatch, atomic-free scatter.
// R14: attn retiled QBLK=128 / 8 waves (512 thr): K/V staging + barriers per
// MFMA halve (each staged tile now feeds 8 waves); 48KB LDS -> 3 blocks/CU.

typedef _Float16 f16;
typedef _Float16 f16x4 __attribute__((ext_vector_type(4)));
typedef _Float16 f16x8 __attribute__((ext_vector_type(8)));
typedef float f32x4 __attribute__((ext_vector_type(4)));
typedef unsigned short ushort;

#define MFMA16(a, b, c) __builtin_amdgcn_mfma_f32_16x16x32_f16((a), (b), (c), 0, 0, 0)

__device__ __forceinline__ void gload16(void* lds, const void* g) {
  __builtin_amdgcn_global_load_lds(
      (const __attribute__((address_space(1))) unsigned int*)g,
      (__attribute__((address_space(3))) unsigned int*)lds, 16, 0, 0);
}

__device__ __forceinline__ void split2(float t, f16& h, f16& l) {
  h = (f16)t;
  l = (f16)(t - (float)h);
}

__device__ __forceinline__ float gelu_f(float x) {  // exact (pre-gate path)
  return 0.5f * x * (1.0f + erff(x * 0.70710678118654752f));
}

__device__ __forceinline__ float gelu_fast(float x) {  // tanh-approx (post-gate experts)
  return x / (1.0f + __expf(-1.5957691216f * (x + 0.044715f * x * x * x)));
}

// ---------------- LayerNorm: one wave per row of 768; split-fp16 planes out ----------------
__global__ __launch_bounds__(256) void ln_kernel(
    const float* __restrict__ x, const float* __restrict__ gam,
    const float* __restrict__ bet, f16* __restrict__ oh, f16* __restrict__ ol) {
  const int w = threadIdx.x >> 6, lane = threadIdx.x & 63;
  const size_t row = (size_t)blockIdx.x * 4 + w;
  const float* xr = x + row * 768;
  f32x4 v[3];
  float s = 0.0f;
#pragma unroll
  for (int c = 0; c < 3; c++) {
    v[c] = *(const f32x4*)(xr + c * 256 + lane * 4);
    s += v[c][0] + v[c][1] + v[c][2] + v[c][3];
  }
#pragma unroll
  for (int off = 32; off; off >>= 1) s += __shfl_xor(s, off);
  const float mean = s * (1.0f / 768.0f);
  float q = 0.0f;
#pragma unroll
  for (int c = 0; c < 3; c++)
#pragma unroll
    for (int j = 0; j < 4; j++) {
      float d = v[c][j] - mean;
      q += d * d;
    }
#pragma unroll
  for (int off = 32; off; off >>= 1) q += __shfl_xor(q, off);
  // precise rsqrt: rsqrtf() approx (~1e-5 rel) would risk gate flips downstream
  const float rstd = 1.0f / sqrtf(q * (1.0f / 768.0f) + 1e-5f);
#pragma unroll
  for (int c = 0; c < 3; c++) {
    const int col = c * 256 + lane * 4;
    f32x4 gv = *(const f32x4*)(gam + col);
    f32x4 bv = *(const f32x4*)(bet + col);
    f16x4 yh, yl;
#pragma unroll
    for (int j = 0; j < 4; j++) {
      float y = (v[c][j] - mean) * rstd * gv[j] + bv[j];
      f16 hh, ll;
      split2(y, hh, ll);
      yh[j] = hh;
      yl[j] = ll;
    }
    *(f16x4*)(oh + row * 768 + col) = yh;
    *(f16x4*)(ol + row * 768 + col) = yl;
  }
}

// ---------------- fp32 -> split fp16 (elementwise, x4) ----------------
__global__ __launch_bounds__(256) void convert_split_k(
    const float* __restrict__ in, f16* __restrict__ oh, f16* __restrict__ ol,
    int n4) {
  const int i = blockIdx.x * 256 + threadIdx.x;
  if (i >= n4) return;
  f32x4 v = ((const f32x4*)in)[i];
  f16x4 h, l;
#pragma unroll
  for (int j = 0; j < 4; j++) {
    f16 hh, ll;
    split2(v[j], hh, ll);
    h[j] = hh;
    l[j] = ll;
  }
  ((f16x4*)oh)[i] = h;
  ((f16x4*)ol)[i] = l;
}

// ---------------- fp32 [R][ldin] (32x32 tiles) -> fp16 [C][R] split ----------------
__global__ __launch_bounds__(256) void transpose_k(
    const float* __restrict__ in, f16* __restrict__ oh, f16* __restrict__ ol,
    int R, int ldin) {
  __shared__ float t[32][33];
  const int tx = threadIdx.x & 31, ty = threadIdx.x >> 5;
  const int r0 = blockIdx.y * 32, c0 = blockIdx.x * 32;
#pragma unroll
  for (int i = 0; i < 4; i++)
    t[ty + 8 * i][tx] = in[(size_t)(r0 + ty + 8 * i) * ldin + c0 + tx];
  __syncthreads();
#pragma unroll
  for (int i = 0; i < 4; i++) {
    const float val = t[tx][ty + 8 * i];
    const size_t o = (size_t)(c0 + ty + 8 * i) * R + r0 + tx;
    f16 hh, ll;
    split2(val, hh, ll);
    oh[o] = hh;
    ol[o] = ll;
  }
}

// ---------------- per-expert fp32 [R][C] -> f16 [C][R] (blockIdx.z = expert) ----------------
__global__ __launch_bounds__(256) void etrans_kernel(
    const float* __restrict__ in0, f16* __restrict__ out0, int R, int C) {
  const size_t eoff = (size_t)blockIdx.z * R * C;
  const float* in = in0 + eoff;
  f16* out = out0 + eoff;
  __shared__ float t[32][33];
  const int tx = threadIdx.x & 31, ty = threadIdx.x >> 5;
  const int r0 = blockIdx.y * 32, c0 = blockIdx.x * 32;
#pragma unroll
  for (int i = 0; i < 4; i++)
    t[ty + 8 * i][tx] = in[(size_t)(r0 + ty + 8 * i) * C + c0 + tx];
  __syncthreads();
#pragma unroll
  for (int i = 0; i < 4; i++)
    out[(size_t)(c0 + ty + 8 * i) * R + r0 + tx] = (f16)t[tx][ty + 8 * i];
}

// ---------------- V transpose: qkv planes (v part) -> [B,H,64,1024]; z = hi/lo ----------------
__global__ __launch_bounds__(256) void vtrans_kernel(
    const ushort* __restrict__ srcH, const ushort* __restrict__ srcL,
    ushort* __restrict__ dstH, ushort* __restrict__ dstL) {
  const int nt = blockIdx.x, bh = blockIdx.y;
  const ushort* src = blockIdx.z ? srcL : srcH;
  ushort* dst = blockIdx.z ? dstL : dstH;
  const int b = bh / 12, h = bh % 12;
  __shared__ ushort t[64][65];
  const int tid = threadIdx.x;
#pragma unroll
  for (int i = 0; i < 16; i++) {
    const int idx = i * 256 + tid;
    const int r = idx >> 6, c = idx & 63;
    t[r][c] = src[((size_t)b * 1024 + nt * 64 + r) * 2304 + 1536 + h * 64 + c];
  }
  __syncthreads();
#pragma unroll
  for (int i = 0; i < 16; i++) {
    const int idx = i * 256 + tid;
    const int d = idx >> 6, n = idx & 63;
    dst[((size_t)bh * 64 + d) * 1024 + nt * 64 + n] = t[n][d];
  }
}

// ---------------- split-fp16 3-term GEMM: C = A·B^T (+bias), A[M,K] B[N,K] ----------------
// 128x128 tile, BK=64, 8 waves (2m x 4n, 512 thr), acc[4][2]/thread.
// LDS 4 planes x [128][64] = 64KB -> 2 blocks/CU (16 waves/CU). Full-128B-row
// staging, XOR chunk-swizzle (pre-swizzled source + same-involution read).
// XCD-chunked 1-D grid (nbx = N tiles).
template <int MODE>
__global__ __launch_bounds__(512) void gemm_split(
    const f16* __restrict__ Ah, const f16* __restrict__ Al, int lda,
    const f16* __restrict__ Bh, const f16* __restrict__ Bl, int ldb,
    const float* __restrict__ bias, const float* __restrict__ residF,
    const f16* __restrict__ residH, const f16* __restrict__ residL, int addto,
    float* __restrict__ outF, f16* __restrict__ outH, f16* __restrict__ outL,
    int ldo, int K, int nbx) {
  __shared__ __align__(16) f16 Ash[128][64];
  __shared__ __align__(16) f16 Asl[128][64];
  __shared__ __align__(16) f16 Bsh[128][64];
  __shared__ __align__(16) f16 Bsl[128][64];
  const int per = gridDim.x >> 3;
  const int lin = ((int)blockIdx.x & 7) * per + ((int)blockIdx.x >> 3);
  const int bx = lin % nbx, by = lin / nbx;
  const int tid = threadIdx.x;
  const int lane = tid & 63, wid = tid >> 6;
  const int wm = wid >> 2, wn4 = wid & 3;  // 2m x 4n wave grid
  const int g = lane >> 4, lr = lane & 15;
  const int swz = (((tid & 7) ^ ((tid >> 3) & 7)) << 3);  // element offset
  const size_t m0 = (size_t)by * 128, n0 = (size_t)bx * 128;
  f32x4 acc[4][2] = {};
  for (int k0 = 0; k0 < K; k0 += 64) {
    __syncthreads();
#pragma unroll
    for (int s = 0; s < 2; s++) {
      const int u = s * 512 + tid;  // 16B unit within a 16KB plane
      const int row = u >> 3;       // s*512 = 64 rows: row&7 invariant vs tid
      const size_t ga = (m0 + row) * (size_t)lda + k0 + swz;
      const size_t gb = (n0 + row) * (size_t)ldb + k0 + swz;
      gload16(&Ash[0][0] + u * 8, Ah + ga);
      gload16(&Asl[0][0] + u * 8, Al + ga);
      gload16(&Bsh[0][0] + u * 8, Bh + gb);
      gload16(&Bsl[0][0] + u * 8, Bl + gb);
    }
    __syncthreads();
#pragma unroll
    for (int kk = 0; kk < 2; kk++) {
      const int c = (((kk * 4 + g) ^ (lr & 7)) << 3);
      f16x8 fah[4], fal[4], fbh[2], fbl[2];
#pragma unroll
      for (int mi = 0; mi < 4; mi++) {
        const int row = wm * 64 + mi * 16 + lr;
        fah[mi] = *(const f16x8*)&Ash[row][c];
        fal[mi] = *(const f16x8*)&Asl[row][c];
      }
#pragma unroll
      for (int ni = 0; ni < 2; ni++) {
        const int row = wn4 * 32 + ni * 16 + lr;
        fbh[ni] = *(const f16x8*)&Bsh[row][c];
        fbl[ni] = *(const f16x8*)&Bsl[row][c];
      }
#pragma unroll
      for (int mi = 0; mi < 4; mi++)
#pragma unroll
        for (int ni = 0; ni < 2; ni++) {
          acc[mi][ni] = MFMA16(fah[mi], fbh[ni], acc[mi][ni]);
          acc[mi][ni] = MFMA16(fah[mi], fbl[ni], acc[mi][ni]);
          acc[mi][ni] = MFMA16(fal[mi], fbh[ni], acc[mi][ni]);
        }
    }
  }
#pragma unroll
  for (int ni = 0; ni < 2; ni++) {
    const size_t col = n0 + wn4 * 32 + ni * 16 + lr;
    const float bv = bias ? bias[col] : 0.0f;
#pragma unroll
    for (int mi = 0; mi < 4; mi++) {
      const size_t rowb = m0 + wm * 64 + mi * 16 + g * 4;
      const f32x4 c = acc[mi][ni];
#pragma unroll
      for (int r = 0; r < 4; r++) {
        const size_t idx = (rowb + r) * (size_t)ldo + col;
        const float v = c[r] + bv;
        if constexpr (MODE == 0) {
          f16 hh, ll;
          split2(v, hh, ll);
          outH[idx] = hh;
          outL[idx] = ll;
        } else if constexpr (MODE == 1) {
          const float tt = v + residF[idx];
          f16 hh, ll;
          split2(tt, hh, ll);
          outH[idx] = hh;
          outL[idx] = ll;
        } else if constexpr (MODE == 2) {
          const float tt = gelu_f(v);
          f16 hh, ll;
          split2(tt, hh, ll);
          outH[idx] = hh;
          outL[idx] = ll;
        } else {
          outF[idx] = addto ? (outF[idx] + v)
                            : ((float)residH[idx] + (float)residL[idx] + v);
        }
      }
    }
  }
}

// ---------------- MoE expert GEMM 1: 64x128 tile, single-buffer 24KB, indirect A ----------------
// 1-D grid 3168 (= 12 x 264). ehid[gr][1536] = gelu_fast(xm[list] . w1t[e] + b1).
__global__ __launch_bounds__(256) void gemm_moe1(
    const f16* __restrict__ xmh, const f16* __restrict__ etw1,
    const float* __restrict__ eb1, const int* __restrict__ lists,
    const int* __restrict__ cnts, const int* __restrict__ starts,
    f16* __restrict__ ehid, int hf) {
  const int per = gridDim.x >> 3;  // 3168/8 = 396
  const int lin = (blockIdx.x & 7) * per + (blockIdx.x >> 3);
  const int bx = lin % 12, by = lin / 12;
  const int m0 = by * 64;
  if (m0 >= starts[4]) return;
  int e = 0;
  while (e < 3 && m0 >= starts[e + 1]) e++;
  const int cnt = cnts[e];
  const int loc0 = m0 - starts[e];
  const int* list = lists + e * 8192;
  const f16* Bw = etw1 + ((size_t)e * 3072 + hf * 1536) * 768;
  const float* bias = eb1 + e * 3072 + hf * 1536;
  __shared__ __align__(16) f16 As[64][64];   // 8 KB
  __shared__ __align__(16) f16 Bs[128][64];  // 16 KB
  const int tid = threadIdx.x;
  const int lane = tid & 63, wn = tid >> 6;  // wave -> 32-col slice
  const int g = lane >> 4, lr = lane & 15;
  const int swz = (((tid & 7) ^ ((tid >> 3) & 7)) << 3);
  const int n0 = bx * 128;
  size_t arow[2];
#pragma unroll
  for (int s = 0; s < 2; s++) {
    const int row = (s * 256 + tid) >> 3;
    const int loc = loc0 + row;
    arow[s] = (size_t)list[loc < cnt ? loc : cnt - 1] * 768;
  }
  f32x4 acc[4][2] = {};
  for (int k0 = 0; k0 < 768; k0 += 64) {
    __syncthreads();
#pragma unroll
    for (int s = 0; s < 2; s++) {
      const int u = s * 256 + tid;
      gload16(&As[0][0] + u * 8, xmh + arow[s] + k0 + swz);
    }
#pragma unroll
    for (int s = 0; s < 4; s++) {
      const int u = s * 256 + tid;
      const int row = u >> 3;
      gload16(&Bs[0][0] + u * 8, Bw + (size_t)(n0 + row) * 768 + k0 + swz);
    }
    __syncthreads();
#pragma unroll
    for (int kk = 0; kk < 2; kk++) {
      const int c = (((kk * 4 + g) ^ (lr & 7)) << 3);
      f16x8 fa[4], fb[2];
#pragma unroll
      for (int mi = 0; mi < 4; mi++) fa[mi] = *(const f16x8*)&As[mi * 16 + lr][c];
#pragma unroll
      for (int ni = 0; ni < 2; ni++)
        fb[ni] = *(const f16x8*)&Bs[wn * 32 + ni * 16 + lr][c];
#pragma unroll
      for (int mi = 0; mi < 4; mi++)
#pragma unroll
        for (int ni = 0; ni < 2; ni++)
          acc[mi][ni] = MFMA16(fa[mi], fb[ni], acc[mi][ni]);
    }
  }
#pragma unroll
  for (int ni = 0; ni < 2; ni++) {
    const int col = n0 + wn * 32 + ni * 16 + lr;
    const float bv = bias[col];
#pragma unroll
    for (int mi = 0; mi < 4; mi++) {
      const int gr = m0 + mi * 16 + g * 4;
      const f32x4 c = acc[mi][ni];
#pragma unroll
      for (int r = 0; r < 4; r++)
        ehid[(size_t)(gr + r) * 1536 + col] = (f16)gelu_fast(c[r] + bv);
    }
  }
}

// ---------------- MoE expert GEMM 2: 64x128 tile, single-buffer 24KB, NO atomics ----------------
// 1-D grid 1584 (= 6 x 264). eout[gr] (f16) = w*(acc+b2) (hf0) / += w*acc (hf1).
__global__ __launch_bounds__(256) void gemm_moe2(
    const f16* __restrict__ ehid, const f16* __restrict__ etw2,
    const float* __restrict__ eb2, const float* __restrict__ comb,
    const int* __restrict__ lists, const int* __restrict__ cnts,
    const int* __restrict__ starts, f16* __restrict__ eout, int hf) {
  const int per = gridDim.x >> 3;  // 1584/8 = 198
  const int lin = (blockIdx.x & 7) * per + (blockIdx.x >> 3);
  const int bx = lin % 6, by = lin / 6;
  const int m0 = by * 64;
  if (m0 >= starts[4]) return;
  int e = 0;
  while (e < 3 && m0 >= starts[e + 1]) e++;
  const int cnt = cnts[e];
  const int st = starts[e];
  const int* list = lists + e * 8192;
  const f16* Bw = etw2 + (size_t)e * 768 * 3072 + hf * 1536;
  __shared__ __align__(16) f16 As[64][64];   // 8 KB
  __shared__ __align__(16) f16 Bs[128][64];  // 16 KB
  const int tid = threadIdx.x;
  const int lane = tid & 63, wn = tid >> 6;
  const int g = lane >> 4, lr = lane & 15;
  const int swz = (((tid & 7) ^ ((tid >> 3) & 7)) << 3);
  const int n0 = bx * 128;
  f32x4 acc[4][2] = {};
  for (int k0 = 0; k0 < 1536; k0 += 64) {
    __syncthreads();
#pragma unroll
    for (int s = 0; s < 2; s++) {
      const int u = s * 256 + tid;
      const int row = u >> 3;
      gload16(&As[0][0] + u * 8, ehid + (size_t)(m0 + row) * 1536 + k0 + swz);
    }
#pragma unroll
    for (int s = 0; s < 4; s++) {
      const int u = s * 256 + tid;
      const int row = u >> 3;
      gload16(&Bs[0][0] + u * 8, Bw + (size_t)(n0 + row) * 3072 + k0 + swz);
    }
    __syncthreads();
#pragma unroll
    for (int kk = 0; kk < 2; kk++) {
      const int c = (((kk * 4 + g) ^ (lr & 7)) << 3);
      f16x8 fa[4], fb[2];
#pragma unroll
      for (int mi = 0; mi < 4; mi++) fa[mi] = *(const f16x8*)&As[mi * 16 + lr][c];
#pragma unroll
      for (int ni = 0; ni < 2; ni++)
        fb[ni] = *(const f16x8*)&Bs[wn * 32 + ni * 16 + lr][c];
#pragma unroll
      for (int mi = 0; mi < 4; mi++)
#pragma unroll
        for (int ni = 0; ni < 2; ni++)
          acc[mi][ni] = MFMA16(fa[mi], fb[ni], acc[mi][ni]);
    }
  }
#pragma unroll
  for (int ni = 0; ni < 2; ni++) {
    const int col = n0 + wn * 32 + ni * 16 + lr;
    const float bv = hf ? 0.0f : eb2[e * 768 + col];
#pragma unroll
    for (int mi = 0; mi < 4; mi++) {
      const int gr = m0 + mi * 16 + g * 4;
      const f32x4 c = acc[mi][ni];
#pragma unroll
      for (int r = 0; r < 4; r++) {
        const int loc = gr + r - st;
        if (loc < cnt) {
          const int tok = list[loc];
          const float w = comb[(size_t)tok * 4 + e];
          const size_t oi = (size_t)(gr + r) * 768 + col;
          const float v = w * (c[r] + bv);
          eout[oi] = hf ? (f16)((float)eout[oi] + v) : (f16)v;
        }
      }
    }
  }
}

// ---------------- final combine: out[t] = x2[t] + eout[posA[t]] + eout[posB[t]] ----------------
__global__ __launch_bounds__(256) void combine_kernel(
    float* __restrict__ out, const f16* __restrict__ eout,
    const int* __restrict__ posA, const int* __restrict__ posB) {
  const int w = threadIdx.x >> 6, lane = threadIdx.x & 63;
  const size_t row = (size_t)blockIdx.x * 4 + w;
  const size_t pa = (size_t)posA[row] * 768, pb = (size_t)posB[row] * 768;
#pragma unroll
  for (int c = 0; c < 3; c++) {
    const int col = c * 256 + lane * 4;
    f32x4 v = *(const f32x4*)(out + row * 768 + col);
    const f16x4 a = *(const f16x4*)(eout + pa + col);
    const f16x4 b = *(const f16x4*)(eout + pb + col);
#pragma unroll
    for (int j = 0; j < 4; j++) v[j] += (float)a[j] + (float)b[j];
    *(f32x4*)(out + row * 768 + col) = v;
  }
}

// ---------------- flash attention, QBLK=128 (8 waves), KVBLK=64 ----------------
// 768 blocks, XCD-swizzled. No-max softmax P=exp(s/8); row-sum via MFMA x ones.
// QK: q_hi x (k_hi + k_lo). PV: P single fp16 plane x (v_hi + v_lo).
// Each staged K/V tile feeds 8 waves (2x the work per barrier vs QBLK=64).
__global__ __launch_bounds__(512) void attn_kernel(
    const f16* __restrict__ qh, const f16* __restrict__ ql,
    const f16* __restrict__ vth, const f16* __restrict__ vtl,
    f16* __restrict__ ch, f16* __restrict__ cl) {
  const int wg = blockIdx.y * 8 + blockIdx.x;           // 0..767
  const int nid = (wg & 7) * 96 + (wg >> 3);            // bijective (768%8==0)
  const int qt = nid & 7, bh = nid >> 3;
  const int b = bh / 12, h = bh % 12;
  const int tid = threadIdx.x;
  const int lane = tid & 63, w = tid >> 6;              // 8 waves x 16 q-rows
  const int g = lane >> 4, lr = lane & 15;
  __shared__ __align__(16) f16 Ksh[64][64];
  __shared__ __align__(16) f16 Ksl[64][64];
  __shared__ __align__(16) f16 Vsh[64][64];
  __shared__ __align__(16) f16 Vsl[64][64];
  __shared__ __align__(16) char Psh[8][2048];  // per-wave P (16 x 64 f16), XOR-swizzled
  const int swz = (((tid & 7) ^ ((tid >> 3) & 7)) << 3);
  const size_t qrow = (size_t)b * 1024 + qt * 128 + w * 16 + lr;
  const f16* qbh = qh + qrow * 2304 + h * 64;
  const f16x8 qfh0 = *(const f16x8*)(qbh + g * 8);
  const f16x8 qfh1 = *(const f16x8*)(qbh + 32 + g * 8);
  const f16x8 ones = {(f16)1, (f16)1, (f16)1, (f16)1, (f16)1, (f16)1, (f16)1, (f16)1};
  f32x4 o[4] = {};
  f32x4 osum = {};
  const f16* kbh = qh + ((size_t)b * 1024) * 2304 + 768 + h * 64;
  const f16* kbl = ql + ((size_t)b * 1024) * 2304 + 768 + h * 64;
  const f16* vbh = vth + (size_t)bh * 64 * 1024;
  const f16* vbl = vtl + (size_t)bh * 64 * 1024;
  char* pbh = Psh[w];
  for (int kv0 = 0; kv0 < 1024; kv0 += 64) {
    __syncthreads();
    {  // 512 threads: one 16B unit each per 8KB plane
      const int row = tid >> 3;
      const size_t ko = (size_t)(kv0 + row) * 2304 + swz;
      gload16(&Ksh[0][0] + tid * 8, kbh + ko);
      gload16(&Ksl[0][0] + tid * 8, kbl + ko);
      const size_t vo = (size_t)row * 1024 + kv0 + swz;  // row = d
      gload16(&Vsh[0][0] + tid * 8, vbh + vo);
      gload16(&Vsl[0][0] + tid * 8, vbl + vo);
    }
    __syncthreads();
    f32x4 s[4];
    __builtin_amdgcn_s_setprio(1);
#pragma unroll
    for (int nb = 0; nb < 4; nb++) {
      const int row = nb * 16 + lr;
      const int c0 = ((g ^ (lr & 7)) << 3);
      const int c1 = (((4 + g) ^ (lr & 7)) << 3);
      const f16x8 kh0 = *(const f16x8*)&Ksh[row][c0];
      const f16x8 kh1 = *(const f16x8*)&Ksh[row][c1];
      const f16x8 kl0 = *(const f16x8*)&Ksl[row][c0];
      const f16x8 kl1 = *(const f16x8*)&Ksl[row][c1];
      f32x4 t = {};
      t = MFMA16(qfh0, kh0, t);
      t = MFMA16(qfh1, kh1, t);
      t = MFMA16(qfh0, kl0, t);
      t = MFMA16(qfh1, kl1, t);
      s[nb] = t;
    }
    __builtin_amdgcn_s_setprio(0);
    // P = exp(s/8), no max subtraction (shift-invariant; overflow at 35 sigma)
#pragma unroll
    for (int nb = 0; nb < 4; nb++)
#pragma unroll
      for (int r = 0; r < 4; r++) {
        const int row = g * 4 + r;
        const int sw = ((nb * 16 + lr) * 2) ^ ((row & 7) << 4);
        *(f16*)(pbh + row * 128 + sw) = (f16)__expf(s[nb][r] * 0.125f);
      }
    // PV + row-sum via MFMA x ones
    __builtin_amdgcn_s_setprio(1);
#pragma unroll
    for (int ks = 0; ks < 2; ks++) {
      const int pc = (ks * 64 + g * 16) ^ ((lr & 7) << 4);
      const f16x8 pfh = *(const f16x8*)(pbh + lr * 128 + pc);
      osum = MFMA16(pfh, ones, osum);
#pragma unroll
      for (int db = 0; db < 4; db++) {
        const int vrow = db * 16 + lr;
        const int vc = (((ks * 4 + g) ^ (lr & 7)) << 3);
        const f16x8 vfh = *(const f16x8*)&Vsh[vrow][vc];
        const f16x8 vfl = *(const f16x8*)&Vsl[vrow][vc];
        o[db] = MFMA16(pfh, vfh, o[db]);
        o[db] = MFMA16(pfh, vfl, o[db]);
      }
    }
    __builtin_amdgcn_s_setprio(0);
  }
  const size_t orow = (size_t)b * 1024 + qt * 128 + w * 16 + g * 4;
#pragma unroll
  for (int r = 0; r < 4; r++) {
    const float inv = 1.0f / osum[r];
#pragma unroll
    for (int db = 0; db < 4; db++) {
      const float val = o[db][r] * inv;
      const size_t oi = (orow + r) * 768 + h * 64 + db * 16 + lr;
      f16 hh, ll;
      split2(val, hh, ll);
      ch[oi] = hh;
      cl[oi] = ll;
    }
  }
}

// ---------------- gate: fp32 logits from split xm, top-2, softmax -> comb[T][4] ----------------
__global__ __launch_bounds__(256) void gate_kernel(
    const f16* __restrict__ xmh, const f16* __restrict__ xml,
    const float* __restrict__ gw, const float* __restrict__ gb,
    float* __restrict__ comb) {
  const int t = blockIdx.x * 256 + threadIdx.x;
  const f16* xrh = xmh + (size_t)t * 768;
  const f16* xrl = xml + (size_t)t * 768;
  float a0 = 0, a1 = 0, a2 = 0, a3 = 0;
  for (int k = 0; k < 768; k += 4) {
    const f16x4 xh = *(const f16x4*)(xrh + k);
    const f16x4 xl = *(const f16x4*)(xrl + k);
    const f32x4 w0 = *(const f32x4*)(gw + k);
    const f32x4 w1 = *(const f32x4*)(gw + 768 + k);
    const f32x4 w2 = *(const f32x4*)(gw + 1536 + k);
    const f32x4 w3 = *(const f32x4*)(gw + 2304 + k);
#pragma unroll
    for (int j = 0; j < 4; j++) {
      const float xv = (float)xh[j] + (float)xl[j];
      a0 += xv * w0[j];
      a1 += xv * w1[j];
      a2 += xv * w2[j];
      a3 += xv * w3[j];
    }
  }
  float l[4] = {a0 + gb[0], a1 + gb[1], a2 + gb[2], a3 + gb[3]};
  int i0 = 0;
#pragma unroll
  for (int e = 1; e < 4; e++)
    if (l[e] > l[i0]) i0 = e;  // strict > matches top_k tie order
  int i1 = -1;
#pragma unroll
  for (int e = 0; e < 4; e++)
    if (e != i0 && (i1 < 0 || l[e] > l[i1])) i1 = e;
  const float e1 = expf(l[i1] - l[i0]);
  const float inv = 1.0f / (1.0f + e1);
  float c[4] = {0.0f, 0.0f, 0.0f, 0.0f};
  c[i0] = inv;
  c[i1] = e1 * inv;
  f32x4 cv = {c[0], c[1], c[2], c[3]};
  *(f32x4*)(comb + (size_t)t * 4) = cv;
}

// ---------------- per-expert token lists + 128-aligned segment starts + inverse map ----------------
__global__ __launch_bounds__(1024) void listbuild_kernel(
    const float* __restrict__ comb, int* __restrict__ lists /*[4][8192]*/,
    int* __restrict__ cnts /*[4]*/, int* __restrict__ starts /*[5]*/,
    int* __restrict__ posA /*[8192]*/, int* __restrict__ posB /*[8192]*/) {
  __shared__ int wsum[16];
  const int tid = threadIdx.x;
  const int lane = tid & 63, wv = tid >> 6;
  unsigned seen = 0;  // bit c: token c*1024+tid already assigned once
  int segbase = 0;    // padded global segment base (identical on all threads)
  for (int e = 0; e < 4; e++) {
    int base = 0;
    for (int c = 0; c < 8; c++) {
      const int t = c * 1024 + tid;
      const int flag = comb[(size_t)t * 4 + e] > 0.0f ? 1 : 0;
      const unsigned long long mask = __ballot(flag);
      const int myrank = __popcll(mask & ((1ull << lane) - 1ull));
      if (lane == 0) wsum[wv] = __popcll(mask);
      __syncthreads();
      int wbase = 0, total = 0;
#pragma unroll
      for (int i = 0; i < 16; i++) {
        if (i < wv) wbase += wsum[i];
        total += wsum[i];
      }
      if (flag) {
        const int idx = base + wbase + myrank;
        lists[e * 8192 + idx] = t;
        const int gidx = segbase + idx;
        if ((seen >> c) & 1) posB[t] = gidx;
        else { posA[t] = gidx; seen |= 1u << c; }
      }
      base += total;
      __syncthreads();
    }
    if (tid == 0) cnts[e] = base;
    segbase += (base + 127) & ~127;
  }
  if (tid == 0) {
    int s = 0;
    starts[0] = 0;
#pragma unroll
    for (int e = 0; e < 4; e++) {
      s += (cnts[e] + 127) & ~127;
      starts[e + 1] = s;
    }
  }
}

extern "C" void kernel_launch(void* const* d_in, const int* in_sizes, int n_in,
                              void* d_out, int out_size, void* d_ws,
                              size_t ws_size, hipStream_t stream) {
  const float* x = (const float*)d_in[0];
  const float* ln1g = (const float*)d_in[1];
  const float* ln1b = (const float*)d_in[2];
  const float* in_w = (const float*)d_in[3];
  const float* in_b = (const float*)d_in[4];
  const float* out_w = (const float*)d_in[5];
  const float* out_b = (const float*)d_in[6];
  const float* mlp_w1 = (const float*)d_in[7];
  const float* mlp_b1 = (const float*)d_in[8];
  const float* mlp_w2 = (const float*)d_in[9];
  const float* mlp_b2 = (const float*)d_in[10];
  const float* ln2g = (const float*)d_in[11];
  const float* ln2b = (const float*)d_in[12];
  const float* gate_w = (const float*)d_in[13];
  const float* gate_b = (const float*)d_in[14];
  const float* exp_w1 = (const float*)d_in[15];
  const float* exp_b1 = (const float*)d_in[16];
  const float* exp_w2 = (const float*)d_in[17];
  const float* exp_b2 = (const float*)d_in[18];
  float* out = (float*)d_out;
  (void)in_sizes; (void)n_in; (void)out_size;

  const size_t MB = 1ull << 20;
  if (ws_size < 130 * MB) return;  // clean absmax failure (not a crash) if ws too small
  char* ws = (char*)d_ws;
  // Pre-MoE layout (as R6-R13, lifetimes hand-verified):
  // S1 [0,24MB):   h planes -> attn ctx planes -> w1t planes -> xm planes
  // S2 [24,33MB):  in_w+out_w planes -> w2t planes
  // S3 [33,105MB): qkv planes -> mlp hid planes
  // S4 [105,129MB): vt planes -> x1 planes
  // MoE phase (everything except xmh [0,12MB) is dead after gate):
  //   etw1 [12,30) etw2 [30,48) ehid [48,100) eout(f16) [100,126)
  // S5 [129MB..): comb, lists, cnts, starts, posA, posB
  char* S1 = ws;
  char* S2 = ws + 24 * MB;
  char* S3 = ws + 33 * MB;
  char* S4 = ws + 105 * MB;
  char* S5 = ws + 129 * MB;

  f16* h_h = (f16*)S1;                       // 12,582,912 B each
  f16* h_l = (f16*)(S1 + 12 * MB);
  f16* ctx_h = (f16*)S1;                     // after qkv gemm, h dead
  f16* ctx_l = (f16*)(S1 + 12 * MB);
  f16* w1t_h = (f16*)S1;                     // after out-proj, ctx dead
  f16* w1t_l = (f16*)(S1 + 4718592);
  f16* xmh = (f16*)S1;                       // after mlp, w1t dead
  f16* xml = (f16*)(S1 + 12 * MB);           // dead after gate

  f16* inw_h = (f16*)S2;                     // 3,538,944 B each
  f16* inw_l = (f16*)(S2 + 3538944);
  f16* outw_h = (f16*)(S2 + 7077888);        // 1,179,648 B each
  f16* outw_l = (f16*)(S2 + 8257536);
  f16* w2t_h = (f16*)S2;                     // after out-proj, inw/outw dead
  f16* w2t_l = (f16*)(S2 + 4718592);

  f16* qkv_h = (f16*)S3;                     // 37,748,736 B each
  f16* qkv_l = (f16*)(S3 + 36 * MB);
  f16* hid_h = (f16*)S3;                     // after attn, qkv dead; [8192][1536] each
  f16* hid_l = (f16*)(S3 + 24 * MB);

  f16* vt_h = (f16*)S4;                      // 12,582,912 B each
  f16* vt_l = (f16*)(S4 + 12 * MB);
  f16* x1h = (f16*)S4;                       // after attn, vt dead
  f16* x1l = (f16*)(S4 + 12 * MB);

  // MoE-phase scratch (xml/w2t/hid/x1 all dead by first use):
  f16* etw1 = (f16*)(ws + 12 * MB);          // [4][3072][768] f16 = 18MB
  f16* etw2 = (f16*)(ws + 30 * MB);          // [4][768][3072] f16 = 18MB
  f16* ehid = (f16*)(ws + 48 * MB);          // [16896][1536] f16 = 51.9MB
  f16* eout = (f16*)(ws + 100 * MB);         // [16896][768] f16 = 25.9MB

  float* comb = (float*)S5;                  // 131,072 B
  int* lists = (int*)(S5 + 131072);          // 4 x 8192 ints
  int* cnts = (int*)(S5 + 262144);           // 4 ints
  int* starts = (int*)(S5 + 262144 + 64);    // 5 ints
  int* posA = (int*)(S5 + 262144 + 256);     // 8192 ints
  int* posB = (int*)(S5 + 262144 + 256 + 32768);

  // ---- attention ----
  convert_split_k<<<dim3(1728), dim3(256), 0, stream>>>(in_w, inw_h, inw_l, 442368);
  convert_split_k<<<dim3(576), dim3(256), 0, stream>>>(out_w, outw_h, outw_l, 147456);
  ln_kernel<<<dim3(2048), dim3(256), 0, stream>>>(x, ln1g, ln1b, h_h, h_l);
  gemm_split<0><<<dim3(1152), dim3(512), 0, stream>>>(
      h_h, h_l, 768, inw_h, inw_l, 768, in_b, nullptr, nullptr, nullptr, 0,
      nullptr, qkv_h, qkv_l, 2304, 768, 18);
  vtrans_kernel<<<dim3(16, 96, 2), dim3(256), 0, stream>>>(
      (const ushort*)qkv_h, (const ushort*)qkv_l, (ushort*)vt_h, (ushort*)vt_l);
  attn_kernel<<<dim3(8, 96), dim3(512), 0, stream>>>(qkv_h, qkv_l, vt_h, vt_l, ctx_h, ctx_l);
  gemm_split<1><<<dim3(384), dim3(512), 0, stream>>>(
      ctx_h, ctx_l, 768, outw_h, outw_l, 768, out_b, x, nullptr, nullptr, 0,
      nullptr, x1h, x1l, 768, 768, 6);

  // ---- MLP (hidden in two halves of 1536; result -> out (=x2, fp32)) ----
  transpose_k<<<dim3(96, 24), dim3(256), 0, stream>>>(mlp_w1, w1t_h, w1t_l, 768, 3072);
  transpose_k<<<dim3(24, 96), dim3(256), 0, stream>>>(mlp_w2, w2t_h, w2t_l, 3072, 768);
  gemm_split<2><<<dim3(768), dim3(512), 0, stream>>>(
      x1h, x1l, 768, w1t_h, w1t_l, 768, mlp_b1, nullptr, nullptr, nullptr, 0,
      nullptr, hid_h, hid_l, 1536, 768, 12);
  gemm_split<3><<<dim3(384), dim3(512), 0, stream>>>(
      hid_h, hid_l, 1536, w2t_h, w2t_l, 3072, mlp_b2, nullptr, x1h, x1l, 0,
      out, nullptr, nullptr, 768, 1536, 6);
  gemm_split<2><<<dim3(768), dim3(512), 0, stream>>>(
      x1h, x1l, 768, w1t_h + (size_t)1536 * 768, w1t_l + (size_t)1536 * 768, 768,
      mlp_b1 + 1536, nullptr, nullptr, nullptr, 0, nullptr, hid_h, hid_l, 1536, 768, 12);
  gemm_split<3><<<dim3(384), dim3(512), 0, stream>>>(
      hid_h, hid_l, 1536, w2t_h + 1536, w2t_l + 1536, 3072,
      nullptr, nullptr, nullptr, nullptr, 1, out, nullptr, nullptr, 768, 1536, 6);

  // ---- MoE (sparse top-2, segment-mapped, 64x128 tiles, atomic-free scatter) ----
  ln_kernel<<<dim3(2048), dim3(256), 0, stream>>>(out, ln2g, ln2b, xmh, xml);
  gate_kernel<<<dim3(32), dim3(256), 0, stream>>>(xmh, xml, gate_w, gate_b, comb);
  listbuild_kernel<<<dim3(1), dim3(1024), 0, stream>>>(comb, lists, cnts, starts, posA, posB);
  etrans_kernel<<<dim3(96, 24, 4), dim3(256), 0, stream>>>(exp_w1, etw1, 768, 3072);
  etrans_kernel<<<dim3(24, 96, 4), dim3(256), 0, stream>>>(exp_w2, etw2, 3072, 768);
  for (int hf = 0; hf < 2; hf++) {
    gemm_moe1<<<dim3(3168), dim3(256), 0, stream>>>(
        xmh, etw1, exp_b1, lists, cnts, starts, ehid, hf);
    gemm_moe2<<<dim3(1584), dim3(256), 0, stream>>>(
        ehid, etw2, exp_b2, comb, lists, cnts, starts, eout, hf);
  }
  combine_kernel<<<dim3(2048), dim3(256), 0, stream>>>(out, eout, posA, posB);
}